// Round 1
// baseline (3353.048 us; speedup 1.0000x reference)
//
#include <hip/hip_runtime.h>
#include <math.h>

// Problem constants
// B=2, L=2048, D_MODEL=1024, D_INNER=2048, D_STATE=16, DT_RANK=64, D_CONV=4
// P = B*L = 4096 positions

#define TILE 64
#define BK 16

__device__ __forceinline__ float silu_f(float x) {
    return x / (1.0f + expf(-x));
}

// ---------------------------------------------------------------------------
// Generic fp32 tiled GEMM: C[M,N] = A[M,K] @ B[K,N]; all dims multiples of 64/16.
// ---------------------------------------------------------------------------
__global__ __launch_bounds__(256) void gemm_nn(
    const float* __restrict__ A, const float* __restrict__ B, float* __restrict__ C,
    int M, int N, int K, int lda, int ldb, int ldc)
{
    __shared__ float As[BK][TILE + 4];
    __shared__ float Bs[BK][TILE];
    const int t  = threadIdx.x;
    const int m0 = blockIdx.y * TILE;
    const int n0 = blockIdx.x * TILE;
    const int am = t >> 2,  ak = (t & 3) * 4;
    const int bk = t >> 4,  bn = (t & 15) * 4;
    const int tm = (t >> 4) * 4, tn = (t & 15) * 4;
    float acc[4][4] = {};
    for (int k0 = 0; k0 < K; k0 += BK) {
        float4 av = *(const float4*)&A[(size_t)(m0 + am) * lda + k0 + ak];
        float4 bv = *(const float4*)&B[(size_t)(k0 + bk) * ldb + n0 + bn];
        As[ak + 0][am] = av.x;
        As[ak + 1][am] = av.y;
        As[ak + 2][am] = av.z;
        As[ak + 3][am] = av.w;
        *(float4*)&Bs[bk][bn] = bv;
        __syncthreads();
        #pragma unroll
        for (int k = 0; k < BK; ++k) {
            float4 a = *(const float4*)&As[k][tm];
            float4 b = *(const float4*)&Bs[k][tn];
            acc[0][0] += a.x * b.x; acc[0][1] += a.x * b.y; acc[0][2] += a.x * b.z; acc[0][3] += a.x * b.w;
            acc[1][0] += a.y * b.x; acc[1][1] += a.y * b.y; acc[1][2] += a.y * b.z; acc[1][3] += a.y * b.w;
            acc[2][0] += a.z * b.x; acc[2][1] += a.z * b.y; acc[2][2] += a.z * b.z; acc[2][3] += a.z * b.w;
            acc[3][0] += a.w * b.x; acc[3][1] += a.w * b.y; acc[3][2] += a.w * b.z; acc[3][3] += a.w * b.w;
        }
        __syncthreads();
    }
    #pragma unroll
    for (int i = 0; i < 4; ++i) {
        float4 r = make_float4(acc[i][0], acc[i][1], acc[i][2], acc[i][3]);
        *(float4*)&C[(size_t)(m0 + tm + i) * ldc + n0 + tn] = r;
    }
}

// ---------------------------------------------------------------------------
// Grouped causal conv as GEMM. M=4096(p), N=2048(o), K=4096(w*1024+i).
// A[p,k] = xz[p + w - 3, g*1024 + i]  (0 when l+w<3);  B[k,o] = conv_k[k*2048+o].
// Epilogue: u = silu(acc + conv_b[o]).
// ---------------------------------------------------------------------------
__global__ __launch_bounds__(256) void conv_gemm(
    const float* __restrict__ XZ, const float* __restrict__ Wk,
    const float* __restrict__ conv_b, float* __restrict__ U)
{
    __shared__ float As[BK][TILE + 4];
    __shared__ float Bs[BK][TILE];
    const int t  = threadIdx.x;
    const int m0 = blockIdx.y * TILE;
    const int n0 = blockIdx.x * TILE;
    const int g1024 = (n0 >> 10) << 10;   // group column offset in xz (0 or 1024)
    const int am = t >> 2,  ak = (t & 3) * 4;
    const int bk = t >> 4,  bn = (t & 15) * 4;
    const int tm = (t >> 4) * 4, tn = (t & 15) * 4;
    const int p = m0 + am;
    const int l = p & 2047;
    float acc[4][4] = {};
    for (int k0 = 0; k0 < 4096; k0 += BK) {
        const int k = k0 + ak;
        const int w = k >> 10;       // 0..3 (constant across the 4-float vector)
        const int i = k & 1023;
        float4 av;
        if (l + w >= 3) {
            av = *(const float4*)&XZ[(size_t)(p + w - 3) * 4096 + g1024 + i];
        } else {
            av = make_float4(0.f, 0.f, 0.f, 0.f);
        }
        float4 bv = *(const float4*)&Wk[(size_t)(k0 + bk) * 2048 + n0 + bn];
        As[ak + 0][am] = av.x;
        As[ak + 1][am] = av.y;
        As[ak + 2][am] = av.z;
        As[ak + 3][am] = av.w;
        *(float4*)&Bs[bk][bn] = bv;
        __syncthreads();
        #pragma unroll
        for (int k2 = 0; k2 < BK; ++k2) {
            float4 a = *(const float4*)&As[k2][tm];
            float4 b = *(const float4*)&Bs[k2][tn];
            acc[0][0] += a.x * b.x; acc[0][1] += a.x * b.y; acc[0][2] += a.x * b.z; acc[0][3] += a.x * b.w;
            acc[1][0] += a.y * b.x; acc[1][1] += a.y * b.y; acc[1][2] += a.y * b.z; acc[1][3] += a.y * b.w;
            acc[2][0] += a.z * b.x; acc[2][1] += a.z * b.y; acc[2][2] += a.z * b.z; acc[2][3] += a.z * b.w;
            acc[3][0] += a.w * b.x; acc[3][1] += a.w * b.y; acc[3][2] += a.w * b.z; acc[3][3] += a.w * b.w;
        }
        __syncthreads();
    }
    #pragma unroll
    for (int i2 = 0; i2 < 4; ++i2) {
        float4 r;
        float z0 = acc[i2][0] + conv_b[n0 + tn + 0];
        float z1 = acc[i2][1] + conv_b[n0 + tn + 1];
        float z2 = acc[i2][2] + conv_b[n0 + tn + 2];
        float z3 = acc[i2][3] + conv_b[n0 + tn + 3];
        r.x = silu_f(z0); r.y = silu_f(z1); r.z = silu_f(z2); r.w = silu_f(z3);
        *(float4*)&U[(size_t)(m0 + tm + i2) * 2048 + n0 + tn] = r;
    }
}

// ---------------------------------------------------------------------------
// dbc[p, 0:96] = u[p, :] @ W_x   (K=2048, N=96). One block per row p.
// ---------------------------------------------------------------------------
__global__ __launch_bounds__(128) void dbc_kernel(
    const float* __restrict__ U, const float* __restrict__ W_x, float* __restrict__ DBC)
{
    const int p = blockIdx.x;
    const int t = threadIdx.x;
    __shared__ float us[2048];
    for (int k = t * 4; k < 2048; k += 512) {
        *(float4*)&us[k] = *(const float4*)&U[(size_t)p * 2048 + k];
    }
    __syncthreads();
    if (t < 96) {
        float acc = 0.f;
        for (int k = 0; k < 2048; ++k) {
            acc += us[k] * W_x[(size_t)k * 96 + t];
        }
        DBC[(size_t)p * 96 + t] = acc;
    }
}

// ---------------------------------------------------------------------------
// delta[p, d] = clip(softplus(dbc[p,0:64] @ W_dt[:,d] + b_dt[d]), 1e-3, 1e-1)
// ---------------------------------------------------------------------------
__global__ __launch_bounds__(256) void delta_kernel(
    const float* __restrict__ DBC, const float* __restrict__ W_dt,
    const float* __restrict__ b_dt, float* __restrict__ DELTA)
{
    const int p  = blockIdx.y;
    const int n0 = blockIdx.x * 256;
    const int t  = threadIdx.x;
    __shared__ float dt_s[64];
    if (t < 64) dt_s[t] = DBC[(size_t)p * 96 + t];
    __syncthreads();
    const int n = n0 + t;
    float acc = b_dt[n];
    #pragma unroll 8
    for (int k = 0; k < 64; ++k) {
        acc += dt_s[k] * W_dt[(size_t)k * 2048 + n];
    }
    float sp = (acc > 20.f) ? acc : log1pf(expf(acc));
    sp = fminf(fmaxf(sp, 0.001f), 0.1f);
    DELTA[(size_t)p * 2048 + n] = sp;
}

// ---------------------------------------------------------------------------
// Sequential selective scan + fused output gate.
// Block = (b, 16-d chunk); 256 threads = 16 d x 16 n. h in registers.
// G[p,d] = (y[p,d] + u[p,d]*D[d]) * silu(res[p,d])
// ---------------------------------------------------------------------------
__global__ __launch_bounds__(256) void scan_kernel(
    const float* __restrict__ DELTA, const float* __restrict__ U,
    const float* __restrict__ DBC, const float* __restrict__ XZ,
    const float* __restrict__ A_log, const float* __restrict__ Dp,
    float* __restrict__ G)
{
    const int b  = blockIdx.y;        // 0..1
    const int d0 = blockIdx.x * 16;   // d chunk
    const int t  = threadIdx.x;
    const int dl = t >> 4;            // 0..15 (local d)
    const int n  = t & 15;            // 0..15 (state)
    const int d  = d0 + dl;
    const float Afac = -expf(A_log[(size_t)d * 16 + n]);
    const float Dd   = Dp[d];
    __shared__ float ds_[16][16], us_[16][16], Bs_[16][16], Cs_[16][16];
    float h = 0.f;
    const int base_p = b * 2048;
    for (int l0 = 0; l0 < 2048; l0 += 16) {
        // stage 16 timesteps
        const int ll = t >> 4, cc = t & 15;
        const int ps = base_p + l0 + ll;
        ds_[ll][cc] = DELTA[(size_t)ps * 2048 + d0 + cc];
        us_[ll][cc] = U[(size_t)ps * 2048 + d0 + cc];
        Bs_[ll][cc] = DBC[(size_t)ps * 96 + 64 + cc];
        Cs_[ll][cc] = DBC[(size_t)ps * 96 + 80 + cc];
        __syncthreads();
        #pragma unroll
        for (int j = 0; j < 16; ++j) {
            const float dv = ds_[j][dl];
            const float uv = us_[j][dl];
            const float bv = Bs_[j][n];
            const float cv = Cs_[j][n];
            const float dA = expf(dv * Afac);
            h = dA * h + dv * uv * bv;
            float y = h * cv;
            y += __shfl_xor(y, 1, 16);
            y += __shfl_xor(y, 2, 16);
            y += __shfl_xor(y, 4, 16);
            y += __shfl_xor(y, 8, 16);
            if (n == 0) {
                const int p2 = base_p + l0 + j;
                const float resv = XZ[(size_t)p2 * 4096 + 2048 + d];
                const float yf = y + uv * Dd;
                G[(size_t)p2 * 2048 + d] = yf * silu_f(resv);
            }
        }
        __syncthreads();
    }
}

// ---------------------------------------------------------------------------
extern "C" void kernel_launch(void* const* d_in, const int* in_sizes, int n_in,
                              void* d_out, int out_size, void* d_ws, size_t ws_size,
                              hipStream_t stream) {
    const float* x      = (const float*)d_in[0];
    const float* W_in   = (const float*)d_in[1];
    const float* conv_k = (const float*)d_in[2];
    const float* conv_b = (const float*)d_in[3];
    const float* W_x    = (const float*)d_in[4];
    const float* W_dt   = (const float*)d_in[5];
    const float* b_dt   = (const float*)d_in[6];
    const float* A_log  = (const float*)d_in[7];
    const float* Dv     = (const float*)d_in[8];
    const float* W_out  = (const float*)d_in[9];
    float* out = (float*)d_out;

    float* ws    = (float*)d_ws;
    float* xz    = ws;                                   // 4096 x 4096
    float* U     = xz    + (size_t)4096 * 4096;          // 4096 x 2048
    float* DBC   = U     + (size_t)4096 * 2048;          // 4096 x 96
    float* DELTA = DBC   + (size_t)4096 * 96;            // 4096 x 2048
    float* G     = DELTA + (size_t)4096 * 2048;          // 4096 x 2048

    // 1) xz = x @ W_in   (M=4096, N=4096, K=1024)
    gemm_nn<<<dim3(64, 64), 256, 0, stream>>>(x, W_in, xz, 4096, 4096, 1024,
                                              1024, 4096, 4096);
    // 2) u = silu(conv(xs) + conv_b)   (M=4096, N=2048, K=4096)
    conv_gemm<<<dim3(32, 64), 256, 0, stream>>>(xz, conv_k, conv_b, U);
    // 3) dbc = u @ W_x
    dbc_kernel<<<4096, 128, 0, stream>>>(U, W_x, DBC);
    // 4) delta
    delta_kernel<<<dim3(8, 4096), 256, 0, stream>>>(DBC, W_dt, b_dt, DELTA);
    // 5) scan -> G
    scan_kernel<<<dim3(128, 2), 256, 0, stream>>>(DELTA, U, DBC, xz, A_log, Dv, G);
    // 6) out = G @ W_out   (M=4096, N=1024, K=2048)
    gemm_nn<<<dim3(16, 64), 256, 0, stream>>>(G, W_out, out, 4096, 1024, 2048,
                                              2048, 1024, 1024);
}

// Round 2
// 1996.660 us; speedup vs baseline: 1.6793x; 1.6793x over previous
//
#include <hip/hip_runtime.h>
#include <math.h>

// B=2, L=2048, D_MODEL=1024, D_INNER=2048, D_STATE=16, DT_RANK=64, D_CONV=4
// P = B*L = 4096

#define TILE 128
#define BK 16

__device__ __forceinline__ float silu_f(float x) {
    return x / (1.0f + __expf(-x));
}

// ---------------------------------------------------------------------------
// fp32 GEMM: C[M,N] = A[M,K] @ B[K,N]. 128x128 tile, 8x8 micro, 256 threads.
// M,N multiples of 128; K multiple of 16.
// ---------------------------------------------------------------------------
__global__ __launch_bounds__(256) void gemm_nn(
    const float* __restrict__ A, const float* __restrict__ B, float* __restrict__ C,
    int K, int lda, int ldb, int ldc)
{
    __shared__ float As[BK][TILE + 4];
    __shared__ float Bs[BK][TILE + 4];
    const int t  = threadIdx.x;
    const int m0 = blockIdx.y * TILE;
    const int n0 = blockIdx.x * TILE;
    const int ar = t >> 2, ac = (t & 3) * 4;    // A rows ar, ar+64; k-cols ac..ac+3
    const int bk = t >> 4, bn = (t & 15) * 4;   // B k-row bk; cols bn, bn+64
    const int tm = (t >> 4) * 8, tn = (t & 15) * 8;

    float4 a0 = *(const float4*)&A[(size_t)(m0 + ar) * lda + ac];
    float4 a1 = *(const float4*)&A[(size_t)(m0 + ar + 64) * lda + ac];
    float4 b0 = *(const float4*)&B[(size_t)bk * ldb + n0 + bn];
    float4 b1 = *(const float4*)&B[(size_t)bk * ldb + n0 + bn + 64];

    float acc[8][8] = {};
    for (int k0 = 0; k0 < K; k0 += BK) {
        As[ac+0][ar] = a0.x; As[ac+1][ar] = a0.y; As[ac+2][ar] = a0.z; As[ac+3][ar] = a0.w;
        As[ac+0][ar+64] = a1.x; As[ac+1][ar+64] = a1.y; As[ac+2][ar+64] = a1.z; As[ac+3][ar+64] = a1.w;
        *(float4*)&Bs[bk][bn]      = b0;
        *(float4*)&Bs[bk][bn + 64] = b1;
        __syncthreads();
        if (k0 + BK < K) {
            const int kn = k0 + BK;
            a0 = *(const float4*)&A[(size_t)(m0 + ar) * lda + kn + ac];
            a1 = *(const float4*)&A[(size_t)(m0 + ar + 64) * lda + kn + ac];
            b0 = *(const float4*)&B[(size_t)(kn + bk) * ldb + n0 + bn];
            b1 = *(const float4*)&B[(size_t)(kn + bk) * ldb + n0 + bn + 64];
        }
        #pragma unroll
        for (int k = 0; k < BK; ++k) {
            float av[8], bv[8];
            *(float4*)&av[0] = *(const float4*)&As[k][tm];
            *(float4*)&av[4] = *(const float4*)&As[k][tm + 4];
            *(float4*)&bv[0] = *(const float4*)&Bs[k][tn];
            *(float4*)&bv[4] = *(const float4*)&Bs[k][tn + 4];
            #pragma unroll
            for (int i = 0; i < 8; ++i)
                #pragma unroll
                for (int j = 0; j < 8; ++j)
                    acc[i][j] += av[i] * bv[j];
        }
        __syncthreads();
    }
    #pragma unroll
    for (int i = 0; i < 8; ++i) {
        *(float4*)&C[(size_t)(m0 + tm + i) * ldc + n0 + tn]     =
            make_float4(acc[i][0], acc[i][1], acc[i][2], acc[i][3]);
        *(float4*)&C[(size_t)(m0 + tm + i) * ldc + n0 + tn + 4] =
            make_float4(acc[i][4], acc[i][5], acc[i][6], acc[i][7]);
    }
}

// ---------------------------------------------------------------------------
// Grouped causal conv as GEMM. M=4096(p), N=2048(o), K=4096 (w*1024+i).
// A[p,k] = xz[p+w-3, g*1024+i] (0 when l+w<3); B[k,o] = conv_k[k*2048+o].
// Epilogue: u = silu(acc + conv_b[o]).
// ---------------------------------------------------------------------------
__global__ __launch_bounds__(256) void conv_gemm(
    const float* __restrict__ XZ, const float* __restrict__ Wk,
    const float* __restrict__ conv_b, float* __restrict__ U)
{
    __shared__ float As[BK][TILE + 4];
    __shared__ float Bs[BK][TILE + 4];
    const int t  = threadIdx.x;
    const int m0 = blockIdx.y * TILE;
    const int n0 = blockIdx.x * TILE;
    const int g1024 = (n0 >= 1024) ? 1024 : 0;
    const int ar = t >> 2, ac = (t & 3) * 4;
    const int bk = t >> 4, bn = (t & 15) * 4;
    const int tm = (t >> 4) * 8, tn = (t & 15) * 8;
    const int p0 = m0 + ar, p1 = m0 + ar + 64;
    const int l0_ = p0 & 2047, l1_ = p1 & 2047;

    auto loadA = [&](int p, int l, int k) -> float4 {
        const int w = k >> 10, i = k & 1023;
        if (l + w >= 3)
            return *(const float4*)&XZ[(size_t)(p + w - 3) * 4096 + g1024 + i];
        return make_float4(0.f, 0.f, 0.f, 0.f);
    };

    float4 a0 = loadA(p0, l0_, ac);
    float4 a1 = loadA(p1, l1_, ac);
    float4 b0 = *(const float4*)&Wk[(size_t)bk * 2048 + n0 + bn];
    float4 b1 = *(const float4*)&Wk[(size_t)bk * 2048 + n0 + bn + 64];

    float acc[8][8] = {};
    for (int k0 = 0; k0 < 4096; k0 += BK) {
        As[ac+0][ar] = a0.x; As[ac+1][ar] = a0.y; As[ac+2][ar] = a0.z; As[ac+3][ar] = a0.w;
        As[ac+0][ar+64] = a1.x; As[ac+1][ar+64] = a1.y; As[ac+2][ar+64] = a1.z; As[ac+3][ar+64] = a1.w;
        *(float4*)&Bs[bk][bn]      = b0;
        *(float4*)&Bs[bk][bn + 64] = b1;
        __syncthreads();
        if (k0 + BK < 4096) {
            const int kn = k0 + BK;
            a0 = loadA(p0, l0_, kn + ac);
            a1 = loadA(p1, l1_, kn + ac);
            b0 = *(const float4*)&Wk[(size_t)(kn + bk) * 2048 + n0 + bn];
            b1 = *(const float4*)&Wk[(size_t)(kn + bk) * 2048 + n0 + bn + 64];
        }
        #pragma unroll
        for (int k = 0; k < BK; ++k) {
            float av[8], bv[8];
            *(float4*)&av[0] = *(const float4*)&As[k][tm];
            *(float4*)&av[4] = *(const float4*)&As[k][tm + 4];
            *(float4*)&bv[0] = *(const float4*)&Bs[k][tn];
            *(float4*)&bv[4] = *(const float4*)&Bs[k][tn + 4];
            #pragma unroll
            for (int i = 0; i < 8; ++i)
                #pragma unroll
                for (int j = 0; j < 8; ++j)
                    acc[i][j] += av[i] * bv[j];
        }
        __syncthreads();
    }
    float bz[8];
    *(float4*)&bz[0] = *(const float4*)&conv_b[n0 + tn];
    *(float4*)&bz[4] = *(const float4*)&conv_b[n0 + tn + 4];
    #pragma unroll
    for (int i = 0; i < 8; ++i) {
        float r[8];
        #pragma unroll
        for (int j = 0; j < 8; ++j) r[j] = silu_f(acc[i][j] + bz[j]);
        *(float4*)&U[(size_t)(m0 + tm + i) * 2048 + n0 + tn]     = *(float4*)&r[0];
        *(float4*)&U[(size_t)(m0 + tm + i) * 2048 + n0 + tn + 4] = *(float4*)&r[4];
    }
}

// ---------------------------------------------------------------------------
// dbc[p,0:96] = u[p,:] @ W_x  (K=2048, N=96). Block = 8 rows, 128 threads
// (96 active for compute), k staged in 256-chunks; W_x read amortized x8.
// ---------------------------------------------------------------------------
__global__ __launch_bounds__(128) void dbc_kernel(
    const float* __restrict__ U, const float* __restrict__ W_x, float* __restrict__ DBC)
{
    const int p0 = blockIdx.x * 8;
    const int t  = threadIdx.x;
    __shared__ float us[8][256];
    float acc[8] = {};
    for (int k0 = 0; k0 < 2048; k0 += 256) {
        #pragma unroll
        for (int j = 0; j < 4; ++j) {
            const int lin = j * 512 + t * 4;
            const int r = lin >> 8, c = lin & 255;
            *(float4*)&us[r][c] = *(const float4*)&U[(size_t)(p0 + r) * 2048 + k0 + c];
        }
        __syncthreads();
        if (t < 96) {
            for (int k = 0; k < 256; ++k) {
                const float wv = W_x[(size_t)(k0 + k) * 96 + t];
                #pragma unroll
                for (int r = 0; r < 8; ++r) acc[r] += us[r][k] * wv;
            }
        }
        __syncthreads();
    }
    if (t < 96) {
        #pragma unroll
        for (int r = 0; r < 8; ++r) DBC[(size_t)(p0 + r) * 96 + t] = acc[r];
    }
}

// ---------------------------------------------------------------------------
// delta[p,d] = clip(softplus(dbc[p,0:64] @ W_dt[:,d] + b_dt[d]), 1e-3, 1e-1)
// Block = 16 rows x 256 cols; W_dt read amortized x16.
// ---------------------------------------------------------------------------
__global__ __launch_bounds__(256) void delta_kernel(
    const float* __restrict__ DBC, const float* __restrict__ W_dt,
    const float* __restrict__ b_dt, float* __restrict__ DELTA)
{
    const int n  = blockIdx.x * 256 + threadIdx.x;
    const int p0 = blockIdx.y * 16;
    const int t  = threadIdx.x;
    __shared__ float dt_s[16][64];
    #pragma unroll
    for (int j = 0; j < 4; ++j) {
        const int lin = j * 256 + t;
        const int r = lin >> 6, k = lin & 63;
        dt_s[r][k] = DBC[(size_t)(p0 + r) * 96 + k];
    }
    __syncthreads();
    float acc[16];
    const float bz = b_dt[n];
    #pragma unroll
    for (int r = 0; r < 16; ++r) acc[r] = bz;
    for (int k = 0; k < 64; ++k) {
        const float wv = W_dt[(size_t)k * 2048 + n];
        #pragma unroll
        for (int r = 0; r < 16; ++r) acc[r] += dt_s[r][k] * wv;
    }
    #pragma unroll
    for (int r = 0; r < 16; ++r) {
        float a = acc[r];
        float sp = (a > 20.f) ? a : log1pf(expf(a));
        sp = fminf(fmaxf(sp, 0.001f), 0.1f);
        DELTA[(size_t)(p0 + r) * 2048 + n] = sp;
    }
}

// ---------------------------------------------------------------------------
// Chunked scan. L=2048 split into 64 chunks of 32. Thread owns one d and all
// 16 states in registers. Layout for inter-chunk arrays:
//   off(c,n,b,d) = c*65536 + n*4096 + b*2048 + d
// Pass 1: per-chunk local scan from 0 -> h_end; a_prod = exp(A[n]*sum(delta)).
// ---------------------------------------------------------------------------
__global__ __launch_bounds__(256) void scan_p1(
    const float* __restrict__ DELTA, const float* __restrict__ U,
    const float* __restrict__ DBC, const float* __restrict__ A_log,
    float* __restrict__ HEND, float* __restrict__ APROD)
{
    const int t = threadIdx.x;
    const int d = blockIdx.x * 256 + t;
    const int c = blockIdx.y;
    const int b = blockIdx.z;
    const int p0 = b * 2048 + c * 32;
    __shared__ float Bs[32][16];
    for (int lin = t; lin < 512; lin += 256) {
        const int s = lin >> 4, n = lin & 15;
        Bs[s][n] = DBC[(size_t)(p0 + s) * 96 + 64 + n];
    }
    __syncthreads();
    float Af[16];
    *(float4*)&Af[0]  = *(const float4*)&A_log[(size_t)d * 16 + 0];
    *(float4*)&Af[4]  = *(const float4*)&A_log[(size_t)d * 16 + 4];
    *(float4*)&Af[8]  = *(const float4*)&A_log[(size_t)d * 16 + 8];
    *(float4*)&Af[12] = *(const float4*)&A_log[(size_t)d * 16 + 12];
    #pragma unroll
    for (int n = 0; n < 16; ++n) Af[n] = -__expf(Af[n]);

    float h[16] = {};
    float sd = 0.f;
    for (int s = 0; s < 32; ++s) {
        const float dv = DELTA[(size_t)(p0 + s) * 2048 + d];
        const float uv = U[(size_t)(p0 + s) * 2048 + d];
        const float du = dv * uv;
        sd += dv;
        #pragma unroll
        for (int n = 0; n < 16; ++n)
            h[n] = __expf(dv * Af[n]) * h[n] + du * Bs[s][n];
    }
    const size_t base = (size_t)c * 65536 + (size_t)b * 2048 + d;
    #pragma unroll
    for (int n = 0; n < 16; ++n) {
        HEND[base + (size_t)n * 4096]  = h[n];
        APROD[base + (size_t)n * 4096] = __expf(Af[n] * sd);
    }
}

// Pass 2: exclusive scan over the 64 chunks. g = n*4096 + b*2048 + d.
__global__ __launch_bounds__(256) void scan_p2(
    const float* __restrict__ HEND, const float* __restrict__ APROD,
    float* __restrict__ HINIT)
{
    const int g = blockIdx.x * 256 + threadIdx.x;
    float h = 0.f;
    for (int c = 0; c < 64; ++c) {
        HINIT[(size_t)c * 65536 + g] = h;
        h = APROD[(size_t)c * 65536 + g] * h + HEND[(size_t)c * 65536 + g];
    }
}

// Pass 3: re-scan from h_init, compute y, fuse output gate -> G.
__global__ __launch_bounds__(256) void scan_p3(
    const float* __restrict__ DELTA, const float* __restrict__ U,
    const float* __restrict__ DBC, const float* __restrict__ XZ,
    const float* __restrict__ A_log, const float* __restrict__ Dp,
    const float* __restrict__ HINIT, float* __restrict__ G)
{
    const int t = threadIdx.x;
    const int d = blockIdx.x * 256 + t;
    const int c = blockIdx.y;
    const int b = blockIdx.z;
    const int p0 = b * 2048 + c * 32;
    __shared__ float Bs[32][16];
    __shared__ float Cs[32][16];
    for (int lin = t; lin < 512; lin += 256) {
        const int s = lin >> 4, n = lin & 15;
        Bs[s][n] = DBC[(size_t)(p0 + s) * 96 + 64 + n];
        Cs[s][n] = DBC[(size_t)(p0 + s) * 96 + 80 + n];
    }
    __syncthreads();
    float Af[16];
    *(float4*)&Af[0]  = *(const float4*)&A_log[(size_t)d * 16 + 0];
    *(float4*)&Af[4]  = *(const float4*)&A_log[(size_t)d * 16 + 4];
    *(float4*)&Af[8]  = *(const float4*)&A_log[(size_t)d * 16 + 8];
    *(float4*)&Af[12] = *(const float4*)&A_log[(size_t)d * 16 + 12];
    #pragma unroll
    for (int n = 0; n < 16; ++n) Af[n] = -__expf(Af[n]);

    const size_t base = (size_t)c * 65536 + (size_t)b * 2048 + d;
    float h[16];
    #pragma unroll
    for (int n = 0; n < 16; ++n) h[n] = HINIT[base + (size_t)n * 4096];
    const float Dd = Dp[d];

    for (int s = 0; s < 32; ++s) {
        const int p = p0 + s;
        const float dv = DELTA[(size_t)p * 2048 + d];
        const float uv = U[(size_t)p * 2048 + d];
        const float du = dv * uv;
        float y = 0.f;
        #pragma unroll
        for (int n = 0; n < 16; ++n) {
            h[n] = __expf(dv * Af[n]) * h[n] + du * Bs[s][n];
            y += h[n] * Cs[s][n];
        }
        const float resv = XZ[(size_t)p * 4096 + 2048 + d];
        G[(size_t)p * 2048 + d] = (y + uv * Dd) * silu_f(resv);
    }
}

// ---------------------------------------------------------------------------
extern "C" void kernel_launch(void* const* d_in, const int* in_sizes, int n_in,
                              void* d_out, int out_size, void* d_ws, size_t ws_size,
                              hipStream_t stream) {
    const float* x      = (const float*)d_in[0];
    const float* W_in   = (const float*)d_in[1];
    const float* conv_k = (const float*)d_in[2];
    const float* conv_b = (const float*)d_in[3];
    const float* W_x    = (const float*)d_in[4];
    const float* W_dt   = (const float*)d_in[5];
    const float* b_dt   = (const float*)d_in[6];
    const float* A_log  = (const float*)d_in[7];
    const float* Dv     = (const float*)d_in[8];
    const float* W_out  = (const float*)d_in[9];
    float* out = (float*)d_out;

    float* ws    = (float*)d_ws;
    float* xz    = ws;                         // 4096 x 4096 = 16,777,216
    float* U     = xz    + (size_t)16777216;   // 4096 x 2048 =  8,388,608
    float* DBC   = U     + (size_t)8388608;    // 4096 x 96   =    393,216
    float* DELTA = DBC   + (size_t)393216;     // 4096 x 2048 =  8,388,608
    float* HEND  = DELTA + (size_t)8388608;    // 64 x 65536  =  4,194,304
    float* APROD = HEND  + (size_t)4194304;    //              4,194,304
    float* HINIT = APROD + (size_t)4194304;    //              4,194,304
    float* G     = HEND;  // alias: HEND+APROD dead after scan_p2 (8,388,608)

    // 1) xz = x @ W_in   (M=4096, N=4096, K=1024)
    gemm_nn<<<dim3(32, 32), 256, 0, stream>>>(x, W_in, xz, 1024, 1024, 4096, 4096);
    // 2) u = silu(conv(xs) + conv_b)
    conv_gemm<<<dim3(16, 32), 256, 0, stream>>>(xz, conv_k, conv_b, U);
    // 3) dbc = u @ W_x
    dbc_kernel<<<512, 128, 0, stream>>>(U, W_x, DBC);
    // 4) delta
    delta_kernel<<<dim3(8, 256), 256, 0, stream>>>(DBC, W_dt, b_dt, DELTA);
    // 5) chunked scan
    scan_p1<<<dim3(8, 64, 2), 256, 0, stream>>>(DELTA, U, DBC, A_log, HEND, APROD);
    scan_p2<<<256, 256, 0, stream>>>(HEND, APROD, HINIT);
    scan_p3<<<dim3(8, 64, 2), 256, 0, stream>>>(DELTA, U, DBC, xz, A_log, Dv, HINIT, G);
    // 6) out = G @ W_out   (M=4096, N=1024, K=2048)
    gemm_nn<<<dim3(8, 32), 256, 0, stream>>>(G, W_out, out, 2048, 2048, 1024, 1024);
}

// Round 3
// 923.447 us; speedup vs baseline: 3.6310x; 2.1622x over previous
//
#include <hip/hip_runtime.h>
#include <math.h>

// B=2, L=2048, D_MODEL=1024, D_INNER=2048, D_STATE=16, DT_RANK=64, D_CONV=4
// P = B*L = 4096

typedef unsigned short ushort_t;
typedef __bf16 bf16x8 __attribute__((ext_vector_type(8)));
typedef float floatx4 __attribute__((ext_vector_type(4)));

#define LDS_STRIDE 40   // 32 + 8 pad: 80B rows, 16B aligned, 2-way-only conflicts

__device__ __forceinline__ float silu_f(float x) { return x / (1.0f + __expf(-x)); }

__device__ __forceinline__ unsigned short f2bf(float f) {
    unsigned u = __float_as_uint(f);
    unsigned r = u + 0x7fffu + ((u >> 16) & 1u);   // RNE (finite values only)
    return (unsigned short)(r >> 16);
}
__device__ __forceinline__ float bf2f(unsigned short h) {
    return __uint_as_float(((unsigned)h) << 16);
}

// ---------------------------------------------------------------------------
// fp32 -> bf16 hi/lo split, row-major (for x, G). 4 elems/thread.
// ---------------------------------------------------------------------------
__global__ __launch_bounds__(256) void split_rm(
    const float* __restrict__ in, ushort_t* __restrict__ oh, ushort_t* __restrict__ ol)
{
    const size_t i4 = ((size_t)blockIdx.x * 256 + threadIdx.x) * 4;
    float4 v = *(const float4*)&in[i4];
    unsigned short h0 = f2bf(v.x), h1 = f2bf(v.y), h2 = f2bf(v.z), h3 = f2bf(v.w);
    unsigned short l0 = f2bf(v.x - bf2f(h0)), l1 = f2bf(v.y - bf2f(h1));
    unsigned short l2 = f2bf(v.z - bf2f(h2)), l3 = f2bf(v.w - bf2f(h3));
    *(uint2*)&oh[i4] = make_uint2((unsigned)h0 | ((unsigned)h1 << 16),
                                  (unsigned)h2 | ((unsigned)h3 << 16));
    *(uint2*)&ol[i4] = make_uint2((unsigned)l0 | ((unsigned)l1 << 16),
                                  (unsigned)l2 | ((unsigned)l3 << 16));
}

// ---------------------------------------------------------------------------
// fp32 [R][C] -> bf16 hi/lo transposed [C][R] (for W_in, conv_k, W_out).
// ---------------------------------------------------------------------------
__global__ __launch_bounds__(256) void split_tr(
    const float* __restrict__ in, int R, int C,
    ushort_t* __restrict__ oh, ushort_t* __restrict__ ol)
{
    __shared__ float ts[32][33];
    const int t = threadIdx.x;
    const int tx = t & 31, ty = t >> 5;     // ty 0..7
    const int r0 = blockIdx.y * 32, c0 = blockIdx.x * 32;
    #pragma unroll
    for (int j = 0; j < 4; ++j)
        ts[ty + j * 8][tx] = in[(size_t)(r0 + ty + j * 8) * C + c0 + tx];
    __syncthreads();
    #pragma unroll
    for (int j = 0; j < 4; ++j) {
        float v = ts[tx][ty + j * 8];
        unsigned short h = f2bf(v);
        unsigned short l = f2bf(v - bf2f(h));
        const size_t a = (size_t)(c0 + ty + j * 8) * R + r0 + tx;
        oh[a] = h;
        ol[a] = l;
    }
}

// Zero the 3 causal-padding rows per batch of XSP (2 batches x 3 rows x 2048).
__global__ __launch_bounds__(256) void zero_pad(ushort_t* __restrict__ xh,
                                                ushort_t* __restrict__ xl)
{
    const int idx = blockIdx.x * 256 + threadIdx.x;   // < 12288
    const int b = idx / 6144, rem = idx % 6144;
    const int lp = rem >> 11, c = rem & 2047;
    const size_t a = ((size_t)b * 2051 + lp) * 2048 + c;
    xh[a] = 0; xl[a] = 0;
}

// ---------------------------------------------------------------------------
// Split-bf16 MFMA GEMM: C = A @ B.  A as hi/lo [M][K] rm; B pre-transposed
// hi/lo [N][K].  128x128 tile, BK=32, 4 waves x (4x4) 16x16x32 MFMA tiles,
// 3 MFMAs per tile (AhBh + AhBl + AlBh) -> ~fp32 precision.
// MODE 0: xz epilogue — cols<2048: write bf16 hi/lo into XSP (+3 row pad);
//         cols>=2048: write fp32 res.   MODE 2: plain fp32 store (ldc=1024).
// ---------------------------------------------------------------------------
template<int MODE>
__global__ __launch_bounds__(256) void gemm_sp(
    const ushort_t* __restrict__ Ah, const ushort_t* __restrict__ Al,
    const ushort_t* __restrict__ Bh, const ushort_t* __restrict__ Bl,
    int K, float* __restrict__ Cf, ushort_t* __restrict__ Oh, ushort_t* __restrict__ Ol)
{
    __shared__ __align__(16) ushort_t As_h[128 * LDS_STRIDE];
    __shared__ __align__(16) ushort_t As_l[128 * LDS_STRIDE];
    __shared__ __align__(16) ushort_t Bs_h[128 * LDS_STRIDE];
    __shared__ __align__(16) ushort_t Bs_l[128 * LDS_STRIDE];
    const int t = threadIdx.x;
    const int m0 = blockIdx.y * 128, n0 = blockIdx.x * 128;
    const int lane = t & 63, wave = t >> 6;
    const int wm = (wave >> 1) * 64, wn = (wave & 1) * 64;
    const int m16 = lane & 15, q = lane >> 4;
    const int r_0 = t >> 2, cc_0 = (t & 3) * 8;            // chunk t
    const int r_1 = (t + 256) >> 2, cc_1 = ((t + 256) & 3) * 8;

    uint4 pa0h = *(const uint4*)&Ah[(size_t)(m0 + r_0) * K + cc_0];
    uint4 pa1h = *(const uint4*)&Ah[(size_t)(m0 + r_1) * K + cc_1];
    uint4 pa0l = *(const uint4*)&Al[(size_t)(m0 + r_0) * K + cc_0];
    uint4 pa1l = *(const uint4*)&Al[(size_t)(m0 + r_1) * K + cc_1];
    uint4 pb0h = *(const uint4*)&Bh[(size_t)(n0 + r_0) * K + cc_0];
    uint4 pb1h = *(const uint4*)&Bh[(size_t)(n0 + r_1) * K + cc_1];
    uint4 pb0l = *(const uint4*)&Bl[(size_t)(n0 + r_0) * K + cc_0];
    uint4 pb1l = *(const uint4*)&Bl[(size_t)(n0 + r_1) * K + cc_1];

    floatx4 acc[4][4];
    const floatx4 zz = {0.f, 0.f, 0.f, 0.f};
    #pragma unroll
    for (int i = 0; i < 4; ++i)
        #pragma unroll
        for (int j = 0; j < 4; ++j) acc[i][j] = zz;

    for (int k0 = 0; k0 < K; k0 += 32) {
        *(uint4*)&As_h[r_0 * LDS_STRIDE + cc_0] = pa0h;
        *(uint4*)&As_h[r_1 * LDS_STRIDE + cc_1] = pa1h;
        *(uint4*)&As_l[r_0 * LDS_STRIDE + cc_0] = pa0l;
        *(uint4*)&As_l[r_1 * LDS_STRIDE + cc_1] = pa1l;
        *(uint4*)&Bs_h[r_0 * LDS_STRIDE + cc_0] = pb0h;
        *(uint4*)&Bs_h[r_1 * LDS_STRIDE + cc_1] = pb1h;
        *(uint4*)&Bs_l[r_0 * LDS_STRIDE + cc_0] = pb0l;
        *(uint4*)&Bs_l[r_1 * LDS_STRIDE + cc_1] = pb1l;
        __syncthreads();
        if (k0 + 32 < K) {
            const int kn = k0 + 32;
            pa0h = *(const uint4*)&Ah[(size_t)(m0 + r_0) * K + kn + cc_0];
            pa1h = *(const uint4*)&Ah[(size_t)(m0 + r_1) * K + kn + cc_1];
            pa0l = *(const uint4*)&Al[(size_t)(m0 + r_0) * K + kn + cc_0];
            pa1l = *(const uint4*)&Al[(size_t)(m0 + r_1) * K + kn + cc_1];
            pb0h = *(const uint4*)&Bh[(size_t)(n0 + r_0) * K + kn + cc_0];
            pb1h = *(const uint4*)&Bh[(size_t)(n0 + r_1) * K + kn + cc_1];
            pb0l = *(const uint4*)&Bl[(size_t)(n0 + r_0) * K + kn + cc_0];
            pb1l = *(const uint4*)&Bl[(size_t)(n0 + r_1) * K + kn + cc_1];
        }
        bf16x8 ah[4], al[4], bh[4], bl[4];
        #pragma unroll
        for (int i = 0; i < 4; ++i) {
            const int off = (wm + i * 16 + m16) * LDS_STRIDE + q * 8;
            ah[i] = *(const bf16x8*)&As_h[off];
            al[i] = *(const bf16x8*)&As_l[off];
        }
        #pragma unroll
        for (int j = 0; j < 4; ++j) {
            const int off = (wn + j * 16 + m16) * LDS_STRIDE + q * 8;
            bh[j] = *(const bf16x8*)&Bs_h[off];
            bl[j] = *(const bf16x8*)&Bs_l[off];
        }
        #pragma unroll
        for (int i = 0; i < 4; ++i)
            #pragma unroll
            for (int j = 0; j < 4; ++j) {
                acc[i][j] = __builtin_amdgcn_mfma_f32_16x16x32_bf16(ah[i], bh[j], acc[i][j], 0, 0, 0);
                acc[i][j] = __builtin_amdgcn_mfma_f32_16x16x32_bf16(ah[i], bl[j], acc[i][j], 0, 0, 0);
                acc[i][j] = __builtin_amdgcn_mfma_f32_16x16x32_bf16(al[i], bh[j], acc[i][j], 0, 0, 0);
            }
        __syncthreads();
    }

    #pragma unroll
    for (int i = 0; i < 4; ++i) {
        const int row_b = m0 + wm + i * 16 + q * 4;
        #pragma unroll
        for (int j = 0; j < 4; ++j) {
            const int col = n0 + wn + j * 16 + m16;
            #pragma unroll
            for (int rr = 0; rr < 4; ++rr) {
                const int row = row_b + rr;
                const float v = acc[i][j][rr];
                if (MODE == 0) {
                    if (n0 < 2048) {
                        const int b = row >> 11, l = row & 2047;
                        const size_t a = ((size_t)b * 2051 + l + 3) * 2048 + col;
                        const unsigned short h = f2bf(v);
                        Oh[a] = h;
                        Ol[a] = f2bf(v - bf2f(h));
                    } else {
                        Cf[(size_t)row * 2048 + (col - 2048)] = v;
                    }
                } else {
                    Cf[(size_t)row * 1024 + col] = v;
                }
            }
        }
    }
}

// ---------------------------------------------------------------------------
// Conv as split-bf16 MFMA GEMM. A[p][k=w*1024+i] = XSP[b][l+w][g*1024+i]
// (XSP zero-padded by 3 rows per batch). B = conv_k^T hi/lo [2048][4096].
// Epilogue: U = silu(acc + conv_b).
// ---------------------------------------------------------------------------
__global__ __launch_bounds__(256) void conv_sp(
    const ushort_t* __restrict__ Xh, const ushort_t* __restrict__ Xl,
    const ushort_t* __restrict__ Bh, const ushort_t* __restrict__ Bl,
    const float* __restrict__ bias, float* __restrict__ U)
{
    __shared__ __align__(16) ushort_t As_h[128 * LDS_STRIDE];
    __shared__ __align__(16) ushort_t As_l[128 * LDS_STRIDE];
    __shared__ __align__(16) ushort_t Bs_h[128 * LDS_STRIDE];
    __shared__ __align__(16) ushort_t Bs_l[128 * LDS_STRIDE];
    const int t = threadIdx.x;
    const int m0 = blockIdx.y * 128, n0 = blockIdx.x * 128;
    const int g1024 = (n0 >= 1024) ? 1024 : 0;
    const int lane = t & 63, wave = t >> 6;
    const int wm = (wave >> 1) * 64, wn = (wave & 1) * 64;
    const int m16 = lane & 15, q = lane >> 4;
    const int r_0 = t >> 2, cc_0 = (t & 3) * 8;
    const int r_1 = (t + 256) >> 2, cc_1 = ((t + 256) & 3) * 8;
    const int p_0 = m0 + r_0, b_0 = p_0 >> 11, l_0 = p_0 & 2047;
    const int p_1 = m0 + r_1, b_1 = p_1 >> 11, l_1 = p_1 & 2047;

    auto aA = [&](int bb, int ll, int k0, int cc) -> size_t {
        const int w = k0 >> 10;
        const int i = (k0 & 1023) + cc;
        return ((size_t)bb * 2051 + ll + w) * 2048 + g1024 + i;
    };

    uint4 pa0h = *(const uint4*)&Xh[aA(b_0, l_0, 0, cc_0)];
    uint4 pa1h = *(const uint4*)&Xh[aA(b_1, l_1, 0, cc_1)];
    uint4 pa0l = *(const uint4*)&Xl[aA(b_0, l_0, 0, cc_0)];
    uint4 pa1l = *(const uint4*)&Xl[aA(b_1, l_1, 0, cc_1)];
    uint4 pb0h = *(const uint4*)&Bh[(size_t)(n0 + r_0) * 4096 + cc_0];
    uint4 pb1h = *(const uint4*)&Bh[(size_t)(n0 + r_1) * 4096 + cc_1];
    uint4 pb0l = *(const uint4*)&Bl[(size_t)(n0 + r_0) * 4096 + cc_0];
    uint4 pb1l = *(const uint4*)&Bl[(size_t)(n0 + r_1) * 4096 + cc_1];

    floatx4 acc[4][4];
    const floatx4 zz = {0.f, 0.f, 0.f, 0.f};
    #pragma unroll
    for (int i = 0; i < 4; ++i)
        #pragma unroll
        for (int j = 0; j < 4; ++j) acc[i][j] = zz;

    for (int k0 = 0; k0 < 4096; k0 += 32) {
        *(uint4*)&As_h[r_0 * LDS_STRIDE + cc_0] = pa0h;
        *(uint4*)&As_h[r_1 * LDS_STRIDE + cc_1] = pa1h;
        *(uint4*)&As_l[r_0 * LDS_STRIDE + cc_0] = pa0l;
        *(uint4*)&As_l[r_1 * LDS_STRIDE + cc_1] = pa1l;
        *(uint4*)&Bs_h[r_0 * LDS_STRIDE + cc_0] = pb0h;
        *(uint4*)&Bs_h[r_1 * LDS_STRIDE + cc_1] = pb1h;
        *(uint4*)&Bs_l[r_0 * LDS_STRIDE + cc_0] = pb0l;
        *(uint4*)&Bs_l[r_1 * LDS_STRIDE + cc_1] = pb1l;
        __syncthreads();
        if (k0 + 32 < 4096) {
            const int kn = k0 + 32;
            pa0h = *(const uint4*)&Xh[aA(b_0, l_0, kn, cc_0)];
            pa1h = *(const uint4*)&Xh[aA(b_1, l_1, kn, cc_1)];
            pa0l = *(const uint4*)&Xl[aA(b_0, l_0, kn, cc_0)];
            pa1l = *(const uint4*)&Xl[aA(b_1, l_1, kn, cc_1)];
            pb0h = *(const uint4*)&Bh[(size_t)(n0 + r_0) * 4096 + kn + cc_0];
            pb1h = *(const uint4*)&Bh[(size_t)(n0 + r_1) * 4096 + kn + cc_1];
            pb0l = *(const uint4*)&Bl[(size_t)(n0 + r_0) * 4096 + kn + cc_0];
            pb1l = *(const uint4*)&Bl[(size_t)(n0 + r_1) * 4096 + kn + cc_1];
        }
        bf16x8 ah[4], al[4], bh[4], bl[4];
        #pragma unroll
        for (int i = 0; i < 4; ++i) {
            const int off = (wm + i * 16 + m16) * LDS_STRIDE + q * 8;
            ah[i] = *(const bf16x8*)&As_h[off];
            al[i] = *(const bf16x8*)&As_l[off];
        }
        #pragma unroll
        for (int j = 0; j < 4; ++j) {
            const int off = (wn + j * 16 + m16) * LDS_STRIDE + q * 8;
            bh[j] = *(const bf16x8*)&Bs_h[off];
            bl[j] = *(const bf16x8*)&Bs_l[off];
        }
        #pragma unroll
        for (int i = 0; i < 4; ++i)
            #pragma unroll
            for (int j = 0; j < 4; ++j) {
                acc[i][j] = __builtin_amdgcn_mfma_f32_16x16x32_bf16(ah[i], bh[j], acc[i][j], 0, 0, 0);
                acc[i][j] = __builtin_amdgcn_mfma_f32_16x16x32_bf16(ah[i], bl[j], acc[i][j], 0, 0, 0);
                acc[i][j] = __builtin_amdgcn_mfma_f32_16x16x32_bf16(al[i], bh[j], acc[i][j], 0, 0, 0);
            }
        __syncthreads();
    }

    #pragma unroll
    for (int i = 0; i < 4; ++i) {
        const int row_b = m0 + wm + i * 16 + q * 4;
        #pragma unroll
        for (int j = 0; j < 4; ++j) {
            const int col = n0 + wn + j * 16 + m16;
            const float bz = bias[col];
            #pragma unroll
            for (int rr = 0; rr < 4; ++rr) {
                const int row = row_b + rr;
                U[(size_t)row * 2048 + col] = silu_f(acc[i][j][rr] + bz);
            }
        }
    }
}

// ---------------------------------------------------------------------------
// dbc[p,0:96] = u[p,:] @ W_x  (K=2048, N=96). 8 rows/block.
// ---------------------------------------------------------------------------
__global__ __launch_bounds__(128) void dbc_kernel(
    const float* __restrict__ U, const float* __restrict__ W_x, float* __restrict__ DBC)
{
    const int p0 = blockIdx.x * 8;
    const int t  = threadIdx.x;
    __shared__ float us[8][256];
    float acc[8] = {};
    for (int k0 = 0; k0 < 2048; k0 += 256) {
        #pragma unroll
        for (int j = 0; j < 4; ++j) {
            const int lin = j * 512 + t * 4;
            const int r = lin >> 8, c = lin & 255;
            *(float4*)&us[r][c] = *(const float4*)&U[(size_t)(p0 + r) * 2048 + k0 + c];
        }
        __syncthreads();
        if (t < 96) {
            for (int k = 0; k < 256; ++k) {
                const float wv = W_x[(size_t)(k0 + k) * 96 + t];
                #pragma unroll
                for (int r = 0; r < 8; ++r) acc[r] += us[r][k] * wv;
            }
        }
        __syncthreads();
    }
    if (t < 96) {
        #pragma unroll
        for (int r = 0; r < 8; ++r) DBC[(size_t)(p0 + r) * 96 + t] = acc[r];
    }
}

// ---------------------------------------------------------------------------
// delta[p,d] = clip(softplus(dbc[p,0:64] @ W_dt[:,d] + b_dt[d]), 1e-3, 1e-1)
// ---------------------------------------------------------------------------
__global__ __launch_bounds__(256) void delta_kernel(
    const float* __restrict__ DBC, const float* __restrict__ W_dt,
    const float* __restrict__ b_dt, float* __restrict__ DELTA)
{
    const int n  = blockIdx.x * 256 + threadIdx.x;
    const int p0 = blockIdx.y * 16;
    const int t  = threadIdx.x;
    __shared__ float dt_s[16][64];
    #pragma unroll
    for (int j = 0; j < 4; ++j) {
        const int lin = j * 256 + t;
        const int r = lin >> 6, k = lin & 63;
        dt_s[r][k] = DBC[(size_t)(p0 + r) * 96 + k];
    }
    __syncthreads();
    float acc[16];
    const float bz = b_dt[n];
    #pragma unroll
    for (int r = 0; r < 16; ++r) acc[r] = bz;
    for (int k = 0; k < 64; ++k) {
        const float wv = W_dt[(size_t)k * 2048 + n];
        #pragma unroll
        for (int r = 0; r < 16; ++r) acc[r] += dt_s[r][k] * wv;
    }
    #pragma unroll
    for (int r = 0; r < 16; ++r) {
        float a = acc[r];
        float sp = (a > 20.f) ? a : log1pf(expf(a));
        sp = fminf(fmaxf(sp, 0.001f), 0.1f);
        DELTA[(size_t)(p0 + r) * 2048 + n] = sp;
    }
}

// ---------------------------------------------------------------------------
// Chunked scan (64 chunks of 32). off(c,n,b,d) = c*65536 + n*4096 + b*2048 + d
// ---------------------------------------------------------------------------
__global__ __launch_bounds__(256) void scan_p1(
    const float* __restrict__ DELTA, const float* __restrict__ U,
    const float* __restrict__ DBC, const float* __restrict__ A_log,
    float* __restrict__ HEND, float* __restrict__ APROD)
{
    const int t = threadIdx.x;
    const int d = blockIdx.x * 256 + t;
    const int c = blockIdx.y;
    const int b = blockIdx.z;
    const int p0 = b * 2048 + c * 32;
    __shared__ float Bs[32][16];
    for (int lin = t; lin < 512; lin += 256) {
        const int s = lin >> 4, n = lin & 15;
        Bs[s][n] = DBC[(size_t)(p0 + s) * 96 + 64 + n];
    }
    __syncthreads();
    float Af[16];
    *(float4*)&Af[0]  = *(const float4*)&A_log[(size_t)d * 16 + 0];
    *(float4*)&Af[4]  = *(const float4*)&A_log[(size_t)d * 16 + 4];
    *(float4*)&Af[8]  = *(const float4*)&A_log[(size_t)d * 16 + 8];
    *(float4*)&Af[12] = *(const float4*)&A_log[(size_t)d * 16 + 12];
    #pragma unroll
    for (int n = 0; n < 16; ++n) Af[n] = -__expf(Af[n]);

    float h[16] = {};
    float sd = 0.f;
    for (int s = 0; s < 32; ++s) {
        const float dv = DELTA[(size_t)(p0 + s) * 2048 + d];
        const float uv = U[(size_t)(p0 + s) * 2048 + d];
        const float du = dv * uv;
        sd += dv;
        #pragma unroll
        for (int n = 0; n < 16; ++n)
            h[n] = __expf(dv * Af[n]) * h[n] + du * Bs[s][n];
    }
    const size_t base = (size_t)c * 65536 + (size_t)b * 2048 + d;
    #pragma unroll
    for (int n = 0; n < 16; ++n) {
        HEND[base + (size_t)n * 4096]  = h[n];
        APROD[base + (size_t)n * 4096] = __expf(Af[n] * sd);
    }
}

__global__ __launch_bounds__(256) void scan_p2(
    const float* __restrict__ HEND, const float* __restrict__ APROD,
    float* __restrict__ HINIT)
{
    const int g = blockIdx.x * 256 + threadIdx.x;
    float h = 0.f;
    for (int c = 0; c < 64; ++c) {
        HINIT[(size_t)c * 65536 + g] = h;
        h = APROD[(size_t)c * 65536 + g] * h + HEND[(size_t)c * 65536 + g];
    }
}

__global__ __launch_bounds__(256) void scan_p3(
    const float* __restrict__ DELTA, const float* __restrict__ U,
    const float* __restrict__ DBC, const float* __restrict__ RES,
    const float* __restrict__ A_log, const float* __restrict__ Dp,
    const float* __restrict__ HINIT, float* __restrict__ G)
{
    const int t = threadIdx.x;
    const int d = blockIdx.x * 256 + t;
    const int c = blockIdx.y;
    const int b = blockIdx.z;
    const int p0 = b * 2048 + c * 32;
    __shared__ float Bs[32][16];
    __shared__ float Cs[32][16];
    for (int lin = t; lin < 512; lin += 256) {
        const int s = lin >> 4, n = lin & 15;
        Bs[s][n] = DBC[(size_t)(p0 + s) * 96 + 64 + n];
        Cs[s][n] = DBC[(size_t)(p0 + s) * 96 + 80 + n];
    }
    __syncthreads();
    float Af[16];
    *(float4*)&Af[0]  = *(const float4*)&A_log[(size_t)d * 16 + 0];
    *(float4*)&Af[4]  = *(const float4*)&A_log[(size_t)d * 16 + 4];
    *(float4*)&Af[8]  = *(const float4*)&A_log[(size_t)d * 16 + 8];
    *(float4*)&Af[12] = *(const float4*)&A_log[(size_t)d * 16 + 12];
    #pragma unroll
    for (int n = 0; n < 16; ++n) Af[n] = -__expf(Af[n]);

    const size_t base = (size_t)c * 65536 + (size_t)b * 2048 + d;
    float h[16];
    #pragma unroll
    for (int n = 0; n < 16; ++n) h[n] = HINIT[base + (size_t)n * 4096];
    const float Dd = Dp[d];

    for (int s = 0; s < 32; ++s) {
        const int p = p0 + s;
        const float dv = DELTA[(size_t)p * 2048 + d];
        const float uv = U[(size_t)p * 2048 + d];
        const float du = dv * uv;
        float y = 0.f;
        #pragma unroll
        for (int n = 0; n < 16; ++n) {
            h[n] = __expf(dv * Af[n]) * h[n] + du * Bs[s][n];
            y += h[n] * Cs[s][n];
        }
        const float resv = RES[(size_t)p * 2048 + d];
        G[(size_t)p * 2048 + d] = (y + uv * Dd) * silu_f(resv);
    }
}

// ---------------------------------------------------------------------------
extern "C" void kernel_launch(void* const* d_in, const int* in_sizes, int n_in,
                              void* d_out, int out_size, void* d_ws, size_t ws_size,
                              hipStream_t stream) {
    const float* x      = (const float*)d_in[0];
    const float* W_in   = (const float*)d_in[1];
    const float* conv_k = (const float*)d_in[2];
    const float* conv_b = (const float*)d_in[3];
    const float* W_x    = (const float*)d_in[4];
    const float* W_dt   = (const float*)d_in[5];
    const float* b_dt   = (const float*)d_in[6];
    const float* A_log  = (const float*)d_in[7];
    const float* Dv     = (const float*)d_in[8];
    const float* W_out  = (const float*)d_in[9];
    float* out = (float*)d_out;

    // Workspace layout (bytes). Total 219,725,824.
    char* base = (char*)d_ws;
    float*    RES   = (float*)(base);                   // 33,554,432 B
    float*    U     = (float*)(base + 33554432);        // 33,554,432
    float*    DBC   = (float*)(base + 67108864);        //  1,572,864
    float*    DELTA = (float*)(base + 68681728);        // 33,554,432 (-> G_h/G_l)
    char*     R1    = base + 102236160;                 // 33,554,432 (convkT -> HEND/APROD -> G)
    float*    HINIT = (float*)(base + 135790592);       // 16,777,216
    char*     R2    = base + 152567808;                 // 33,554,432 (x,WinT -> WoutT)
    ushort_t* XSP_h = (ushort_t*)(base + 186122240);    // 16,801,792 (2 x 2051 x 2048)
    ushort_t* XSP_l = (ushort_t*)(base + 202924032);    // 16,801,792

    ushort_t* convkT_h = (ushort_t*)R1;
    ushort_t* convkT_l = (ushort_t*)(R1 + 16777216);
    float*    HEND     = (float*)R1;
    float*    APROD    = (float*)(R1 + 16777216);
    float*    G        = (float*)R1;
    ushort_t* G_h      = (ushort_t*)DELTA;
    ushort_t* G_l      = (ushort_t*)((char*)DELTA + 16777216);
    ushort_t* x_h      = (ushort_t*)R2;
    ushort_t* x_l      = (ushort_t*)(R2 + 8388608);
    ushort_t* WinT_h   = (ushort_t*)(R2 + 16777216);
    ushort_t* WinT_l   = (ushort_t*)(R2 + 25165824);
    ushort_t* WoutT_h  = (ushort_t*)R2;                 // after xz gemm
    ushort_t* WoutT_l  = (ushort_t*)(R2 + 4194304);

    // Prep: splits/transposes
    split_rm<<<4096, 256, 0, stream>>>(x, x_h, x_l);                          // [4096][1024]
    split_tr<<<dim3(128, 32), 256, 0, stream>>>(W_in, 1024, 4096, WinT_h, WinT_l);
    split_tr<<<dim3(64, 128), 256, 0, stream>>>(conv_k, 4096, 2048, convkT_h, convkT_l);
    zero_pad<<<48, 256, 0, stream>>>(XSP_h, XSP_l);
    // 1) xz: xs half -> XSP bf16 hi/lo (+3-row causal pad), res half -> RES fp32
    gemm_sp<0><<<dim3(32, 32), 256, 0, stream>>>(x_h, x_l, WinT_h, WinT_l, 1024,
                                                 RES, XSP_h, XSP_l);
    split_tr<<<dim3(32, 64), 256, 0, stream>>>(W_out, 2048, 1024, WoutT_h, WoutT_l);
    // 2) u = silu(conv + b)
    conv_sp<<<dim3(16, 32), 256, 0, stream>>>(XSP_h, XSP_l, convkT_h, convkT_l, conv_b, U);
    // 3) dbc, 4) delta
    dbc_kernel<<<512, 128, 0, stream>>>(U, W_x, DBC);
    delta_kernel<<<dim3(8, 256), 256, 0, stream>>>(DBC, W_dt, b_dt, DELTA);
    // 5) chunked scan
    scan_p1<<<dim3(8, 64, 2), 256, 0, stream>>>(DELTA, U, DBC, A_log, HEND, APROD);
    scan_p2<<<256, 256, 0, stream>>>(HEND, APROD, HINIT);
    scan_p3<<<dim3(8, 64, 2), 256, 0, stream>>>(DELTA, U, DBC, RES, A_log, Dv, HINIT, G);
    // 6) out = G @ W_out
    split_rm<<<8192, 256, 0, stream>>>(G, G_h, G_l);
    gemm_sp<2><<<dim3(8, 32), 256, 0, stream>>>(G_h, G_l, WoutT_h, WoutT_l, 2048,
                                                out, nullptr, nullptr);
}

// Round 4
// 767.289 us; speedup vs baseline: 4.3700x; 1.2035x over previous
//
#include <hip/hip_runtime.h>
#include <math.h>

// B=2, L=2048, D_MODEL=1024, D_INNER=2048, D_STATE=16, DT_RANK=64, D_CONV=4
// P = B*L = 4096

typedef unsigned short ushort_t;
typedef __bf16 bf16x8 __attribute__((ext_vector_type(8)));
typedef float floatx4 __attribute__((ext_vector_type(4)));

#define LDS_STRIDE 40   // 32 + 8 pad: 80B rows, 16B aligned, 2-way-only conflicts

__device__ __forceinline__ float silu_f(float x) { return x / (1.0f + __expf(-x)); }

__device__ __forceinline__ unsigned short f2bf(float f) {
    unsigned u = __float_as_uint(f);
    unsigned r = u + 0x7fffu + ((u >> 16) & 1u);   // RNE (finite values only)
    return (unsigned short)(r >> 16);
}
__device__ __forceinline__ float bf2f(unsigned short h) {
    return __uint_as_float(((unsigned)h) << 16);
}

// ---------------------------------------------------------------------------
// fp32 -> bf16 hi/lo split, row-major (for x). 4 elems/thread.
// ---------------------------------------------------------------------------
__global__ __launch_bounds__(256) void split_rm(
    const float* __restrict__ in, ushort_t* __restrict__ oh, ushort_t* __restrict__ ol)
{
    const size_t i4 = ((size_t)blockIdx.x * 256 + threadIdx.x) * 4;
    float4 v = *(const float4*)&in[i4];
    unsigned short h0 = f2bf(v.x), h1 = f2bf(v.y), h2 = f2bf(v.z), h3 = f2bf(v.w);
    unsigned short l0 = f2bf(v.x - bf2f(h0)), l1 = f2bf(v.y - bf2f(h1));
    unsigned short l2 = f2bf(v.z - bf2f(h2)), l3 = f2bf(v.w - bf2f(h3));
    *(uint2*)&oh[i4] = make_uint2((unsigned)h0 | ((unsigned)h1 << 16),
                                  (unsigned)h2 | ((unsigned)h3 << 16));
    *(uint2*)&ol[i4] = make_uint2((unsigned)l0 | ((unsigned)l1 << 16),
                                  (unsigned)l2 | ((unsigned)l3 << 16));
}

// ---------------------------------------------------------------------------
// fp32 [R][C] -> bf16 hi/lo transposed [C][R] (for W_in, conv_k, W_out).
// ---------------------------------------------------------------------------
__global__ __launch_bounds__(256) void split_tr(
    const float* __restrict__ in, int R, int C,
    ushort_t* __restrict__ oh, ushort_t* __restrict__ ol)
{
    __shared__ float ts[32][33];
    const int t = threadIdx.x;
    const int tx = t & 31, ty = t >> 5;     // ty 0..7
    const int r0 = blockIdx.y * 32, c0 = blockIdx.x * 32;
    #pragma unroll
    for (int j = 0; j < 4; ++j)
        ts[ty + j * 8][tx] = in[(size_t)(r0 + ty + j * 8) * C + c0 + tx];
    __syncthreads();
    #pragma unroll
    for (int j = 0; j < 4; ++j) {
        float v = ts[tx][ty + j * 8];
        unsigned short h = f2bf(v);
        unsigned short l = f2bf(v - bf2f(h));
        const size_t a = (size_t)(c0 + ty + j * 8) * R + r0 + tx;
        oh[a] = h;
        ol[a] = l;
    }
}

// Zero the 3 causal-padding rows per batch of XSP (2 batches x 3 rows x 2048).
__global__ __launch_bounds__(256) void zero_pad(ushort_t* __restrict__ xh,
                                                ushort_t* __restrict__ xl)
{
    const int idx = blockIdx.x * 256 + threadIdx.x;   // < 12288
    const int b = idx / 6144, rem = idx % 6144;
    const int lp = rem >> 11, c = rem & 2047;
    const size_t a = ((size_t)b * 2051 + lp) * 2048 + c;
    xh[a] = 0; xl[a] = 0;
}

// W_x [2048][96] fp32 -> WxT hi/lo [128][2048] bf16 (rows 96..127 zero).
__global__ __launch_bounds__(256) void wx_prep(
    const float* __restrict__ W_x, ushort_t* __restrict__ oh, ushort_t* __restrict__ ol)
{
    const int idx = blockIdx.x * 256 + threadIdx.x;  // < 262144
    const int r = idx >> 11, k = idx & 2047;
    float v = (r < 96) ? W_x[(size_t)k * 96 + r] : 0.f;
    unsigned short h = f2bf(v);
    oh[idx] = h;
    ol[idx] = f2bf(v - bf2f(h));
}

// ---------------------------------------------------------------------------
// Split-bf16 MFMA GEMM: C = A @ B.  A as hi/lo [M][K] rm; B pre-transposed
// hi/lo [N][K].  128x128 tile, BK=32, 4 waves x (4x4) 16x16x32 MFMA tiles,
// 3 MFMAs per tile (AhBh + AhBl + AlBh) -> ~fp32 precision.
// MODE 0: xz epilogue — cols<2048: write bf16 hi/lo into XSP (+3 row pad);
//         cols>=2048: write fp32 res.   MODE 2: plain fp32 store (ldc=1024).
// ---------------------------------------------------------------------------
template<int MODE>
__global__ __launch_bounds__(256) void gemm_sp(
    const ushort_t* __restrict__ Ah, const ushort_t* __restrict__ Al,
    const ushort_t* __restrict__ Bh, const ushort_t* __restrict__ Bl,
    int K, float* __restrict__ Cf, ushort_t* __restrict__ Oh, ushort_t* __restrict__ Ol)
{
    __shared__ __align__(16) ushort_t As_h[128 * LDS_STRIDE];
    __shared__ __align__(16) ushort_t As_l[128 * LDS_STRIDE];
    __shared__ __align__(16) ushort_t Bs_h[128 * LDS_STRIDE];
    __shared__ __align__(16) ushort_t Bs_l[128 * LDS_STRIDE];
    const int t = threadIdx.x;
    const int m0 = blockIdx.y * 128, n0 = blockIdx.x * 128;
    const int lane = t & 63, wave = t >> 6;
    const int wm = (wave >> 1) * 64, wn = (wave & 1) * 64;
    const int m16 = lane & 15, q = lane >> 4;
    const int r_0 = t >> 2, cc_0 = (t & 3) * 8;            // chunk t
    const int r_1 = (t + 256) >> 2, cc_1 = ((t + 256) & 3) * 8;

    uint4 pa0h = *(const uint4*)&Ah[(size_t)(m0 + r_0) * K + cc_0];
    uint4 pa1h = *(const uint4*)&Ah[(size_t)(m0 + r_1) * K + cc_1];
    uint4 pa0l = *(const uint4*)&Al[(size_t)(m0 + r_0) * K + cc_0];
    uint4 pa1l = *(const uint4*)&Al[(size_t)(m0 + r_1) * K + cc_1];
    uint4 pb0h = *(const uint4*)&Bh[(size_t)(n0 + r_0) * K + cc_0];
    uint4 pb1h = *(const uint4*)&Bh[(size_t)(n0 + r_1) * K + cc_1];
    uint4 pb0l = *(const uint4*)&Bl[(size_t)(n0 + r_0) * K + cc_0];
    uint4 pb1l = *(const uint4*)&Bl[(size_t)(n0 + r_1) * K + cc_1];

    floatx4 acc[4][4];
    const floatx4 zz = {0.f, 0.f, 0.f, 0.f};
    #pragma unroll
    for (int i = 0; i < 4; ++i)
        #pragma unroll
        for (int j = 0; j < 4; ++j) acc[i][j] = zz;

    for (int k0 = 0; k0 < K; k0 += 32) {
        *(uint4*)&As_h[r_0 * LDS_STRIDE + cc_0] = pa0h;
        *(uint4*)&As_h[r_1 * LDS_STRIDE + cc_1] = pa1h;
        *(uint4*)&As_l[r_0 * LDS_STRIDE + cc_0] = pa0l;
        *(uint4*)&As_l[r_1 * LDS_STRIDE + cc_1] = pa1l;
        *(uint4*)&Bs_h[r_0 * LDS_STRIDE + cc_0] = pb0h;
        *(uint4*)&Bs_h[r_1 * LDS_STRIDE + cc_1] = pb1h;
        *(uint4*)&Bs_l[r_0 * LDS_STRIDE + cc_0] = pb0l;
        *(uint4*)&Bs_l[r_1 * LDS_STRIDE + cc_1] = pb1l;
        __syncthreads();
        if (k0 + 32 < K) {
            const int kn = k0 + 32;
            pa0h = *(const uint4*)&Ah[(size_t)(m0 + r_0) * K + kn + cc_0];
            pa1h = *(const uint4*)&Ah[(size_t)(m0 + r_1) * K + kn + cc_1];
            pa0l = *(const uint4*)&Al[(size_t)(m0 + r_0) * K + kn + cc_0];
            pa1l = *(const uint4*)&Al[(size_t)(m0 + r_1) * K + kn + cc_1];
            pb0h = *(const uint4*)&Bh[(size_t)(n0 + r_0) * K + kn + cc_0];
            pb1h = *(const uint4*)&Bh[(size_t)(n0 + r_1) * K + kn + cc_1];
            pb0l = *(const uint4*)&Bl[(size_t)(n0 + r_0) * K + kn + cc_0];
            pb1l = *(const uint4*)&Bl[(size_t)(n0 + r_1) * K + kn + cc_1];
        }
        bf16x8 ah[4], al[4], bh[4], bl[4];
        #pragma unroll
        for (int i = 0; i < 4; ++i) {
            const int off = (wm + i * 16 + m16) * LDS_STRIDE + q * 8;
            ah[i] = *(const bf16x8*)&As_h[off];
            al[i] = *(const bf16x8*)&As_l[off];
        }
        #pragma unroll
        for (int j = 0; j < 4; ++j) {
            const int off = (wn + j * 16 + m16) * LDS_STRIDE + q * 8;
            bh[j] = *(const bf16x8*)&Bs_h[off];
            bl[j] = *(const bf16x8*)&Bs_l[off];
        }
        #pragma unroll
        for (int i = 0; i < 4; ++i)
            #pragma unroll
            for (int j = 0; j < 4; ++j) {
                acc[i][j] = __builtin_amdgcn_mfma_f32_16x16x32_bf16(ah[i], bh[j], acc[i][j], 0, 0, 0);
                acc[i][j] = __builtin_amdgcn_mfma_f32_16x16x32_bf16(ah[i], bl[j], acc[i][j], 0, 0, 0);
                acc[i][j] = __builtin_amdgcn_mfma_f32_16x16x32_bf16(al[i], bh[j], acc[i][j], 0, 0, 0);
            }
        __syncthreads();
    }

    #pragma unroll
    for (int i = 0; i < 4; ++i) {
        const int row_b = m0 + wm + i * 16 + q * 4;
        #pragma unroll
        for (int j = 0; j < 4; ++j) {
            const int col = n0 + wn + j * 16 + m16;
            #pragma unroll
            for (int rr = 0; rr < 4; ++rr) {
                const int row = row_b + rr;
                const float v = acc[i][j][rr];
                if (MODE == 0) {
                    if (n0 < 2048) {
                        const int b = row >> 11, l = row & 2047;
                        const size_t a = ((size_t)b * 2051 + l + 3) * 2048 + col;
                        const unsigned short h = f2bf(v);
                        Oh[a] = h;
                        Ol[a] = f2bf(v - bf2f(h));
                    } else {
                        Cf[(size_t)row * 2048 + (col - 2048)] = v;
                    }
                } else {
                    Cf[(size_t)row * 1024 + col] = v;
                }
            }
        }
    }
}

// ---------------------------------------------------------------------------
// dbc = U @ W_x via split-bf16 MFMA. A = U hi/lo [4096][2048]; B = WxT hi/lo
// [128][2048] (rows 96..127 zero). Single N-tile; store cols < 96 fp32.
// ---------------------------------------------------------------------------
__global__ __launch_bounds__(256) void gemm_dbc(
    const ushort_t* __restrict__ Ah, const ushort_t* __restrict__ Al,
    const ushort_t* __restrict__ Bh, const ushort_t* __restrict__ Bl,
    float* __restrict__ DBC)
{
    __shared__ __align__(16) ushort_t As_h[128 * LDS_STRIDE];
    __shared__ __align__(16) ushort_t As_l[128 * LDS_STRIDE];
    __shared__ __align__(16) ushort_t Bs_h[128 * LDS_STRIDE];
    __shared__ __align__(16) ushort_t Bs_l[128 * LDS_STRIDE];
    const int t = threadIdx.x;
    const int m0 = blockIdx.y * 128;
    const int lane = t & 63, wave = t >> 6;
    const int wm = (wave >> 1) * 64, wn = (wave & 1) * 64;
    const int m16 = lane & 15, q = lane >> 4;
    const int r_0 = t >> 2, cc_0 = (t & 3) * 8;
    const int r_1 = (t + 256) >> 2, cc_1 = ((t + 256) & 3) * 8;
    const int K = 2048;

    uint4 pa0h = *(const uint4*)&Ah[(size_t)(m0 + r_0) * K + cc_0];
    uint4 pa1h = *(const uint4*)&Ah[(size_t)(m0 + r_1) * K + cc_1];
    uint4 pa0l = *(const uint4*)&Al[(size_t)(m0 + r_0) * K + cc_0];
    uint4 pa1l = *(const uint4*)&Al[(size_t)(m0 + r_1) * K + cc_1];
    uint4 pb0h = *(const uint4*)&Bh[(size_t)r_0 * K + cc_0];
    uint4 pb1h = *(const uint4*)&Bh[(size_t)r_1 * K + cc_1];
    uint4 pb0l = *(const uint4*)&Bl[(size_t)r_0 * K + cc_0];
    uint4 pb1l = *(const uint4*)&Bl[(size_t)r_1 * K + cc_1];

    floatx4 acc[4][4];
    const floatx4 zz = {0.f, 0.f, 0.f, 0.f};
    #pragma unroll
    for (int i = 0; i < 4; ++i)
        #pragma unroll
        for (int j = 0; j < 4; ++j) acc[i][j] = zz;

    for (int k0 = 0; k0 < K; k0 += 32) {
        *(uint4*)&As_h[r_0 * LDS_STRIDE + cc_0] = pa0h;
        *(uint4*)&As_h[r_1 * LDS_STRIDE + cc_1] = pa1h;
        *(uint4*)&As_l[r_0 * LDS_STRIDE + cc_0] = pa0l;
        *(uint4*)&As_l[r_1 * LDS_STRIDE + cc_1] = pa1l;
        *(uint4*)&Bs_h[r_0 * LDS_STRIDE + cc_0] = pb0h;
        *(uint4*)&Bs_h[r_1 * LDS_STRIDE + cc_1] = pb1h;
        *(uint4*)&Bs_l[r_0 * LDS_STRIDE + cc_0] = pb0l;
        *(uint4*)&Bs_l[r_1 * LDS_STRIDE + cc_1] = pb1l;
        __syncthreads();
        if (k0 + 32 < K) {
            const int kn = k0 + 32;
            pa0h = *(const uint4*)&Ah[(size_t)(m0 + r_0) * K + kn + cc_0];
            pa1h = *(const uint4*)&Ah[(size_t)(m0 + r_1) * K + kn + cc_1];
            pa0l = *(const uint4*)&Al[(size_t)(m0 + r_0) * K + kn + cc_0];
            pa1l = *(const uint4*)&Al[(size_t)(m0 + r_1) * K + kn + cc_1];
            pb0h = *(const uint4*)&Bh[(size_t)r_0 * K + kn + cc_0];
            pb1h = *(const uint4*)&Bh[(size_t)r_1 * K + kn + cc_1];
            pb0l = *(const uint4*)&Bl[(size_t)r_0 * K + kn + cc_0];
            pb1l = *(const uint4*)&Bl[(size_t)r_1 * K + kn + cc_1];
        }
        bf16x8 ah[4], al[4], bh[4], bl[4];
        #pragma unroll
        for (int i = 0; i < 4; ++i) {
            const int off = (wm + i * 16 + m16) * LDS_STRIDE + q * 8;
            ah[i] = *(const bf16x8*)&As_h[off];
            al[i] = *(const bf16x8*)&As_l[off];
        }
        #pragma unroll
        for (int j = 0; j < 4; ++j) {
            const int off = (wn + j * 16 + m16) * LDS_STRIDE + q * 8;
            bh[j] = *(const bf16x8*)&Bs_h[off];
            bl[j] = *(const bf16x8*)&Bs_l[off];
        }
        #pragma unroll
        for (int i = 0; i < 4; ++i)
            #pragma unroll
            for (int j = 0; j < 4; ++j) {
                acc[i][j] = __builtin_amdgcn_mfma_f32_16x16x32_bf16(ah[i], bh[j], acc[i][j], 0, 0, 0);
                acc[i][j] = __builtin_amdgcn_mfma_f32_16x16x32_bf16(ah[i], bl[j], acc[i][j], 0, 0, 0);
                acc[i][j] = __builtin_amdgcn_mfma_f32_16x16x32_bf16(al[i], bh[j], acc[i][j], 0, 0, 0);
            }
        __syncthreads();
    }

    #pragma unroll
    for (int i = 0; i < 4; ++i) {
        const int row_b = m0 + wm + i * 16 + q * 4;
        #pragma unroll
        for (int j = 0; j < 4; ++j) {
            const int col = wn + j * 16 + m16;
            if (col < 96) {
                #pragma unroll
                for (int rr = 0; rr < 4; ++rr)
                    DBC[(size_t)(row_b + rr) * 96 + col] = acc[i][j][rr];
            }
        }
    }
}

// ---------------------------------------------------------------------------
// Conv as split-bf16 MFMA GEMM. A[p][k=w*1024+i] = XSP[b][l+w][g*1024+i]
// (XSP zero-padded by 3 rows per batch). B = conv_k^T hi/lo [2048][4096].
// Epilogue: U = silu(acc + conv_b), written fp32 + bf16 hi/lo (for dbc GEMM).
// ---------------------------------------------------------------------------
__global__ __launch_bounds__(256) void conv_sp(
    const ushort_t* __restrict__ Xh, const ushort_t* __restrict__ Xl,
    const ushort_t* __restrict__ Bh, const ushort_t* __restrict__ Bl,
    const float* __restrict__ bias, float* __restrict__ U,
    ushort_t* __restrict__ Uh, ushort_t* __restrict__ Ul)
{
    __shared__ __align__(16) ushort_t As_h[128 * LDS_STRIDE];
    __shared__ __align__(16) ushort_t As_l[128 * LDS_STRIDE];
    __shared__ __align__(16) ushort_t Bs_h[128 * LDS_STRIDE];
    __shared__ __align__(16) ushort_t Bs_l[128 * LDS_STRIDE];
    const int t = threadIdx.x;
    const int m0 = blockIdx.y * 128, n0 = blockIdx.x * 128;
    const int g1024 = (n0 >= 1024) ? 1024 : 0;
    const int lane = t & 63, wave = t >> 6;
    const int wm = (wave >> 1) * 64, wn = (wave & 1) * 64;
    const int m16 = lane & 15, q = lane >> 4;
    const int r_0 = t >> 2, cc_0 = (t & 3) * 8;
    const int r_1 = (t + 256) >> 2, cc_1 = ((t + 256) & 3) * 8;
    const int p_0 = m0 + r_0, b_0 = p_0 >> 11, l_0 = p_0 & 2047;
    const int p_1 = m0 + r_1, b_1 = p_1 >> 11, l_1 = p_1 & 2047;

    auto aA = [&](int bb, int ll, int k0, int cc) -> size_t {
        const int w = k0 >> 10;
        const int i = (k0 & 1023) + cc;
        return ((size_t)bb * 2051 + ll + w) * 2048 + g1024 + i;
    };

    uint4 pa0h = *(const uint4*)&Xh[aA(b_0, l_0, 0, cc_0)];
    uint4 pa1h = *(const uint4*)&Xh[aA(b_1, l_1, 0, cc_1)];
    uint4 pa0l = *(const uint4*)&Xl[aA(b_0, l_0, 0, cc_0)];
    uint4 pa1l = *(const uint4*)&Xl[aA(b_1, l_1, 0, cc_1)];
    uint4 pb0h = *(const uint4*)&Bh[(size_t)(n0 + r_0) * 4096 + cc_0];
    uint4 pb1h = *(const uint4*)&Bh[(size_t)(n0 + r_1) * 4096 + cc_1];
    uint4 pb0l = *(const uint4*)&Bl[(size_t)(n0 + r_0) * 4096 + cc_0];
    uint4 pb1l = *(const uint4*)&Bl[(size_t)(n0 + r_1) * 4096 + cc_1];

    floatx4 acc[4][4];
    const floatx4 zz = {0.f, 0.f, 0.f, 0.f};
    #pragma unroll
    for (int i = 0; i < 4; ++i)
        #pragma unroll
        for (int j = 0; j < 4; ++j) acc[i][j] = zz;

    for (int k0 = 0; k0 < 4096; k0 += 32) {
        *(uint4*)&As_h[r_0 * LDS_STRIDE + cc_0] = pa0h;
        *(uint4*)&As_h[r_1 * LDS_STRIDE + cc_1] = pa1h;
        *(uint4*)&As_l[r_0 * LDS_STRIDE + cc_0] = pa0l;
        *(uint4*)&As_l[r_1 * LDS_STRIDE + cc_1] = pa1l;
        *(uint4*)&Bs_h[r_0 * LDS_STRIDE + cc_0] = pb0h;
        *(uint4*)&Bs_h[r_1 * LDS_STRIDE + cc_1] = pb1h;
        *(uint4*)&Bs_l[r_0 * LDS_STRIDE + cc_0] = pb0l;
        *(uint4*)&Bs_l[r_1 * LDS_STRIDE + cc_1] = pb1l;
        __syncthreads();
        if (k0 + 32 < 4096) {
            const int kn = k0 + 32;
            pa0h = *(const uint4*)&Xh[aA(b_0, l_0, kn, cc_0)];
            pa1h = *(const uint4*)&Xh[aA(b_1, l_1, kn, cc_1)];
            pa0l = *(const uint4*)&Xl[aA(b_0, l_0, kn, cc_0)];
            pa1l = *(const uint4*)&Xl[aA(b_1, l_1, kn, cc_1)];
            pb0h = *(const uint4*)&Bh[(size_t)(n0 + r_0) * 4096 + kn + cc_0];
            pb1h = *(const uint4*)&Bh[(size_t)(n0 + r_1) * 4096 + kn + cc_1];
            pb0l = *(const uint4*)&Bl[(size_t)(n0 + r_0) * 4096 + kn + cc_0];
            pb1l = *(const uint4*)&Bl[(size_t)(n0 + r_1) * 4096 + kn + cc_1];
        }
        bf16x8 ah[4], al[4], bh[4], bl[4];
        #pragma unroll
        for (int i = 0; i < 4; ++i) {
            const int off = (wm + i * 16 + m16) * LDS_STRIDE + q * 8;
            ah[i] = *(const bf16x8*)&As_h[off];
            al[i] = *(const bf16x8*)&As_l[off];
        }
        #pragma unroll
        for (int j = 0; j < 4; ++j) {
            const int off = (wn + j * 16 + m16) * LDS_STRIDE + q * 8;
            bh[j] = *(const bf16x8*)&Bs_h[off];
            bl[j] = *(const bf16x8*)&Bs_l[off];
        }
        #pragma unroll
        for (int i = 0; i < 4; ++i)
            #pragma unroll
            for (int j = 0; j < 4; ++j) {
                acc[i][j] = __builtin_amdgcn_mfma_f32_16x16x32_bf16(ah[i], bh[j], acc[i][j], 0, 0, 0);
                acc[i][j] = __builtin_amdgcn_mfma_f32_16x16x32_bf16(ah[i], bl[j], acc[i][j], 0, 0, 0);
                acc[i][j] = __builtin_amdgcn_mfma_f32_16x16x32_bf16(al[i], bh[j], acc[i][j], 0, 0, 0);
            }
        __syncthreads();
    }

    #pragma unroll
    for (int i = 0; i < 4; ++i) {
        const int row_b = m0 + wm + i * 16 + q * 4;
        #pragma unroll
        for (int j = 0; j < 4; ++j) {
            const int col = n0 + wn + j * 16 + m16;
            const float bz = bias[col];
            #pragma unroll
            for (int rr = 0; rr < 4; ++rr) {
                const int row = row_b + rr;
                const float v = silu_f(acc[i][j][rr] + bz);
                const size_t a = (size_t)row * 2048 + col;
                U[a] = v;
                const unsigned short h = f2bf(v);
                Uh[a] = h;
                Ul[a] = f2bf(v - bf2f(h));
            }
        }
    }
}

// ---------------------------------------------------------------------------
// delta[p,d] = clip(softplus(dbc[p,0:64] @ W_dt[:,d] + b_dt[d]), 1e-3, 1e-1)
// ---------------------------------------------------------------------------
__global__ __launch_bounds__(256) void delta_kernel(
    const float* __restrict__ DBC, const float* __restrict__ W_dt,
    const float* __restrict__ b_dt, float* __restrict__ DELTA)
{
    const int n  = blockIdx.x * 256 + threadIdx.x;
    const int p0 = blockIdx.y * 16;
    const int t  = threadIdx.x;
    __shared__ float dt_s[16][64];
    #pragma unroll
    for (int j = 0; j < 4; ++j) {
        const int lin = j * 256 + t;
        const int r = lin >> 6, k = lin & 63;
        dt_s[r][k] = DBC[(size_t)(p0 + r) * 96 + k];
    }
    __syncthreads();
    float acc[16];
    const float bz = b_dt[n];
    #pragma unroll
    for (int r = 0; r < 16; ++r) acc[r] = bz;
    for (int k = 0; k < 64; ++k) {
        const float wv = W_dt[(size_t)k * 2048 + n];
        #pragma unroll
        for (int r = 0; r < 16; ++r) acc[r] += dt_s[r][k] * wv;
    }
    #pragma unroll
    for (int r = 0; r < 16; ++r) {
        float a = acc[r];
        float sp = (a > 20.f) ? a : log1pf(expf(a));
        sp = fminf(fmaxf(sp, 0.001f), 0.1f);
        DELTA[(size_t)(p0 + r) * 2048 + n] = sp;
    }
}

// ---------------------------------------------------------------------------
// Chunked scan (64 chunks of 32). off(c,n,b,d) = c*65536 + n*4096 + b*2048 + d
// ---------------------------------------------------------------------------
__global__ __launch_bounds__(256) void scan_p1(
    const float* __restrict__ DELTA, const float* __restrict__ U,
    const float* __restrict__ DBC, const float* __restrict__ A_log,
    float* __restrict__ HEND, float* __restrict__ APROD)
{
    const int t = threadIdx.x;
    const int d = blockIdx.x * 256 + t;
    const int c = blockIdx.y;
    const int b = blockIdx.z;
    const int p0 = b * 2048 + c * 32;
    __shared__ float Bs[32][16];
    for (int lin = t; lin < 512; lin += 256) {
        const int s = lin >> 4, n = lin & 15;
        Bs[s][n] = DBC[(size_t)(p0 + s) * 96 + 64 + n];
    }
    __syncthreads();
    float Af[16];
    *(float4*)&Af[0]  = *(const float4*)&A_log[(size_t)d * 16 + 0];
    *(float4*)&Af[4]  = *(const float4*)&A_log[(size_t)d * 16 + 4];
    *(float4*)&Af[8]  = *(const float4*)&A_log[(size_t)d * 16 + 8];
    *(float4*)&Af[12] = *(const float4*)&A_log[(size_t)d * 16 + 12];
    #pragma unroll
    for (int n = 0; n < 16; ++n) Af[n] = -__expf(Af[n]);

    float h[16] = {};
    float sd = 0.f;
    for (int s = 0; s < 32; ++s) {
        const float dv = DELTA[(size_t)(p0 + s) * 2048 + d];
        const float uv = U[(size_t)(p0 + s) * 2048 + d];
        const float du = dv * uv;
        sd += dv;
        #pragma unroll
        for (int n = 0; n < 16; ++n)
            h[n] = __expf(dv * Af[n]) * h[n] + du * Bs[s][n];
    }
    const size_t base = (size_t)c * 65536 + (size_t)b * 2048 + d;
    #pragma unroll
    for (int n = 0; n < 16; ++n) {
        HEND[base + (size_t)n * 4096]  = h[n];
        APROD[base + (size_t)n * 4096] = __expf(Af[n] * sd);
    }
}

__global__ __launch_bounds__(256) void scan_p2(
    const float* __restrict__ HEND, const float* __restrict__ APROD,
    float* __restrict__ HINIT)
{
    const int g = blockIdx.x * 256 + threadIdx.x;
    float h = 0.f;
    for (int c = 0; c < 64; ++c) {
        HINIT[(size_t)c * 65536 + g] = h;
        h = APROD[(size_t)c * 65536 + g] * h + HEND[(size_t)c * 65536 + g];
    }
}

// Pass 3: re-scan from h_init, y, gate; emit G directly as bf16 hi/lo.
__global__ __launch_bounds__(256) void scan_p3(
    const float* __restrict__ DELTA, const float* __restrict__ U,
    const float* __restrict__ DBC, const float* __restrict__ RES,
    const float* __restrict__ A_log, const float* __restrict__ Dp,
    const float* __restrict__ HINIT,
    ushort_t* __restrict__ Gh, ushort_t* __restrict__ Gl)
{
    const int t = threadIdx.x;
    const int d = blockIdx.x * 256 + t;
    const int c = blockIdx.y;
    const int b = blockIdx.z;
    const int p0 = b * 2048 + c * 32;
    __shared__ float Bs[32][16];
    __shared__ float Cs[32][16];
    for (int lin = t; lin < 512; lin += 256) {
        const int s = lin >> 4, n = lin & 15;
        Bs[s][n] = DBC[(size_t)(p0 + s) * 96 + 64 + n];
        Cs[s][n] = DBC[(size_t)(p0 + s) * 96 + 80 + n];
    }
    __syncthreads();
    float Af[16];
    *(float4*)&Af[0]  = *(const float4*)&A_log[(size_t)d * 16 + 0];
    *(float4*)&Af[4]  = *(const float4*)&A_log[(size_t)d * 16 + 4];
    *(float4*)&Af[8]  = *(const float4*)&A_log[(size_t)d * 16 + 8];
    *(float4*)&Af[12] = *(const float4*)&A_log[(size_t)d * 16 + 12];
    #pragma unroll
    for (int n = 0; n < 16; ++n) Af[n] = -__expf(Af[n]);

    const size_t base = (size_t)c * 65536 + (size_t)b * 2048 + d;
    float h[16];
    #pragma unroll
    for (int n = 0; n < 16; ++n) h[n] = HINIT[base + (size_t)n * 4096];
    const float Dd = Dp[d];

    for (int s = 0; s < 32; ++s) {
        const int p = p0 + s;
        const float dv = DELTA[(size_t)p * 2048 + d];
        const float uv = U[(size_t)p * 2048 + d];
        const float du = dv * uv;
        float y = 0.f;
        #pragma unroll
        for (int n = 0; n < 16; ++n) {
            h[n] = __expf(dv * Af[n]) * h[n] + du * Bs[s][n];
            y += h[n] * Cs[s][n];
        }
        const float resv = RES[(size_t)p * 2048 + d];
        const float gv = (y + uv * Dd) * silu_f(resv);
        const unsigned short gh = f2bf(gv);
        Gh[(size_t)p * 2048 + d] = gh;
        Gl[(size_t)p * 2048 + d] = f2bf(gv - bf2f(gh));
    }
}

// ---------------------------------------------------------------------------
extern "C" void kernel_launch(void* const* d_in, const int* in_sizes, int n_in,
                              void* d_out, int out_size, void* d_ws, size_t ws_size,
                              hipStream_t stream) {
    const float* x      = (const float*)d_in[0];
    const float* W_in   = (const float*)d_in[1];
    const float* conv_k = (const float*)d_in[2];
    const float* conv_b = (const float*)d_in[3];
    const float* W_x    = (const float*)d_in[4];
    const float* W_dt   = (const float*)d_in[5];
    const float* b_dt   = (const float*)d_in[6];
    const float* A_log  = (const float*)d_in[7];
    const float* Dv     = (const float*)d_in[8];
    const float* W_out  = (const float*)d_in[9];
    float* out = (float*)d_out;

    // Workspace layout (bytes). Total 219,725,824 (same as round 3).
    char* base = (char*)d_ws;
    float*    RES   = (float*)(base);                   // 33,554,432 B
    float*    U     = (float*)(base + 33554432);        // 33,554,432
    float*    DBC   = (float*)(base + 67108864);        //  1,572,864
    char*     DREG  = base + 68681728;                  // 33,554,432 (Uh/Ul -> DELTA)
    char*     R1    = base + 102236160;                 // 33,554,432 (convkT -> HEND/APROD -> G_h/G_l)
    char*     HREG  = base + 135790592;                 // 16,777,216 (WxT -> HINIT)
    char*     R2    = base + 152567808;                 // 33,554,432 (x,WinT -> WoutT)
    ushort_t* XSP_h = (ushort_t*)(base + 186122240);    // 16,801,792 (2 x 2051 x 2048)
    ushort_t* XSP_l = (ushort_t*)(base + 202924032);    // 16,801,792

    ushort_t* Uh       = (ushort_t*)DREG;               // dead after gemm_dbc
    ushort_t* Ul       = (ushort_t*)(DREG + 16777216);
    float*    DELTA    = (float*)DREG;                  // written after gemm_dbc
    ushort_t* convkT_h = (ushort_t*)R1;
    ushort_t* convkT_l = (ushort_t*)(R1 + 16777216);
    float*    HEND     = (float*)R1;
    float*    APROD    = (float*)(R1 + 16777216);
    ushort_t* G_h      = (ushort_t*)R1;                 // after scan_p2
    ushort_t* G_l      = (ushort_t*)(R1 + 16777216);
    ushort_t* WxT_h    = (ushort_t*)HREG;               // dead after gemm_dbc
    ushort_t* WxT_l    = (ushort_t*)(HREG + 524288);
    float*    HINIT    = (float*)HREG;                  // written in scan_p2
    ushort_t* x_h      = (ushort_t*)R2;
    ushort_t* x_l      = (ushort_t*)(R2 + 8388608);
    ushort_t* WinT_h   = (ushort_t*)(R2 + 16777216);
    ushort_t* WinT_l   = (ushort_t*)(R2 + 25165824);
    ushort_t* WoutT_h  = (ushort_t*)R2;                 // after xz gemm
    ushort_t* WoutT_l  = (ushort_t*)(R2 + 4194304);

    // Prep: splits/transposes
    split_rm<<<4096, 256, 0, stream>>>(x, x_h, x_l);                          // [4096][1024]
    split_tr<<<dim3(128, 32), 256, 0, stream>>>(W_in, 1024, 4096, WinT_h, WinT_l);
    split_tr<<<dim3(64, 128), 256, 0, stream>>>(conv_k, 4096, 2048, convkT_h, convkT_l);
    zero_pad<<<48, 256, 0, stream>>>(XSP_h, XSP_l);
    wx_prep<<<1024, 256, 0, stream>>>(W_x, WxT_h, WxT_l);
    // 1) xz: xs half -> XSP bf16 hi/lo (+3-row causal pad), res half -> RES fp32
    gemm_sp<0><<<dim3(32, 32), 256, 0, stream>>>(x_h, x_l, WinT_h, WinT_l, 1024,
                                                 RES, XSP_h, XSP_l);
    split_tr<<<dim3(32, 64), 256, 0, stream>>>(W_out, 2048, 1024, WoutT_h, WoutT_l);
    // 2) u = silu(conv + b) -> fp32 U + bf16 hi/lo Uh/Ul
    conv_sp<<<dim3(16, 32), 256, 0, stream>>>(XSP_h, XSP_l, convkT_h, convkT_l,
                                              conv_b, U, Uh, Ul);
    // 3) dbc = U @ W_x (MFMA split)
    gemm_dbc<<<dim3(1, 32), 256, 0, stream>>>(Uh, Ul, WxT_h, WxT_l, DBC);
    // 4) delta (overwrites Uh/Ul region)
    delta_kernel<<<dim3(8, 256), 256, 0, stream>>>(DBC, W_dt, b_dt, DELTA);
    // 5) chunked scan
    scan_p1<<<dim3(8, 64, 2), 256, 0, stream>>>(DELTA, U, DBC, A_log, HEND, APROD);
    scan_p2<<<256, 256, 0, stream>>>(HEND, APROD, HINIT);
    scan_p3<<<dim3(8, 64, 2), 256, 0, stream>>>(DELTA, U, DBC, RES, A_log, Dv,
                                                HINIT, G_h, G_l);
    // 6) out = G @ W_out
    gemm_sp<2><<<dim3(8, 32), 256, 0, stream>>>(G_h, G_l, WoutT_h, WoutT_l, 2048,
                                                out, nullptr, nullptr);
}

// Round 5
// 583.120 us; speedup vs baseline: 5.7502x; 1.3158x over previous
//
#include <hip/hip_runtime.h>
#include <math.h>

// B=2, L=2048, D_MODEL=1024, D_INNER=2048, D_STATE=16, DT_RANK=64, D_CONV=4
// P = B*L = 4096

typedef unsigned short ushort_t;
typedef __bf16 bf16x8 __attribute__((ext_vector_type(8)));
typedef float floatx4 __attribute__((ext_vector_type(4)));

#define LDS_STRIDE 40   // 32 + 8 pad: 80B rows, 16B aligned, 2-way-only conflicts

__device__ __forceinline__ float silu_f(float x) { return x / (1.0f + __expf(-x)); }

__device__ __forceinline__ unsigned short f2bf(float f) {
    unsigned u = __float_as_uint(f);
    unsigned r = u + 0x7fffu + ((u >> 16) & 1u);   // RNE (finite values only)
    return (unsigned short)(r >> 16);
}
__device__ __forceinline__ float bf2f(unsigned short h) {
    return __uint_as_float(((unsigned)h) << 16);
}

// ---------------------------------------------------------------------------
// One mega prep kernel (block-range switch):
//  [0,4096)      : x fp32 -> x_h/x_l split (row-major)
//  [4096,8192)   : W_in   [1024][4096] -> WinT_h  [4096][1024] (hi only)
//  [8192,16384)  : conv_k [4096][2048] -> convkT_h[2048][4096] (hi only)
//  [16384,18432) : W_out  [2048][1024] -> WoutT_h [1024][2048] (hi only)
//  [18432,19456) : W_x    [2048][96]   -> WxT_h   [128][2048]  (pad rows 96..127)
//  [19456,19504) : zero XSP causal pad rows
// ---------------------------------------------------------------------------
__global__ __launch_bounds__(256) void prep_all(
    const float* __restrict__ x, const float* __restrict__ W_in,
    const float* __restrict__ conv_k, const float* __restrict__ W_out,
    const float* __restrict__ W_x,
    ushort_t* __restrict__ x_h, ushort_t* __restrict__ x_l,
    ushort_t* __restrict__ WinT_h, ushort_t* __restrict__ convkT_h,
    ushort_t* __restrict__ WoutT_h, ushort_t* __restrict__ WxT_h,
    ushort_t* __restrict__ XSP_h, ushort_t* __restrict__ XSP_l)
{
    __shared__ float ts[32][33];
    const int bid = blockIdx.x;
    const int t = threadIdx.x;
    if (bid < 4096) {
        const size_t i4 = ((size_t)bid * 256 + t) * 4;
        float4 v = *(const float4*)&x[i4];
        unsigned short h0 = f2bf(v.x), h1 = f2bf(v.y), h2 = f2bf(v.z), h3 = f2bf(v.w);
        unsigned short l0 = f2bf(v.x - bf2f(h0)), l1 = f2bf(v.y - bf2f(h1));
        unsigned short l2 = f2bf(v.z - bf2f(h2)), l3 = f2bf(v.w - bf2f(h3));
        *(uint2*)&x_h[i4] = make_uint2((unsigned)h0 | ((unsigned)h1 << 16),
                                       (unsigned)h2 | ((unsigned)h3 << 16));
        *(uint2*)&x_l[i4] = make_uint2((unsigned)l0 | ((unsigned)l1 << 16),
                                       (unsigned)l2 | ((unsigned)l3 << 16));
        return;
    }
    if (bid >= 18432 && bid < 19456) {
        const int idx = (bid - 18432) * 256 + t;
        const int r = idx >> 11, k = idx & 2047;
        float v = (r < 96) ? W_x[(size_t)k * 96 + r] : 0.f;
        WxT_h[idx] = f2bf(v);
        return;
    }
    if (bid >= 19456) {
        const int idx = (bid - 19456) * 256 + t;   // < 12288
        const int b = idx / 6144, rem = idx % 6144;
        const int lp = rem >> 11, c = rem & 2047;
        const size_t a = ((size_t)b * 2051 + lp) * 2048 + c;
        XSP_h[a] = 0; XSP_l[a] = 0;
        return;
    }
    // transpose-hi cases
    const float* src; int R, C; ushort_t* dst; int bx, by;
    if (bid < 8192)       { src = W_in;   R = 1024; C = 4096; dst = WinT_h;
                            int l = bid - 4096;  bx = l & 127; by = l >> 7; }
    else if (bid < 16384) { src = conv_k; R = 4096; C = 2048; dst = convkT_h;
                            int l = bid - 8192;  bx = l & 63;  by = l >> 6; }
    else                  { src = W_out;  R = 2048; C = 1024; dst = WoutT_h;
                            int l = bid - 16384; bx = l & 31;  by = l >> 5; }
    const int tx = t & 31, ty = t >> 5;
    const int r0 = by * 32, c0 = bx * 32;
    #pragma unroll
    for (int j = 0; j < 4; ++j)
        ts[ty + j * 8][tx] = src[(size_t)(r0 + ty + j * 8) * C + c0 + tx];
    __syncthreads();
    #pragma unroll
    for (int j = 0; j < 4; ++j)
        dst[(size_t)(c0 + ty + j * 8) * R + r0 + tx] = f2bf(ts[tx][ty + j * 8]);
}

// ---------------------------------------------------------------------------
// 2-term split-bf16 MFMA GEMM: C = A @ B. A hi/lo [M][Kfull]; B hi [N][Kfull].
// 128x128 tile, BK=32, 4 waves x (4x4) 16x16x32 tiles, 2 MFMAs/tile (AhB+AlB).
// MODE 0 (xz): cols<2048 -> XSP bf16 hi/lo (+3-row causal pad); else RES fp32.
// MODE 1 (out): fp32 store ldc=1024.
// MODE 2 (dbc): split-K, blockIdx.x = k-segment (512); partial to Cf+ks*393216,
//               cols<96 only.
// ---------------------------------------------------------------------------
template<int MODE>
__global__ __launch_bounds__(256) void gemm2(
    const ushort_t* __restrict__ Ah, const ushort_t* __restrict__ Al,
    const ushort_t* __restrict__ Bh, int Kfull,
    float* __restrict__ Cf, ushort_t* __restrict__ Oh, ushort_t* __restrict__ Ol)
{
    __shared__ __align__(16) ushort_t As_h[128 * LDS_STRIDE];
    __shared__ __align__(16) ushort_t As_l[128 * LDS_STRIDE];
    __shared__ __align__(16) ushort_t Bs_h[128 * LDS_STRIDE];
    const int t = threadIdx.x;
    const int m0 = blockIdx.y * 128;
    const int n0 = (MODE == 2) ? 0 : blockIdx.x * 128;
    const int kbeg = (MODE == 2) ? blockIdx.x * 512 : 0;
    const int kend = (MODE == 2) ? kbeg + 512 : Kfull;
    const int lane = t & 63, wave = t >> 6;
    const int wm = (wave >> 1) * 64, wn = (wave & 1) * 64;
    const int m16 = lane & 15, q = lane >> 4;
    const int r_0 = t >> 2, cc_0 = (t & 3) * 8;
    const int r_1 = (t + 256) >> 2, cc_1 = ((t + 256) & 3) * 8;

    uint4 pa0h = *(const uint4*)&Ah[(size_t)(m0 + r_0) * Kfull + kbeg + cc_0];
    uint4 pa1h = *(const uint4*)&Ah[(size_t)(m0 + r_1) * Kfull + kbeg + cc_1];
    uint4 pa0l = *(const uint4*)&Al[(size_t)(m0 + r_0) * Kfull + kbeg + cc_0];
    uint4 pa1l = *(const uint4*)&Al[(size_t)(m0 + r_1) * Kfull + kbeg + cc_1];
    uint4 pb0  = *(const uint4*)&Bh[(size_t)(n0 + r_0) * Kfull + kbeg + cc_0];
    uint4 pb1  = *(const uint4*)&Bh[(size_t)(n0 + r_1) * Kfull + kbeg + cc_1];

    floatx4 acc[4][4];
    const floatx4 zz = {0.f, 0.f, 0.f, 0.f};
    #pragma unroll
    for (int i = 0; i < 4; ++i)
        #pragma unroll
        for (int j = 0; j < 4; ++j) acc[i][j] = zz;

    for (int k0 = kbeg; k0 < kend; k0 += 32) {
        *(uint4*)&As_h[r_0 * LDS_STRIDE + cc_0] = pa0h;
        *(uint4*)&As_h[r_1 * LDS_STRIDE + cc_1] = pa1h;
        *(uint4*)&As_l[r_0 * LDS_STRIDE + cc_0] = pa0l;
        *(uint4*)&As_l[r_1 * LDS_STRIDE + cc_1] = pa1l;
        *(uint4*)&Bs_h[r_0 * LDS_STRIDE + cc_0] = pb0;
        *(uint4*)&Bs_h[r_1 * LDS_STRIDE + cc_1] = pb1;
        __syncthreads();
        if (k0 + 32 < kend) {
            const int kn = k0 + 32;
            pa0h = *(const uint4*)&Ah[(size_t)(m0 + r_0) * Kfull + kn + cc_0];
            pa1h = *(const uint4*)&Ah[(size_t)(m0 + r_1) * Kfull + kn + cc_1];
            pa0l = *(const uint4*)&Al[(size_t)(m0 + r_0) * Kfull + kn + cc_0];
            pa1l = *(const uint4*)&Al[(size_t)(m0 + r_1) * Kfull + kn + cc_1];
            pb0  = *(const uint4*)&Bh[(size_t)(n0 + r_0) * Kfull + kn + cc_0];
            pb1  = *(const uint4*)&Bh[(size_t)(n0 + r_1) * Kfull + kn + cc_1];
        }
        bf16x8 ah[4], al[4], bh[4];
        #pragma unroll
        for (int i = 0; i < 4; ++i) {
            const int off = (wm + i * 16 + m16) * LDS_STRIDE + q * 8;
            ah[i] = *(const bf16x8*)&As_h[off];
            al[i] = *(const bf16x8*)&As_l[off];
        }
        #pragma unroll
        for (int j = 0; j < 4; ++j)
            bh[j] = *(const bf16x8*)&Bs_h[(wn + j * 16 + m16) * LDS_STRIDE + q * 8];
        #pragma unroll
        for (int i = 0; i < 4; ++i)
            #pragma unroll
            for (int j = 0; j < 4; ++j) {
                acc[i][j] = __builtin_amdgcn_mfma_f32_16x16x32_bf16(ah[i], bh[j], acc[i][j], 0, 0, 0);
                acc[i][j] = __builtin_amdgcn_mfma_f32_16x16x32_bf16(al[i], bh[j], acc[i][j], 0, 0, 0);
            }
        __syncthreads();
    }

    float* Cp = (MODE == 2) ? (Cf + (size_t)blockIdx.x * 393216) : Cf;
    #pragma unroll
    for (int i = 0; i < 4; ++i) {
        const int row_b = m0 + wm + i * 16 + q * 4;
        #pragma unroll
        for (int j = 0; j < 4; ++j) {
            const int col = n0 + wn + j * 16 + m16;
            #pragma unroll
            for (int rr = 0; rr < 4; ++rr) {
                const int row = row_b + rr;
                const float v = acc[i][j][rr];
                if (MODE == 0) {
                    if (n0 < 2048) {
                        const int b = row >> 11, l = row & 2047;
                        const size_t a = ((size_t)b * 2051 + l + 3) * 2048 + col;
                        const unsigned short h = f2bf(v);
                        Oh[a] = h;
                        Ol[a] = f2bf(v - bf2f(h));
                    } else {
                        Cp[(size_t)row * 2048 + (col - 2048)] = v;
                    }
                } else if (MODE == 1) {
                    Cp[(size_t)row * 1024 + col] = v;
                } else {
                    if (col < 96) Cp[(size_t)row * 96 + col] = v;
                }
            }
        }
    }
}

// ---------------------------------------------------------------------------
// Conv as 2-term split MFMA GEMM. A[p][k=w*1024+i] = XSP[b][l+w][g*1024+i]
// (3-row zero pad). B = convkT_h [2048][4096]. Epilogue: u=silu(acc+bias)
// written as bf16 hi/lo only.
// ---------------------------------------------------------------------------
__global__ __launch_bounds__(256) void conv2(
    const ushort_t* __restrict__ Xh, const ushort_t* __restrict__ Xl,
    const ushort_t* __restrict__ Bh, const float* __restrict__ bias,
    ushort_t* __restrict__ Uh, ushort_t* __restrict__ Ul)
{
    __shared__ __align__(16) ushort_t As_h[128 * LDS_STRIDE];
    __shared__ __align__(16) ushort_t As_l[128 * LDS_STRIDE];
    __shared__ __align__(16) ushort_t Bs_h[128 * LDS_STRIDE];
    const int t = threadIdx.x;
    const int m0 = blockIdx.y * 128, n0 = blockIdx.x * 128;
    const int g1024 = (n0 >= 1024) ? 1024 : 0;
    const int lane = t & 63, wave = t >> 6;
    const int wm = (wave >> 1) * 64, wn = (wave & 1) * 64;
    const int m16 = lane & 15, q = lane >> 4;
    const int r_0 = t >> 2, cc_0 = (t & 3) * 8;
    const int r_1 = (t + 256) >> 2, cc_1 = ((t + 256) & 3) * 8;
    const int p_0 = m0 + r_0, b_0 = p_0 >> 11, l_0 = p_0 & 2047;
    const int p_1 = m0 + r_1, b_1 = p_1 >> 11, l_1 = p_1 & 2047;

    auto aA = [&](int bb, int ll, int k0, int cc) -> size_t {
        const int w = k0 >> 10;
        const int i = (k0 & 1023) + cc;
        return ((size_t)bb * 2051 + ll + w) * 2048 + g1024 + i;
    };

    uint4 pa0h = *(const uint4*)&Xh[aA(b_0, l_0, 0, cc_0)];
    uint4 pa1h = *(const uint4*)&Xh[aA(b_1, l_1, 0, cc_1)];
    uint4 pa0l = *(const uint4*)&Xl[aA(b_0, l_0, 0, cc_0)];
    uint4 pa1l = *(const uint4*)&Xl[aA(b_1, l_1, 0, cc_1)];
    uint4 pb0  = *(const uint4*)&Bh[(size_t)(n0 + r_0) * 4096 + cc_0];
    uint4 pb1  = *(const uint4*)&Bh[(size_t)(n0 + r_1) * 4096 + cc_1];

    floatx4 acc[4][4];
    const floatx4 zz = {0.f, 0.f, 0.f, 0.f};
    #pragma unroll
    for (int i = 0; i < 4; ++i)
        #pragma unroll
        for (int j = 0; j < 4; ++j) acc[i][j] = zz;

    for (int k0 = 0; k0 < 4096; k0 += 32) {
        *(uint4*)&As_h[r_0 * LDS_STRIDE + cc_0] = pa0h;
        *(uint4*)&As_h[r_1 * LDS_STRIDE + cc_1] = pa1h;
        *(uint4*)&As_l[r_0 * LDS_STRIDE + cc_0] = pa0l;
        *(uint4*)&As_l[r_1 * LDS_STRIDE + cc_1] = pa1l;
        *(uint4*)&Bs_h[r_0 * LDS_STRIDE + cc_0] = pb0;
        *(uint4*)&Bs_h[r_1 * LDS_STRIDE + cc_1] = pb1;
        __syncthreads();
        if (k0 + 32 < 4096) {
            const int kn = k0 + 32;
            pa0h = *(const uint4*)&Xh[aA(b_0, l_0, kn, cc_0)];
            pa1h = *(const uint4*)&Xh[aA(b_1, l_1, kn, cc_1)];
            pa0l = *(const uint4*)&Xl[aA(b_0, l_0, kn, cc_0)];
            pa1l = *(const uint4*)&Xl[aA(b_1, l_1, kn, cc_1)];
            pb0  = *(const uint4*)&Bh[(size_t)(n0 + r_0) * 4096 + kn + cc_0];
            pb1  = *(const uint4*)&Bh[(size_t)(n0 + r_1) * 4096 + kn + cc_1];
        }
        bf16x8 ah[4], al[4], bh[4];
        #pragma unroll
        for (int i = 0; i < 4; ++i) {
            const int off = (wm + i * 16 + m16) * LDS_STRIDE + q * 8;
            ah[i] = *(const bf16x8*)&As_h[off];
            al[i] = *(const bf16x8*)&As_l[off];
        }
        #pragma unroll
        for (int j = 0; j < 4; ++j)
            bh[j] = *(const bf16x8*)&Bs_h[(wn + j * 16 + m16) * LDS_STRIDE + q * 8];
        #pragma unroll
        for (int i = 0; i < 4; ++i)
            #pragma unroll
            for (int j = 0; j < 4; ++j) {
                acc[i][j] = __builtin_amdgcn_mfma_f32_16x16x32_bf16(ah[i], bh[j], acc[i][j], 0, 0, 0);
                acc[i][j] = __builtin_amdgcn_mfma_f32_16x16x32_bf16(al[i], bh[j], acc[i][j], 0, 0, 0);
            }
        __syncthreads();
    }

    #pragma unroll
    for (int i = 0; i < 4; ++i) {
        const int row_b = m0 + wm + i * 16 + q * 4;
        #pragma unroll
        for (int j = 0; j < 4; ++j) {
            const int col = n0 + wn + j * 16 + m16;
            const float bz = bias[col];
            #pragma unroll
            for (int rr = 0; rr < 4; ++rr) {
                const int row = row_b + rr;
                const float v = silu_f(acc[i][j][rr] + bz);
                const size_t a = (size_t)row * 2048 + col;
                const unsigned short h = f2bf(v);
                Uh[a] = h;
                Ul[a] = f2bf(v - bf2f(h));
            }
        }
    }
}

// Sum the 4 split-K partials of dbc.
__global__ __launch_bounds__(256) void dbc_reduce(
    const float* __restrict__ DBCP, float* __restrict__ DBC)
{
    const int i = blockIdx.x * 256 + threadIdx.x;   // < 393216
    DBC[i] = (DBCP[i] + DBCP[393216 + i]) + (DBCP[786432 + i] + DBCP[1179648 + i]);
}

// ---------------------------------------------------------------------------
// delta[p,d] = clip(softplus(dbc[p,0:64] @ W_dt[:,d] + b_dt[d]), 1e-3, 1e-1)
// ---------------------------------------------------------------------------
__global__ __launch_bounds__(256) void delta_kernel(
    const float* __restrict__ DBC, const float* __restrict__ W_dt,
    const float* __restrict__ b_dt, float* __restrict__ DELTA)
{
    const int n  = blockIdx.x * 256 + threadIdx.x;
    const int p0 = blockIdx.y * 16;
    const int t  = threadIdx.x;
    __shared__ float dt_s[16][64];
    #pragma unroll
    for (int j = 0; j < 4; ++j) {
        const int lin = j * 256 + t;
        const int r = lin >> 6, k = lin & 63;
        dt_s[r][k] = DBC[(size_t)(p0 + r) * 96 + k];
    }
    __syncthreads();
    float acc[16];
    const float bz = b_dt[n];
    #pragma unroll
    for (int r = 0; r < 16; ++r) acc[r] = bz;
    for (int k = 0; k < 64; ++k) {
        const float wv = W_dt[(size_t)k * 2048 + n];
        #pragma unroll
        for (int r = 0; r < 16; ++r) acc[r] += dt_s[r][k] * wv;
    }
    #pragma unroll
    for (int r = 0; r < 16; ++r) {
        float a = acc[r];
        float sp = (a > 20.f) ? a : log1pf(expf(a));
        sp = fminf(fmaxf(sp, 0.001f), 0.1f);
        DELTA[(size_t)(p0 + r) * 2048 + n] = sp;
    }
}

// ---------------------------------------------------------------------------
// Chunked scan (64 chunks of 32). off(c,n,b,d) = c*65536 + n*4096 + b*2048 + d
// ---------------------------------------------------------------------------
__global__ __launch_bounds__(256) void scan_p1(
    const float* __restrict__ DELTA,
    const ushort_t* __restrict__ Uh, const ushort_t* __restrict__ Ul,
    const float* __restrict__ DBC, const float* __restrict__ A_log,
    float* __restrict__ HEND, float* __restrict__ APROD)
{
    const int t = threadIdx.x;
    const int d = blockIdx.x * 256 + t;
    const int c = blockIdx.y;
    const int b = blockIdx.z;
    const int p0 = b * 2048 + c * 32;
    __shared__ float Bs[32][16];
    for (int lin = t; lin < 512; lin += 256) {
        const int s = lin >> 4, n = lin & 15;
        Bs[s][n] = DBC[(size_t)(p0 + s) * 96 + 64 + n];
    }
    __syncthreads();
    float Af[16];
    *(float4*)&Af[0]  = *(const float4*)&A_log[(size_t)d * 16 + 0];
    *(float4*)&Af[4]  = *(const float4*)&A_log[(size_t)d * 16 + 4];
    *(float4*)&Af[8]  = *(const float4*)&A_log[(size_t)d * 16 + 8];
    *(float4*)&Af[12] = *(const float4*)&A_log[(size_t)d * 16 + 12];
    #pragma unroll
    for (int n = 0; n < 16; ++n) Af[n] = -__expf(Af[n]);

    float h[16] = {};
    float sd = 0.f;
    for (int s = 0; s < 32; ++s) {
        const size_t ix = (size_t)(p0 + s) * 2048 + d;
        const float dv = DELTA[ix];
        const float uv = bf2f(Uh[ix]) + bf2f(Ul[ix]);
        const float du = dv * uv;
        sd += dv;
        #pragma unroll
        for (int n = 0; n < 16; ++n)
            h[n] = __expf(dv * Af[n]) * h[n] + du * Bs[s][n];
    }
    const size_t base = (size_t)c * 65536 + (size_t)b * 2048 + d;
    #pragma unroll
    for (int n = 0; n < 16; ++n) {
        HEND[base + (size_t)n * 4096]  = h[n];
        APROD[base + (size_t)n * 4096] = __expf(Af[n] * sd);
    }
}

__global__ __launch_bounds__(256) void scan_p2(
    const float* __restrict__ HEND, const float* __restrict__ APROD,
    float* __restrict__ HINIT)
{
    const int g = blockIdx.x * 256 + threadIdx.x;
    float h = 0.f;
    for (int c = 0; c < 64; ++c) {
        HINIT[(size_t)c * 65536 + g] = h;
        h = APROD[(size_t)c * 65536 + g] * h + HEND[(size_t)c * 65536 + g];
    }
}

// Pass 3: re-scan from h_init, y, gate; emit G as bf16 hi/lo.
__global__ __launch_bounds__(256) void scan_p3(
    const float* __restrict__ DELTA,
    const ushort_t* __restrict__ Uh, const ushort_t* __restrict__ Ul,
    const float* __restrict__ DBC, const float* __restrict__ RES,
    const float* __restrict__ A_log, const float* __restrict__ Dp,
    const float* __restrict__ HINIT,
    ushort_t* __restrict__ Gh, ushort_t* __restrict__ Gl)
{
    const int t = threadIdx.x;
    const int d = blockIdx.x * 256 + t;
    const int c = blockIdx.y;
    const int b = blockIdx.z;
    const int p0 = b * 2048 + c * 32;
    __shared__ float Bs[32][16];
    __shared__ float Cs[32][16];
    for (int lin = t; lin < 512; lin += 256) {
        const int s = lin >> 4, n = lin & 15;
        Bs[s][n] = DBC[(size_t)(p0 + s) * 96 + 64 + n];
        Cs[s][n] = DBC[(size_t)(p0 + s) * 96 + 80 + n];
    }
    __syncthreads();
    float Af[16];
    *(float4*)&Af[0]  = *(const float4*)&A_log[(size_t)d * 16 + 0];
    *(float4*)&Af[4]  = *(const float4*)&A_log[(size_t)d * 16 + 4];
    *(float4*)&Af[8]  = *(const float4*)&A_log[(size_t)d * 16 + 8];
    *(float4*)&Af[12] = *(const float4*)&A_log[(size_t)d * 16 + 12];
    #pragma unroll
    for (int n = 0; n < 16; ++n) Af[n] = -__expf(Af[n]);

    const size_t base = (size_t)c * 65536 + (size_t)b * 2048 + d;
    float h[16];
    #pragma unroll
    for (int n = 0; n < 16; ++n) h[n] = HINIT[base + (size_t)n * 4096];
    const float Dd = Dp[d];

    for (int s = 0; s < 32; ++s) {
        const int p = p0 + s;
        const size_t ix = (size_t)p * 2048 + d;
        const float dv = DELTA[ix];
        const float uv = bf2f(Uh[ix]) + bf2f(Ul[ix]);
        const float du = dv * uv;
        float y = 0.f;
        #pragma unroll
        for (int n = 0; n < 16; ++n) {
            h[n] = __expf(dv * Af[n]) * h[n] + du * Bs[s][n];
            y += h[n] * Cs[s][n];
        }
        const float resv = RES[ix];
        const float gv = (y + uv * Dd) * silu_f(resv);
        const unsigned short gh = f2bf(gv);
        Gh[ix] = gh;
        Gl[ix] = f2bf(gv - bf2f(gh));
    }
}

// ---------------------------------------------------------------------------
extern "C" void kernel_launch(void* const* d_in, const int* in_sizes, int n_in,
                              void* d_out, int out_size, void* d_ws, size_t ws_size,
                              hipStream_t stream) {
    const float* x      = (const float*)d_in[0];
    const float* W_in   = (const float*)d_in[1];
    const float* conv_k = (const float*)d_in[2];
    const float* conv_b = (const float*)d_in[3];
    const float* W_x    = (const float*)d_in[4];
    const float* W_dt   = (const float*)d_in[5];
    const float* b_dt   = (const float*)d_in[6];
    const float* A_log  = (const float*)d_in[7];
    const float* Dv     = (const float*)d_in[8];
    const float* W_out  = (const float*)d_in[9];
    float* out = (float*)d_out;

    // Workspace layout (total 205,570,048 B; round-4 used 219.7MB so ws fits).
    char* base = (char*)d_ws;
    float*    RES      = (float*)(base);                  // 33,554,432
    ushort_t* Uh       = (ushort_t*)(base + 33554432);    // 16,777,216
    ushort_t* Ul       = (ushort_t*)(base + 50331648);    // 16,777,216
    float*    DELTA    = (float*)(base + 67108864);       // 33,554,432
    ushort_t* XSP_h    = (ushort_t*)(base + 100663296);   // 16,801,792
    ushort_t* XSP_l    = (ushort_t*)(base + 117465088);   // 16,801,792
    float*    HEND     = (float*)(base + 100663296);      // alias over XSP (dead)
    float*    APROD    = (float*)(base + 117440512);      // alias
    ushort_t* x_h      = (ushort_t*)(base + 134266880);   //  8,388,608
    ushort_t* x_l      = (ushort_t*)(base + 142655488);   //  8,388,608
    ushort_t* convkT_h = (ushort_t*)(base + 151044096);   // 16,777,216
    ushort_t* G_h      = (ushort_t*)(base + 134266880);   // alias over x (dead)
    ushort_t* G_l      = (ushort_t*)(base + 151044096);   // alias over convkT (dead)
    ushort_t* WinT_h   = (ushort_t*)(base + 167821312);   //  8,388,608
    ushort_t* WoutT_h  = (ushort_t*)(base + 176209920);   //  4,194,304
    ushort_t* WxT_h    = (ushort_t*)(base + 180404224);   //    524,288
    float*    DBCP     = (float*)(base + 180928512);      //  6,291,456
    float*    DBC      = (float*)(base + 187219968);      //  1,572,864
    float*    HINIT    = (float*)(base + 188792832);      // 16,777,216

    // 0) all prep in one launch
    prep_all<<<19504, 256, 0, stream>>>(x, W_in, conv_k, W_out, W_x,
                                        x_h, x_l, WinT_h, convkT_h, WoutT_h,
                                        WxT_h, XSP_h, XSP_l);
    // 1) xz: xs -> XSP bf16 hi/lo (+pad), res -> RES fp32
    gemm2<0><<<dim3(32, 32), 256, 0, stream>>>(x_h, x_l, WinT_h, 1024,
                                               RES, XSP_h, XSP_l);
    // 2) u = silu(conv + b) -> Uh/Ul
    conv2<<<dim3(16, 32), 256, 0, stream>>>(XSP_h, XSP_l, convkT_h, conv_b, Uh, Ul);
    // 3) dbc = U @ W_x, split-K x4 + reduce
    gemm2<2><<<dim3(4, 32), 256, 0, stream>>>(Uh, Ul, WxT_h, 2048,
                                              DBCP, nullptr, nullptr);
    dbc_reduce<<<1536, 256, 0, stream>>>(DBCP, DBC);
    // 4) delta
    delta_kernel<<<dim3(8, 256), 256, 0, stream>>>(DBC, W_dt, b_dt, DELTA);
    // 5) chunked scan
    scan_p1<<<dim3(8, 64, 2), 256, 0, stream>>>(DELTA, Uh, Ul, DBC, A_log, HEND, APROD);
    scan_p2<<<256, 256, 0, stream>>>(HEND, APROD, HINIT);
    scan_p3<<<dim3(8, 64, 2), 256, 0, stream>>>(DELTA, Uh, Ul, DBC, RES, A_log, Dv,
                                                HINIT, G_h, G_l);
    // 6) out = G @ W_out
    gemm2<1><<<dim3(8, 32), 256, 0, stream>>>(G_h, G_l, WoutT_h, 2048,
                                              out, nullptr, nullptr);
}

// Round 6
// 515.218 us; speedup vs baseline: 6.5080x; 1.1318x over previous
//
#include <hip/hip_runtime.h>
#include <math.h>

// B=2, L=2048, D_MODEL=1024, D_INNER=2048, D_STATE=16, DT_RANK=64, D_CONV=4
// P = B*L = 4096

typedef unsigned short ushort_t;
typedef __bf16 bf16x8 __attribute__((ext_vector_type(8)));
typedef float floatx4 __attribute__((ext_vector_type(4)));

#define LDS_STRIDE 40   // 32 + 8 pad: 80B rows, 16B aligned, 2-way-only conflicts

__device__ __forceinline__ float silu_f(float x) { return x / (1.0f + __expf(-x)); }

__device__ __forceinline__ unsigned short f2bf(float f) {
    unsigned u = __float_as_uint(f);
    unsigned r = u + 0x7fffu + ((u >> 16) & 1u);   // RNE (finite values only)
    return (unsigned short)(r >> 16);
}
__device__ __forceinline__ float bf2f(unsigned short h) {
    return __uint_as_float(((unsigned)h) << 16);
}

// ---------------------------------------------------------------------------
// One mega prep kernel (block-range switch):
//  [0,4096)      : x fp32 -> x_h/x_l split (row-major)
//  [4096,8192)   : W_in   [1024][4096] -> WinT_h  [4096][1024] (hi only)
//  [8192,16384)  : conv_k [4096][2048] -> convkT_h[2048][4096] (hi only)
//  [16384,18432) : W_out  [2048][1024] -> WoutT_h [1024][2048] (hi only)
//  [18432,19456) : W_x    [2048][96]   -> WxT_h   [128][2048]  (pad rows 96..127)
//  [19456,19504) : zero XSP_h causal pad rows
// ---------------------------------------------------------------------------
__global__ __launch_bounds__(256) void prep_all(
    const float* __restrict__ x, const float* __restrict__ W_in,
    const float* __restrict__ conv_k, const float* __restrict__ W_out,
    const float* __restrict__ W_x,
    ushort_t* __restrict__ x_h, ushort_t* __restrict__ x_l,
    ushort_t* __restrict__ WinT_h, ushort_t* __restrict__ convkT_h,
    ushort_t* __restrict__ WoutT_h, ushort_t* __restrict__ WxT_h,
    ushort_t* __restrict__ XSP_h)
{
    __shared__ float ts[32][33];
    const int bid = blockIdx.x;
    const int t = threadIdx.x;
    if (bid < 4096) {
        const size_t i4 = ((size_t)bid * 256 + t) * 4;
        float4 v = *(const float4*)&x[i4];
        unsigned short h0 = f2bf(v.x), h1 = f2bf(v.y), h2 = f2bf(v.z), h3 = f2bf(v.w);
        unsigned short l0 = f2bf(v.x - bf2f(h0)), l1 = f2bf(v.y - bf2f(h1));
        unsigned short l2 = f2bf(v.z - bf2f(h2)), l3 = f2bf(v.w - bf2f(h3));
        *(uint2*)&x_h[i4] = make_uint2((unsigned)h0 | ((unsigned)h1 << 16),
                                       (unsigned)h2 | ((unsigned)h3 << 16));
        *(uint2*)&x_l[i4] = make_uint2((unsigned)l0 | ((unsigned)l1 << 16),
                                       (unsigned)l2 | ((unsigned)l3 << 16));
        return;
    }
    if (bid >= 18432 && bid < 19456) {
        const int idx = (bid - 18432) * 256 + t;
        const int r = idx >> 11, k = idx & 2047;
        float v = (r < 96) ? W_x[(size_t)k * 96 + r] : 0.f;
        WxT_h[idx] = f2bf(v);
        return;
    }
    if (bid >= 19456) {
        const int idx = (bid - 19456) * 256 + t;   // < 12288
        const int b = idx / 6144, rem = idx % 6144;
        const int lp = rem >> 11, c = rem & 2047;
        XSP_h[((size_t)b * 2051 + lp) * 2048 + c] = 0;
        return;
    }
    // transpose-hi cases
    const float* src; int R, C; ushort_t* dst; int bx, by;
    if (bid < 8192)       { src = W_in;   R = 1024; C = 4096; dst = WinT_h;
                            int l = bid - 4096;  bx = l & 127; by = l >> 7; }
    else if (bid < 16384) { src = conv_k; R = 4096; C = 2048; dst = convkT_h;
                            int l = bid - 8192;  bx = l & 63;  by = l >> 6; }
    else                  { src = W_out;  R = 2048; C = 1024; dst = WoutT_h;
                            int l = bid - 16384; bx = l & 31;  by = l >> 5; }
    const int tx = t & 31, ty = t >> 5;
    const int r0 = by * 32, c0 = bx * 32;
    #pragma unroll
    for (int j = 0; j < 4; ++j)
        ts[ty + j * 8][tx] = src[(size_t)(r0 + ty + j * 8) * C + c0 + tx];
    __syncthreads();
    #pragma unroll
    for (int j = 0; j < 4; ++j)
        dst[(size_t)(c0 + ty + j * 8) * R + r0 + tx] = f2bf(ts[tx][ty + j * 8]);
}

// ---------------------------------------------------------------------------
// 2-term split-bf16 MFMA GEMM: C = A @ B. A hi/lo [M][Kfull]; B hi [N][Kfull].
// 128x128 tile, BK=32, 4 waves x (4x4) 16x16x32 tiles, 2 MFMAs/tile (AhB+AlB).
// Modes 0/1: 1-D grid, XCD swizzle (xcd=lin&7 owns 4 row tiles, streams cols).
// MODE 0 (xz): cols<2048 -> XSP bf16 hi (+3-row causal pad); else RES fp32.
// MODE 1 (out): fp32 store ldc=1024.
// MODE 2 (dbc): 2-D grid, split-K (blockIdx.x = 512-wide k-seg), cols<96.
// ---------------------------------------------------------------------------
template<int MODE, int BX>
__global__ __launch_bounds__(256) void gemm2(
    const ushort_t* __restrict__ Ah, const ushort_t* __restrict__ Al,
    const ushort_t* __restrict__ Bh, int Kfull,
    float* __restrict__ Cf, ushort_t* __restrict__ Oh)
{
    __shared__ __align__(16) ushort_t As_h[128 * LDS_STRIDE];
    __shared__ __align__(16) ushort_t As_l[128 * LDS_STRIDE];
    __shared__ __align__(16) ushort_t Bs_h[128 * LDS_STRIDE];
    const int t = threadIdx.x;
    int bx, by;
    if (MODE == 2) { bx = blockIdx.x; by = blockIdx.y; }
    else {
        const int lin = blockIdx.x, xcd = lin & 7, s = lin >> 3;
        by = xcd + 8 * (s / BX);
        bx = s % BX;
    }
    const int m0 = by * 128;
    const int n0 = (MODE == 2) ? 0 : bx * 128;
    const int kbeg = (MODE == 2) ? bx * 512 : 0;
    const int kend = (MODE == 2) ? kbeg + 512 : Kfull;
    const int lane = t & 63, wave = t >> 6;
    const int wm = (wave >> 1) * 64, wn = (wave & 1) * 64;
    const int m16 = lane & 15, q = lane >> 4;
    const int r_0 = t >> 2, cc_0 = (t & 3) * 8;
    const int r_1 = (t + 256) >> 2, cc_1 = ((t + 256) & 3) * 8;

    uint4 pa0h = *(const uint4*)&Ah[(size_t)(m0 + r_0) * Kfull + kbeg + cc_0];
    uint4 pa1h = *(const uint4*)&Ah[(size_t)(m0 + r_1) * Kfull + kbeg + cc_1];
    uint4 pa0l = *(const uint4*)&Al[(size_t)(m0 + r_0) * Kfull + kbeg + cc_0];
    uint4 pa1l = *(const uint4*)&Al[(size_t)(m0 + r_1) * Kfull + kbeg + cc_1];
    uint4 pb0  = *(const uint4*)&Bh[(size_t)(n0 + r_0) * Kfull + kbeg + cc_0];
    uint4 pb1  = *(const uint4*)&Bh[(size_t)(n0 + r_1) * Kfull + kbeg + cc_1];

    floatx4 acc[4][4];
    const floatx4 zz = {0.f, 0.f, 0.f, 0.f};
    #pragma unroll
    for (int i = 0; i < 4; ++i)
        #pragma unroll
        for (int j = 0; j < 4; ++j) acc[i][j] = zz;

    for (int k0 = kbeg; k0 < kend; k0 += 32) {
        *(uint4*)&As_h[r_0 * LDS_STRIDE + cc_0] = pa0h;
        *(uint4*)&As_h[r_1 * LDS_STRIDE + cc_1] = pa1h;
        *(uint4*)&As_l[r_0 * LDS_STRIDE + cc_0] = pa0l;
        *(uint4*)&As_l[r_1 * LDS_STRIDE + cc_1] = pa1l;
        *(uint4*)&Bs_h[r_0 * LDS_STRIDE + cc_0] = pb0;
        *(uint4*)&Bs_h[r_1 * LDS_STRIDE + cc_1] = pb1;
        __syncthreads();
        if (k0 + 32 < kend) {
            const int kn = k0 + 32;
            pa0h = *(const uint4*)&Ah[(size_t)(m0 + r_0) * Kfull + kn + cc_0];
            pa1h = *(const uint4*)&Ah[(size_t)(m0 + r_1) * Kfull + kn + cc_1];
            pa0l = *(const uint4*)&Al[(size_t)(m0 + r_0) * Kfull + kn + cc_0];
            pa1l = *(const uint4*)&Al[(size_t)(m0 + r_1) * Kfull + kn + cc_1];
            pb0  = *(const uint4*)&Bh[(size_t)(n0 + r_0) * Kfull + kn + cc_0];
            pb1  = *(const uint4*)&Bh[(size_t)(n0 + r_1) * Kfull + kn + cc_1];
        }
        bf16x8 ah[4], al[4], bh[4];
        #pragma unroll
        for (int i = 0; i < 4; ++i) {
            const int off = (wm + i * 16 + m16) * LDS_STRIDE + q * 8;
            ah[i] = *(const bf16x8*)&As_h[off];
            al[i] = *(const bf16x8*)&As_l[off];
        }
        #pragma unroll
        for (int j = 0; j < 4; ++j)
            bh[j] = *(const bf16x8*)&Bs_h[(wn + j * 16 + m16) * LDS_STRIDE + q * 8];
        #pragma unroll
        for (int i = 0; i < 4; ++i)
            #pragma unroll
            for (int j = 0; j < 4; ++j) {
                acc[i][j] = __builtin_amdgcn_mfma_f32_16x16x32_bf16(ah[i], bh[j], acc[i][j], 0, 0, 0);
                acc[i][j] = __builtin_amdgcn_mfma_f32_16x16x32_bf16(al[i], bh[j], acc[i][j], 0, 0, 0);
            }
        __syncthreads();
    }

    float* Cp = (MODE == 2) ? (Cf + (size_t)bx * 393216) : Cf;
    #pragma unroll
    for (int i = 0; i < 4; ++i) {
        const int row_b = m0 + wm + i * 16 + q * 4;
        #pragma unroll
        for (int j = 0; j < 4; ++j) {
            const int col = n0 + wn + j * 16 + m16;
            #pragma unroll
            for (int rr = 0; rr < 4; ++rr) {
                const int row = row_b + rr;
                const float v = acc[i][j][rr];
                if (MODE == 0) {
                    if (n0 < 2048) {
                        const int b = row >> 11, l = row & 2047;
                        Oh[((size_t)b * 2051 + l + 3) * 2048 + col] = f2bf(v);
                    } else {
                        Cp[(size_t)row * 2048 + (col - 2048)] = v;
                    }
                } else if (MODE == 1) {
                    Cp[(size_t)row * 1024 + col] = v;
                } else {
                    if (col < 96) Cp[(size_t)row * 96 + col] = v;
                }
            }
        }
    }
}

// ---------------------------------------------------------------------------
// Conv as plain-bf16 MFMA GEMM (A hi-only). A[p][k=w*1024+i] =
// XSP_h[b][l+w][g*1024+i] (3-row zero pad). B = convkT_h [2048][4096].
// 1-D grid with XCD swizzle (BX=16). Epilogue: u=silu(acc+bias) -> bf16 hi/lo.
// ---------------------------------------------------------------------------
__global__ __launch_bounds__(256) void conv2(
    const ushort_t* __restrict__ Xh, const ushort_t* __restrict__ Bh,
    const float* __restrict__ bias,
    ushort_t* __restrict__ Uh, ushort_t* __restrict__ Ul)
{
    __shared__ __align__(16) ushort_t As_h[128 * LDS_STRIDE];
    __shared__ __align__(16) ushort_t Bs_h[128 * LDS_STRIDE];
    const int t = threadIdx.x;
    const int lin = blockIdx.x, xcd = lin & 7, s = lin >> 3;
    const int by = xcd + 8 * (s / 16);
    const int bxp = s % 16;
    const int m0 = by * 128, n0 = bxp * 128;
    const int g1024 = (n0 >= 1024) ? 1024 : 0;
    const int lane = t & 63, wave = t >> 6;
    const int wm = (wave >> 1) * 64, wn = (wave & 1) * 64;
    const int m16 = lane & 15, q = lane >> 4;
    const int r_0 = t >> 2, cc_0 = (t & 3) * 8;
    const int r_1 = (t + 256) >> 2, cc_1 = ((t + 256) & 3) * 8;
    const int p_0 = m0 + r_0, b_0 = p_0 >> 11, l_0 = p_0 & 2047;
    const int p_1 = m0 + r_1, b_1 = p_1 >> 11, l_1 = p_1 & 2047;

    auto aA = [&](int bb, int ll, int k0, int cc) -> size_t {
        const int w = k0 >> 10;
        const int i = (k0 & 1023) + cc;
        return ((size_t)bb * 2051 + ll + w) * 2048 + g1024 + i;
    };

    uint4 pa0 = *(const uint4*)&Xh[aA(b_0, l_0, 0, cc_0)];
    uint4 pa1 = *(const uint4*)&Xh[aA(b_1, l_1, 0, cc_1)];
    uint4 pb0 = *(const uint4*)&Bh[(size_t)(n0 + r_0) * 4096 + cc_0];
    uint4 pb1 = *(const uint4*)&Bh[(size_t)(n0 + r_1) * 4096 + cc_1];

    floatx4 acc[4][4];
    const floatx4 zz = {0.f, 0.f, 0.f, 0.f};
    #pragma unroll
    for (int i = 0; i < 4; ++i)
        #pragma unroll
        for (int j = 0; j < 4; ++j) acc[i][j] = zz;

    for (int k0 = 0; k0 < 4096; k0 += 32) {
        *(uint4*)&As_h[r_0 * LDS_STRIDE + cc_0] = pa0;
        *(uint4*)&As_h[r_1 * LDS_STRIDE + cc_1] = pa1;
        *(uint4*)&Bs_h[r_0 * LDS_STRIDE + cc_0] = pb0;
        *(uint4*)&Bs_h[r_1 * LDS_STRIDE + cc_1] = pb1;
        __syncthreads();
        if (k0 + 32 < 4096) {
            const int kn = k0 + 32;
            pa0 = *(const uint4*)&Xh[aA(b_0, l_0, kn, cc_0)];
            pa1 = *(const uint4*)&Xh[aA(b_1, l_1, kn, cc_1)];
            pb0 = *(const uint4*)&Bh[(size_t)(n0 + r_0) * 4096 + kn + cc_0];
            pb1 = *(const uint4*)&Bh[(size_t)(n0 + r_1) * 4096 + kn + cc_1];
        }
        bf16x8 ah[4], bh[4];
        #pragma unroll
        for (int i = 0; i < 4; ++i)
            ah[i] = *(const bf16x8*)&As_h[(wm + i * 16 + m16) * LDS_STRIDE + q * 8];
        #pragma unroll
        for (int j = 0; j < 4; ++j)
            bh[j] = *(const bf16x8*)&Bs_h[(wn + j * 16 + m16) * LDS_STRIDE + q * 8];
        #pragma unroll
        for (int i = 0; i < 4; ++i)
            #pragma unroll
            for (int j = 0; j < 4; ++j)
                acc[i][j] = __builtin_amdgcn_mfma_f32_16x16x32_bf16(ah[i], bh[j], acc[i][j], 0, 0, 0);
        __syncthreads();
    }

    #pragma unroll
    for (int i = 0; i < 4; ++i) {
        const int row_b = m0 + wm + i * 16 + q * 4;
        #pragma unroll
        for (int j = 0; j < 4; ++j) {
            const int col = n0 + wn + j * 16 + m16;
            const float bz = bias[col];
            #pragma unroll
            for (int rr = 0; rr < 4; ++rr) {
                const int row = row_b + rr;
                const float v = silu_f(acc[i][j][rr] + bz);
                const size_t a = (size_t)row * 2048 + col;
                const unsigned short h = f2bf(v);
                Uh[a] = h;
                Ul[a] = f2bf(v - bf2f(h));
            }
        }
    }
}

// Sum the 4 split-K partials of dbc.
__global__ __launch_bounds__(256) void dbc_reduce(
    const float* __restrict__ DBCP, float* __restrict__ DBC)
{
    const int i = blockIdx.x * 256 + threadIdx.x;   // < 393216
    DBC[i] = (DBCP[i] + DBCP[393216 + i]) + (DBCP[786432 + i] + DBCP[1179648 + i]);
}

// ---------------------------------------------------------------------------
// delta[p,d] = clip(softplus(dbc[p,0:64] @ W_dt[:,d] + b_dt[d]), 1e-3, 1e-1)
// ---------------------------------------------------------------------------
__global__ __launch_bounds__(256) void delta_kernel(
    const float* __restrict__ DBC, const float* __restrict__ W_dt,
    const float* __restrict__ b_dt, float* __restrict__ DELTA)
{
    const int n  = blockIdx.x * 256 + threadIdx.x;
    const int p0 = blockIdx.y * 16;
    const int t  = threadIdx.x;
    __shared__ float dt_s[16][64];
    #pragma unroll
    for (int j = 0; j < 4; ++j) {
        const int lin = j * 256 + t;
        const int r = lin >> 6, k = lin & 63;
        dt_s[r][k] = DBC[(size_t)(p0 + r) * 96 + k];
    }
    __syncthreads();
    float acc[16];
    const float bz = b_dt[n];
    #pragma unroll
    for (int r = 0; r < 16; ++r) acc[r] = bz;
    for (int k = 0; k < 64; ++k) {
        const float wv = W_dt[(size_t)k * 2048 + n];
        #pragma unroll
        for (int r = 0; r < 16; ++r) acc[r] += dt_s[r][k] * wv;
    }
    #pragma unroll
    for (int r = 0; r < 16; ++r) {
        float a = acc[r];
        float sp = (a > 20.f) ? a : log1pf(expf(a));
        sp = fminf(fmaxf(sp, 0.001f), 0.1f);
        DELTA[(size_t)(p0 + r) * 2048 + n] = sp;
    }
}

// ---------------------------------------------------------------------------
// Chunked scan (64 chunks of 32). off(c,n,b,d) = c*65536 + n*4096 + b*2048 + d
// ---------------------------------------------------------------------------
__global__ __launch_bounds__(256) void scan_p1(
    const float* __restrict__ DELTA,
    const ushort_t* __restrict__ Uh, const ushort_t* __restrict__ Ul,
    const float* __restrict__ DBC, const float* __restrict__ A_log,
    float* __restrict__ HEND, float* __restrict__ APROD)
{
    const int t = threadIdx.x;
    const int d = blockIdx.x * 256 + t;
    const int c = blockIdx.y;
    const int b = blockIdx.z;
    const int p0 = b * 2048 + c * 32;
    __shared__ float Bs[32][16];
    for (int lin = t; lin < 512; lin += 256) {
        const int s = lin >> 4, n = lin & 15;
        Bs[s][n] = DBC[(size_t)(p0 + s) * 96 + 64 + n];
    }
    __syncthreads();
    float Af[16];
    *(float4*)&Af[0]  = *(const float4*)&A_log[(size_t)d * 16 + 0];
    *(float4*)&Af[4]  = *(const float4*)&A_log[(size_t)d * 16 + 4];
    *(float4*)&Af[8]  = *(const float4*)&A_log[(size_t)d * 16 + 8];
    *(float4*)&Af[12] = *(const float4*)&A_log[(size_t)d * 16 + 12];
    #pragma unroll
    for (int n = 0; n < 16; ++n) Af[n] = -__expf(Af[n]);

    float h[16] = {};
    float sd = 0.f;
    for (int s = 0; s < 32; ++s) {
        const size_t ix = (size_t)(p0 + s) * 2048 + d;
        const float dv = DELTA[ix];
        const float uv = bf2f(Uh[ix]) + bf2f(Ul[ix]);
        const float du = dv * uv;
        sd += dv;
        #pragma unroll
        for (int n = 0; n < 16; ++n)
            h[n] = __expf(dv * Af[n]) * h[n] + du * Bs[s][n];
    }
    const size_t base = (size_t)c * 65536 + (size_t)b * 2048 + d;
    #pragma unroll
    for (int n = 0; n < 16; ++n) {
        HEND[base + (size_t)n * 4096]  = h[n];
        APROD[base + (size_t)n * 4096] = __expf(Af[n] * sd);
    }
}

__global__ __launch_bounds__(256) void scan_p2(
    const float* __restrict__ HEND, const float* __restrict__ APROD,
    float* __restrict__ HINIT)
{
    const int g = blockIdx.x * 256 + threadIdx.x;
    float h = 0.f;
    for (int c = 0; c < 64; ++c) {
        HINIT[(size_t)c * 65536 + g] = h;
        h = APROD[(size_t)c * 65536 + g] * h + HEND[(size_t)c * 65536 + g];
    }
}

// Pass 3: re-scan from h_init, y, gate; emit G as bf16 hi/lo.
__global__ __launch_bounds__(256) void scan_p3(
    const float* __restrict__ DELTA,
    const ushort_t* __restrict__ Uh, const ushort_t* __restrict__ Ul,
    const float* __restrict__ DBC, const float* __restrict__ RES,
    const float* __restrict__ A_log, const float* __restrict__ Dp,
    const float* __restrict__ HINIT,
    ushort_t* __restrict__ Gh, ushort_t* __restrict__ Gl)
{
    const int t = threadIdx.x;
    const int d = blockIdx.x * 256 + t;
    const int c = blockIdx.y;
    const int b = blockIdx.z;
    const int p0 = b * 2048 + c * 32;
    __shared__ float Bs[32][16];
    __shared__ float Cs[32][16];
    for (int lin = t; lin < 512; lin += 256) {
        const int s = lin >> 4, n = lin & 15;
        Bs[s][n] = DBC[(size_t)(p0 + s) * 96 + 64 + n];
        Cs[s][n] = DBC[(size_t)(p0 + s) * 96 + 80 + n];
    }
    __syncthreads();
    float Af[16];
    *(float4*)&Af[0]  = *(const float4*)&A_log[(size_t)d * 16 + 0];
    *(float4*)&Af[4]  = *(const float4*)&A_log[(size_t)d * 16 + 4];
    *(float4*)&Af[8]  = *(const float4*)&A_log[(size_t)d * 16 + 8];
    *(float4*)&Af[12] = *(const float4*)&A_log[(size_t)d * 16 + 12];
    #pragma unroll
    for (int n = 0; n < 16; ++n) Af[n] = -__expf(Af[n]);

    const size_t base = (size_t)c * 65536 + (size_t)b * 2048 + d;
    float h[16];
    #pragma unroll
    for (int n = 0; n < 16; ++n) h[n] = HINIT[base + (size_t)n * 4096];
    const float Dd = Dp[d];

    for (int s = 0; s < 32; ++s) {
        const int p = p0 + s;
        const size_t ix = (size_t)p * 2048 + d;
        const float dv = DELTA[ix];
        const float uv = bf2f(Uh[ix]) + bf2f(Ul[ix]);
        const float du = dv * uv;
        float y = 0.f;
        #pragma unroll
        for (int n = 0; n < 16; ++n) {
            h[n] = __expf(dv * Af[n]) * h[n] + du * Bs[s][n];
            y += h[n] * Cs[s][n];
        }
        const float resv = RES[ix];
        const float gv = (y + uv * Dd) * silu_f(resv);
        const unsigned short gh = f2bf(gv);
        Gh[ix] = gh;
        Gl[ix] = f2bf(gv - bf2f(gh));
    }
}

// ---------------------------------------------------------------------------
extern "C" void kernel_launch(void* const* d_in, const int* in_sizes, int n_in,
                              void* d_out, int out_size, void* d_ws, size_t ws_size,
                              hipStream_t stream) {
    const float* x      = (const float*)d_in[0];
    const float* W_in   = (const float*)d_in[1];
    const float* conv_k = (const float*)d_in[2];
    const float* conv_b = (const float*)d_in[3];
    const float* W_x    = (const float*)d_in[4];
    const float* W_dt   = (const float*)d_in[5];
    const float* b_dt   = (const float*)d_in[6];
    const float* A_log  = (const float*)d_in[7];
    const float* Dv     = (const float*)d_in[8];
    const float* W_out  = (const float*)d_in[9];
    float* out = (float*)d_out;

    // Workspace layout (same map as round 5; XSP_l slot now unused).
    char* base = (char*)d_ws;
    float*    RES      = (float*)(base);                  // 33,554,432
    ushort_t* Uh       = (ushort_t*)(base + 33554432);    // 16,777,216
    ushort_t* Ul       = (ushort_t*)(base + 50331648);    // 16,777,216
    float*    DELTA    = (float*)(base + 67108864);       // 33,554,432
    ushort_t* XSP_h    = (ushort_t*)(base + 100663296);   // 16,801,792
    float*    HEND     = (float*)(base + 100663296);      // alias over XSP (dead)
    float*    APROD    = (float*)(base + 117440512);      // alias (old XSP_l slot)
    ushort_t* x_h      = (ushort_t*)(base + 134266880);   //  8,388,608
    ushort_t* x_l      = (ushort_t*)(base + 142655488);   //  8,388,608
    ushort_t* convkT_h = (ushort_t*)(base + 151044096);   // 16,777,216
    ushort_t* G_h      = (ushort_t*)(base + 134266880);   // alias over x (dead)
    ushort_t* G_l      = (ushort_t*)(base + 151044096);   // alias over convkT (dead)
    ushort_t* WinT_h   = (ushort_t*)(base + 167821312);   //  8,388,608
    ushort_t* WoutT_h  = (ushort_t*)(base + 176209920);   //  4,194,304
    ushort_t* WxT_h    = (ushort_t*)(base + 180404224);   //    524,288
    float*    DBCP     = (float*)(base + 180928512);      //  6,291,456
    float*    DBC      = (float*)(base + 187219968);      //  1,572,864
    float*    HINIT    = (float*)(base + 188792832);      // 16,777,216

    // 0) all prep in one launch
    prep_all<<<19504, 256, 0, stream>>>(x, W_in, conv_k, W_out, W_x,
                                        x_h, x_l, WinT_h, convkT_h, WoutT_h,
                                        WxT_h, XSP_h);
    // 1) xz: xs -> XSP bf16 hi (+pad), res -> RES fp32   (swizzled 1-D grid)
    gemm2<0, 32><<<1024, 256, 0, stream>>>(x_h, x_l, WinT_h, 1024, RES, XSP_h);
    // 2) u = silu(conv + b) -> Uh/Ul   (A hi-only, swizzled 1-D grid)
    conv2<<<512, 256, 0, stream>>>(XSP_h, convkT_h, conv_b, Uh, Ul);
    // 3) dbc = U @ W_x, split-K x4 + reduce
    gemm2<2, 4><<<dim3(4, 32), 256, 0, stream>>>(Uh, Ul, WxT_h, 2048, DBCP, nullptr);
    dbc_reduce<<<1536, 256, 0, stream>>>(DBCP, DBC);
    // 4) delta
    delta_kernel<<<dim3(8, 256), 256, 0, stream>>>(DBC, W_dt, b_dt, DELTA);
    // 5) chunked scan
    scan_p1<<<dim3(8, 64, 2), 256, 0, stream>>>(DELTA, Uh, Ul, DBC, A_log, HEND, APROD);
    scan_p2<<<256, 256, 0, stream>>>(HEND, APROD, HINIT);
    scan_p3<<<dim3(8, 64, 2), 256, 0, stream>>>(DELTA, Uh, Ul, DBC, RES, A_log, Dv,
                                                HINIT, G_h, G_l);
    // 6) out = G @ W_out   (swizzled 1-D grid)
    gemm2<1, 8><<<256, 256, 0, stream>>>(G_h, G_l, WoutT_h, 2048, out, nullptr);
}

// Round 7
// 494.336 us; speedup vs baseline: 6.7829x; 1.0422x over previous
//
#include <hip/hip_runtime.h>
#include <math.h>

// B=2, L=2048, D_MODEL=1024, D_INNER=2048, D_STATE=16, DT_RANK=64, D_CONV=4
// P = B*L = 4096

typedef unsigned short ushort_t;
typedef unsigned int uint_t;
typedef __bf16 bf16x8 __attribute__((ext_vector_type(8)));
typedef float floatx4 __attribute__((ext_vector_type(4)));

#define LDS_STRIDE 40   // 32 + 8 pad shorts: 80B rows, 16B aligned, 2-way-only conflicts

__device__ __forceinline__ float silu_f(float x) { return x / (1.0f + __expf(-x)); }

__device__ __forceinline__ unsigned short f2bf(float f) {
    unsigned u = __float_as_uint(f);
    unsigned r = u + 0x7fffu + ((u >> 16) & 1u);   // RNE (finite values only)
    return (unsigned short)(r >> 16);
}
__device__ __forceinline__ float bf2f(unsigned short h) {
    return __uint_as_float(((unsigned)h) << 16);
}
// pack fp32 -> (hi bf16) | (lo bf16 << 16)
__device__ __forceinline__ uint_t packhl(float v) {
    const unsigned short h = f2bf(v);
    const unsigned short l = f2bf(v - bf2f(h));
    return (uint_t)h | ((uint_t)l << 16);
}
// unpack sum
__device__ __forceinline__ float unpack_sum(uint_t pk) {
    return __uint_as_float(pk << 16) + __uint_as_float(pk & 0xffff0000u);
}
// 8 packed elems (2 uint4) -> 8 hi shorts + 8 lo shorts (uint4 each)
__device__ __forceinline__ void unpack8(uint4 w0, uint4 w1, uint4& H, uint4& L) {
    H.x = (w0.x & 0xffffu) | (w0.y << 16);  L.x = (w0.x >> 16) | (w0.y & 0xffff0000u);
    H.y = (w0.z & 0xffffu) | (w0.w << 16);  L.y = (w0.z >> 16) | (w0.w & 0xffff0000u);
    H.z = (w1.x & 0xffffu) | (w1.y << 16);  L.z = (w1.x >> 16) | (w1.y & 0xffff0000u);
    H.w = (w1.z & 0xffffu) | (w1.w << 16);  L.w = (w1.z >> 16) | (w1.w & 0xffff0000u);
}

// ---------------------------------------------------------------------------
// Mega prep kernel (block-range switch):
//  [0,4096)      : x fp32 -> xpk (packed hi|lo)
//  [4096,8192)   : W_in   [1024][4096] -> WinT_h  [4096][1024] (hi only)
//  [8192,16384)  : conv_k [4096][2048] -> convkT_h[2048][4096] (hi only)
//  [16384,18432) : W_out  [2048][1024] -> WoutT_h [1024][2048] (hi only)
//  [18432,19456) : W_x    [2048][96]   -> WxT_h   [128][2048]  (pad rows 96..127)
//  [19456,19504) : zero XSP_h causal pad rows
// ---------------------------------------------------------------------------
__global__ __launch_bounds__(256) void prep_all(
    const float* __restrict__ x, const float* __restrict__ W_in,
    const float* __restrict__ conv_k, const float* __restrict__ W_out,
    const float* __restrict__ W_x,
    uint_t* __restrict__ xpk,
    ushort_t* __restrict__ WinT_h, ushort_t* __restrict__ convkT_h,
    ushort_t* __restrict__ WoutT_h, ushort_t* __restrict__ WxT_h,
    ushort_t* __restrict__ XSP_h)
{
    __shared__ float ts[32][33];
    const int bid = blockIdx.x;
    const int t = threadIdx.x;
    if (bid < 4096) {
        const size_t i4 = ((size_t)bid * 256 + t) * 4;
        float4 v = *(const float4*)&x[i4];
        uint4 pk;
        pk.x = packhl(v.x); pk.y = packhl(v.y); pk.z = packhl(v.z); pk.w = packhl(v.w);
        *(uint4*)&xpk[i4] = pk;
        return;
    }
    if (bid >= 18432 && bid < 19456) {
        const int idx = (bid - 18432) * 256 + t;
        const int r = idx >> 11, k = idx & 2047;
        float v = (r < 96) ? W_x[(size_t)k * 96 + r] : 0.f;
        WxT_h[idx] = f2bf(v);
        return;
    }
    if (bid >= 19456) {
        const int idx = (bid - 19456) * 256 + t;   // < 12288
        const int b = idx / 6144, rem = idx % 6144;
        const int lp = rem >> 11, c = rem & 2047;
        XSP_h[((size_t)b * 2051 + lp) * 2048 + c] = 0;
        return;
    }
    // transpose-hi cases
    const float* src; int R, C; ushort_t* dst; int bx, by;
    if (bid < 8192)       { src = W_in;   R = 1024; C = 4096; dst = WinT_h;
                            int l = bid - 4096;  bx = l & 127; by = l >> 7; }
    else if (bid < 16384) { src = conv_k; R = 4096; C = 2048; dst = convkT_h;
                            int l = bid - 8192;  bx = l & 63;  by = l >> 6; }
    else                  { src = W_out;  R = 2048; C = 1024; dst = WoutT_h;
                            int l = bid - 16384; bx = l & 31;  by = l >> 5; }
    const int tx = t & 31, ty = t >> 5;
    const int r0 = by * 32, c0 = bx * 32;
    #pragma unroll
    for (int j = 0; j < 4; ++j)
        ts[ty + j * 8][tx] = src[(size_t)(r0 + ty + j * 8) * C + c0 + tx];
    __syncthreads();
    #pragma unroll
    for (int j = 0; j < 4; ++j)
        dst[(size_t)(c0 + ty + j * 8) * R + r0 + tx] = f2bf(ts[tx][ty + j * 8]);
}

// ---------------------------------------------------------------------------
// 2-term split-bf16 MFMA GEMM, packed A: C = A @ B.
// A packed hi|lo [M][Kfull]; B hi [N][Kfull]. 128x128 tile, BK=32,
// 4 waves x (4x4) 16x16x32 tiles, 2 MFMAs per tile (AhB + AlB).
// Swizzle (modes 0/1): xcd=lin&7 owns 4 contiguous row-tiles (by=xcd*4+byl),
// bx-outer by-inner => A slab + B slab L2-resident.
// MODE 0 (xz): cols<2048 -> XSP_h bf16 (+3-row causal pad); else RES fp32.
// MODE 1 (out): fp32 store ldc=1024.
// MODE 2 (dbc): 2-D grid, split-K (blockIdx.x = 512-wide k-seg), cols<96.
// ---------------------------------------------------------------------------
template<int MODE>
__global__ __launch_bounds__(256) void gemm2(
    const uint_t* __restrict__ Apk, const ushort_t* __restrict__ Bh, int Kfull,
    float* __restrict__ Cf, ushort_t* __restrict__ Oh)
{
    __shared__ __align__(16) ushort_t As_h[128 * LDS_STRIDE];
    __shared__ __align__(16) ushort_t As_l[128 * LDS_STRIDE];
    __shared__ __align__(16) ushort_t Bs_h[128 * LDS_STRIDE];
    const int t = threadIdx.x;
    int bx, by;
    if (MODE == 2) { bx = blockIdx.x; by = blockIdx.y; }
    else {
        const int lin = blockIdx.x, xcd = lin & 7, s = lin >> 3;
        bx = s >> 2;                 // MODE0: 0..31, MODE1: 0..7
        by = xcd * 4 + (s & 3);
    }
    const int m0 = by * 128;
    const int n0 = (MODE == 2) ? 0 : bx * 128;
    const int kbeg = (MODE == 2) ? bx * 512 : 0;
    const int kend = (MODE == 2) ? kbeg + 512 : Kfull;
    const int lane = t & 63, wave = t >> 6;
    const int wm = (wave >> 1) * 64, wn = (wave & 1) * 64;
    const int m16 = lane & 15, q = lane >> 4;
    const int r_0 = t >> 2, cc_0 = (t & 3) * 8;
    const int r_1 = (t + 256) >> 2, cc_1 = ((t + 256) & 3) * 8;

    uint4 a00 = *(const uint4*)&Apk[(size_t)(m0 + r_0) * Kfull + kbeg + cc_0];
    uint4 a01 = *(const uint4*)&Apk[(size_t)(m0 + r_0) * Kfull + kbeg + cc_0 + 4];
    uint4 a10 = *(const uint4*)&Apk[(size_t)(m0 + r_1) * Kfull + kbeg + cc_1];
    uint4 a11 = *(const uint4*)&Apk[(size_t)(m0 + r_1) * Kfull + kbeg + cc_1 + 4];
    uint4 pb0 = *(const uint4*)&Bh[(size_t)(n0 + r_0) * Kfull + kbeg + cc_0];
    uint4 pb1 = *(const uint4*)&Bh[(size_t)(n0 + r_1) * Kfull + kbeg + cc_1];

    floatx4 acc[4][4];
    const floatx4 zz = {0.f, 0.f, 0.f, 0.f};
    #pragma unroll
    for (int i = 0; i < 4; ++i)
        #pragma unroll
        for (int j = 0; j < 4; ++j) acc[i][j] = zz;

    for (int k0 = kbeg; k0 < kend; k0 += 32) {
        uint4 H, L;
        unpack8(a00, a01, H, L);
        *(uint4*)&As_h[r_0 * LDS_STRIDE + cc_0] = H;
        *(uint4*)&As_l[r_0 * LDS_STRIDE + cc_0] = L;
        unpack8(a10, a11, H, L);
        *(uint4*)&As_h[r_1 * LDS_STRIDE + cc_1] = H;
        *(uint4*)&As_l[r_1 * LDS_STRIDE + cc_1] = L;
        *(uint4*)&Bs_h[r_0 * LDS_STRIDE + cc_0] = pb0;
        *(uint4*)&Bs_h[r_1 * LDS_STRIDE + cc_1] = pb1;
        __syncthreads();
        if (k0 + 32 < kend) {
            const int kn = k0 + 32;
            a00 = *(const uint4*)&Apk[(size_t)(m0 + r_0) * Kfull + kn + cc_0];
            a01 = *(const uint4*)&Apk[(size_t)(m0 + r_0) * Kfull + kn + cc_0 + 4];
            a10 = *(const uint4*)&Apk[(size_t)(m0 + r_1) * Kfull + kn + cc_1];
            a11 = *(const uint4*)&Apk[(size_t)(m0 + r_1) * Kfull + kn + cc_1 + 4];
            pb0 = *(const uint4*)&Bh[(size_t)(n0 + r_0) * Kfull + kn + cc_0];
            pb1 = *(const uint4*)&Bh[(size_t)(n0 + r_1) * Kfull + kn + cc_1];
        }
        bf16x8 ah[4], al[4], bh[4];
        #pragma unroll
        for (int i = 0; i < 4; ++i) {
            const int off = (wm + i * 16 + m16) * LDS_STRIDE + q * 8;
            ah[i] = *(const bf16x8*)&As_h[off];
            al[i] = *(const bf16x8*)&As_l[off];
        }
        #pragma unroll
        for (int j = 0; j < 4; ++j)
            bh[j] = *(const bf16x8*)&Bs_h[(wn + j * 16 + m16) * LDS_STRIDE + q * 8];
        #pragma unroll
        for (int i = 0; i < 4; ++i)
            #pragma unroll
            for (int j = 0; j < 4; ++j) {
                acc[i][j] = __builtin_amdgcn_mfma_f32_16x16x32_bf16(ah[i], bh[j], acc[i][j], 0, 0, 0);
                acc[i][j] = __builtin_amdgcn_mfma_f32_16x16x32_bf16(al[i], bh[j], acc[i][j], 0, 0, 0);
            }
        __syncthreads();
    }

    float* Cp = (MODE == 2) ? (Cf + (size_t)bx * 393216) : Cf;
    #pragma unroll
    for (int i = 0; i < 4; ++i) {
        const int row_b = m0 + wm + i * 16 + q * 4;
        #pragma unroll
        for (int j = 0; j < 4; ++j) {
            const int col = n0 + wn + j * 16 + m16;
            #pragma unroll
            for (int rr = 0; rr < 4; ++rr) {
                const int row = row_b + rr;
                const float v = acc[i][j][rr];
                if (MODE == 0) {
                    if (n0 < 2048) {
                        const int b = row >> 11, l = row & 2047;
                        Oh[((size_t)b * 2051 + l + 3) * 2048 + col] = f2bf(v);
                    } else {
                        Cp[(size_t)row * 2048 + (col - 2048)] = v;
                    }
                } else if (MODE == 1) {
                    Cp[(size_t)row * 1024 + col] = v;
                } else {
                    if (col < 96) Cp[(size_t)row * 96 + col] = v;
                }
            }
        }
    }
}

// ---------------------------------------------------------------------------
// Conv as plain-bf16 MFMA GEMM (A hi-only). A[p][k=w*1024+i] =
// XSP_h[b][l+w][g*1024+i] (3-row zero pad). B = convkT_h [2048][4096].
// Swizzle: per XCD 2 sweeps x (16 bx x 2 by) -> 2 A-slabs + 1 B-slab in L2.
// Epilogue: u = silu(acc+bias) -> Upk (packed hi|lo).
// ---------------------------------------------------------------------------
__global__ __launch_bounds__(256) void conv2(
    const ushort_t* __restrict__ Xh, const ushort_t* __restrict__ Bh,
    const float* __restrict__ bias, uint_t* __restrict__ Upk)
{
    __shared__ __align__(16) ushort_t As_h[128 * LDS_STRIDE];
    __shared__ __align__(16) ushort_t Bs_h[128 * LDS_STRIDE];
    const int t = threadIdx.x;
    const int lin = blockIdx.x, xcd = lin & 7, s = lin >> 3;   // s in [0,64)
    const int sweep = s >> 5, r = s & 31;
    const int bxp = r >> 1;
    const int by = xcd * 4 + ((sweep << 1) | (r & 1));
    const int m0 = by * 128, n0 = bxp * 128;
    const int g1024 = (n0 >= 1024) ? 1024 : 0;
    const int lane = t & 63, wave = t >> 6;
    const int wm = (wave >> 1) * 64, wn = (wave & 1) * 64;
    const int m16 = lane & 15, q = lane >> 4;
    const int r_0 = t >> 2, cc_0 = (t & 3) * 8;
    const int r_1 = (t + 256) >> 2, cc_1 = ((t + 256) & 3) * 8;
    const int p_0 = m0 + r_0, b_0 = p_0 >> 11, l_0 = p_0 & 2047;
    const int p_1 = m0 + r_1, b_1 = p_1 >> 11, l_1 = p_1 & 2047;

    auto aA = [&](int bb, int ll, int k0, int cc) -> size_t {
        const int w = k0 >> 10;
        const int i = (k0 & 1023) + cc;
        return ((size_t)bb * 2051 + ll + w) * 2048 + g1024 + i;
    };

    uint4 pa0 = *(const uint4*)&Xh[aA(b_0, l_0, 0, cc_0)];
    uint4 pa1 = *(const uint4*)&Xh[aA(b_1, l_1, 0, cc_1)];
    uint4 pb0 = *(const uint4*)&Bh[(size_t)(n0 + r_0) * 4096 + cc_0];
    uint4 pb1 = *(const uint4*)&Bh[(size_t)(n0 + r_1) * 4096 + cc_1];

    floatx4 acc[4][4];
    const floatx4 zz = {0.f, 0.f, 0.f, 0.f};
    #pragma unroll
    for (int i = 0; i < 4; ++i)
        #pragma unroll
        for (int j = 0; j < 4; ++j) acc[i][j] = zz;

    for (int k0 = 0; k0 < 4096; k0 += 32) {
        *(uint4*)&As_h[r_0 * LDS_STRIDE + cc_0] = pa0;
        *(uint4*)&As_h[r_1 * LDS_STRIDE + cc_1] = pa1;
        *(uint4*)&Bs_h[r_0 * LDS_STRIDE + cc_0] = pb0;
        *(uint4*)&Bs_h[r_1 * LDS_STRIDE + cc_1] = pb1;
        __syncthreads();
        if (k0 + 32 < 4096) {
            const int kn = k0 + 32;
            pa0 = *(const uint4*)&Xh[aA(b_0, l_0, kn, cc_0)];
            pa1 = *(const uint4*)&Xh[aA(b_1, l_1, kn, cc_1)];
            pb0 = *(const uint4*)&Bh[(size_t)(n0 + r_0) * 4096 + kn + cc_0];
            pb1 = *(const uint4*)&Bh[(size_t)(n0 + r_1) * 4096 + kn + cc_1];
        }
        bf16x8 ah[4], bh[4];
        #pragma unroll
        for (int i = 0; i < 4; ++i)
            ah[i] = *(const bf16x8*)&As_h[(wm + i * 16 + m16) * LDS_STRIDE + q * 8];
        #pragma unroll
        for (int j = 0; j < 4; ++j)
            bh[j] = *(const bf16x8*)&Bs_h[(wn + j * 16 + m16) * LDS_STRIDE + q * 8];
        #pragma unroll
        for (int i = 0; i < 4; ++i)
            #pragma unroll
            for (int j = 0; j < 4; ++j)
                acc[i][j] = __builtin_amdgcn_mfma_f32_16x16x32_bf16(ah[i], bh[j], acc[i][j], 0, 0, 0);
        __syncthreads();
    }

    #pragma unroll
    for (int i = 0; i < 4; ++i) {
        const int row_b = m0 + wm + i * 16 + q * 4;
        #pragma unroll
        for (int j = 0; j < 4; ++j) {
            const int col = n0 + wn + j * 16 + m16;
            const float bz = bias[col];
            #pragma unroll
            for (int rr = 0; rr < 4; ++rr) {
                const int row = row_b + rr;
                const float v = silu_f(acc[i][j][rr] + bz);
                Upk[(size_t)row * 2048 + col] = packhl(v);
            }
        }
    }
}

// Sum the 4 split-K partials of dbc.
__global__ __launch_bounds__(256) void dbc_reduce(
    const float* __restrict__ DBCP, float* __restrict__ DBC)
{
    const int i = blockIdx.x * 256 + threadIdx.x;   // < 393216
    DBC[i] = (DBCP[i] + DBCP[393216 + i]) + (DBCP[786432 + i] + DBCP[1179648 + i]);
}

// ---------------------------------------------------------------------------
// delta[p,d] = clip(softplus(dbc[p,0:64] @ W_dt[:,d] + b_dt[d]), 1e-3, 1e-1)
// ---------------------------------------------------------------------------
__global__ __launch_bounds__(256) void delta_kernel(
    const float* __restrict__ DBC, const float* __restrict__ W_dt,
    const float* __restrict__ b_dt, float* __restrict__ DELTA)
{
    const int n  = blockIdx.x * 256 + threadIdx.x;
    const int p0 = blockIdx.y * 16;
    const int t  = threadIdx.x;
    __shared__ float dt_s[16][64];
    #pragma unroll
    for (int j = 0; j < 4; ++j) {
        const int lin = j * 256 + t;
        const int r = lin >> 6, k = lin & 63;
        dt_s[r][k] = DBC[(size_t)(p0 + r) * 96 + k];
    }
    __syncthreads();
    float acc[16];
    const float bz = b_dt[n];
    #pragma unroll
    for (int r = 0; r < 16; ++r) acc[r] = bz;
    for (int k = 0; k < 64; ++k) {
        const float wv = W_dt[(size_t)k * 2048 + n];
        #pragma unroll
        for (int r = 0; r < 16; ++r) acc[r] += dt_s[r][k] * wv;
    }
    #pragma unroll
    for (int r = 0; r < 16; ++r) {
        float a = acc[r];
        float sp = (a > 20.f) ? a : log1pf(expf(a));
        sp = fminf(fmaxf(sp, 0.001f), 0.1f);
        DELTA[(size_t)(p0 + r) * 2048 + n] = sp;
    }
}

// ---------------------------------------------------------------------------
// Chunked scan (64 chunks of 32). Aux layout: HEND/HINIT [c][b][d][16n]
// (coalesced 64B per thread); SD[c][b][d] scalar (APROD recomputed in p2).
// ---------------------------------------------------------------------------
__global__ __launch_bounds__(256) void scan_p1(
    const float* __restrict__ DELTA, const uint_t* __restrict__ Upk,
    const float* __restrict__ DBC, const float* __restrict__ A_log,
    float* __restrict__ HEND, float* __restrict__ SD)
{
    const int t = threadIdx.x;
    const int d = blockIdx.x * 256 + t;
    const int c = blockIdx.y;
    const int b = blockIdx.z;
    const int p0 = b * 2048 + c * 32;
    __shared__ float Bs[32][16];
    for (int lin = t; lin < 512; lin += 256) {
        const int s = lin >> 4, n = lin & 15;
        Bs[s][n] = DBC[(size_t)(p0 + s) * 96 + 64 + n];
    }
    __syncthreads();
    float Af[16];
    *(float4*)&Af[0]  = *(const float4*)&A_log[(size_t)d * 16 + 0];
    *(float4*)&Af[4]  = *(const float4*)&A_log[(size_t)d * 16 + 4];
    *(float4*)&Af[8]  = *(const float4*)&A_log[(size_t)d * 16 + 8];
    *(float4*)&Af[12] = *(const float4*)&A_log[(size_t)d * 16 + 12];
    #pragma unroll
    for (int n = 0; n < 16; ++n) Af[n] = -__expf(Af[n]);

    float h[16] = {};
    float sd = 0.f;
    for (int s = 0; s < 32; ++s) {
        const size_t ix = (size_t)(p0 + s) * 2048 + d;
        const float dv = DELTA[ix];
        const float uv = unpack_sum(Upk[ix]);
        const float du = dv * uv;
        sd += dv;
        #pragma unroll
        for (int n = 0; n < 16; ++n)
            h[n] = __expf(dv * Af[n]) * h[n] + du * Bs[s][n];
    }
    const size_t hb = (((size_t)c * 2 + b) * 2048 + d) * 16;
    *(float4*)&HEND[hb + 0]  = *(float4*)&h[0];
    *(float4*)&HEND[hb + 4]  = *(float4*)&h[4];
    *(float4*)&HEND[hb + 8]  = *(float4*)&h[8];
    *(float4*)&HEND[hb + 12] = *(float4*)&h[12];
    SD[((size_t)c * 2 + b) * 2048 + d] = sd;
}

__global__ __launch_bounds__(256) void scan_p2(
    const float* __restrict__ HEND, const float* __restrict__ SD,
    const float* __restrict__ A_log, float* __restrict__ HINIT)
{
    const int g = blockIdx.x * 256 + threadIdx.x;   // < 65536
    const int n = g & 15, d = (g >> 4) & 2047, b = (g >> 15) & 1;
    const float Af = -__expf(A_log[(size_t)d * 16 + n]);
    float h = 0.f;
    #pragma unroll 8
    for (int c = 0; c < 64; ++c) {
        const size_t cb = (size_t)c * 2 + b;
        const size_t idx = (cb * 2048 + d) * 16 + n;
        HINIT[idx] = h;
        h = __expf(Af * SD[cb * 2048 + d]) * h + HEND[idx];
    }
}

// Pass 3: re-scan from h_init, y, gate; emit G packed hi|lo.
__global__ __launch_bounds__(256) void scan_p3(
    const float* __restrict__ DELTA, const uint_t* __restrict__ Upk,
    const float* __restrict__ DBC, const float* __restrict__ RES,
    const float* __restrict__ A_log, const float* __restrict__ Dp,
    const float* __restrict__ HINIT, uint_t* __restrict__ Gpk)
{
    const int t = threadIdx.x;
    const int d = blockIdx.x * 256 + t;
    const int c = blockIdx.y;
    const int b = blockIdx.z;
    const int p0 = b * 2048 + c * 32;
    __shared__ float Bs[32][16];
    __shared__ float Cs[32][16];
    for (int lin = t; lin < 512; lin += 256) {
        const int s = lin >> 4, n = lin & 15;
        Bs[s][n] = DBC[(size_t)(p0 + s) * 96 + 64 + n];
        Cs[s][n] = DBC[(size_t)(p0 + s) * 96 + 80 + n];
    }
    __syncthreads();
    float Af[16];
    *(float4*)&Af[0]  = *(const float4*)&A_log[(size_t)d * 16 + 0];
    *(float4*)&Af[4]  = *(const float4*)&A_log[(size_t)d * 16 + 4];
    *(float4*)&Af[8]  = *(const float4*)&A_log[(size_t)d * 16 + 8];
    *(float4*)&Af[12] = *(const float4*)&A_log[(size_t)d * 16 + 12];
    #pragma unroll
    for (int n = 0; n < 16; ++n) Af[n] = -__expf(Af[n]);

    const size_t hb = (((size_t)c * 2 + b) * 2048 + d) * 16;
    float h[16];
    *(float4*)&h[0]  = *(const float4*)&HINIT[hb + 0];
    *(float4*)&h[4]  = *(const float4*)&HINIT[hb + 4];
    *(float4*)&h[8]  = *(const float4*)&HINIT[hb + 8];
    *(float4*)&h[12] = *(const float4*)&HINIT[hb + 12];
    const float Dd = Dp[d];

    for (int s = 0; s < 32; ++s) {
        const int p = p0 + s;
        const size_t ix = (size_t)p * 2048 + d;
        const float dv = DELTA[ix];
        const float uv = unpack_sum(Upk[ix]);
        const float du = dv * uv;
        float y = 0.f;
        #pragma unroll
        for (int n = 0; n < 16; ++n) {
            h[n] = __expf(dv * Af[n]) * h[n] + du * Bs[s][n];
            y += h[n] * Cs[s][n];
        }
        const float resv = RES[ix];
        const float gv = (y + uv * Dd) * silu_f(resv);
        Gpk[ix] = packhl(gv);
    }
}

// ---------------------------------------------------------------------------
extern "C" void kernel_launch(void* const* d_in, const int* in_sizes, int n_in,
                              void* d_out, int out_size, void* d_ws, size_t ws_size,
                              hipStream_t stream) {
    const float* x      = (const float*)d_in[0];
    const float* W_in   = (const float*)d_in[1];
    const float* conv_k = (const float*)d_in[2];
    const float* conv_b = (const float*)d_in[3];
    const float* W_x    = (const float*)d_in[4];
    const float* W_dt   = (const float*)d_in[5];
    const float* b_dt   = (const float*)d_in[6];
    const float* A_log  = (const float*)d_in[7];
    const float* Dv     = (const float*)d_in[8];
    const float* W_out  = (const float*)d_in[9];
    float* out = (float*)d_out;

    // Workspace layout (total ~190 MB, < previous 219.7 MB usage).
    char* base = (char*)d_ws;
    float*    RES      = (float*)(base);                  // 33,554,432
    uint_t*   Upk      = (uint_t*)(base + 33554432);      // 33,554,432
    float*    DELTA    = (float*)(base + 67108864);       // 33,554,432
    ushort_t* XSP_h    = (ushort_t*)(base + 100663296);   // 16,801,792 (2 x 2051 x 2048)
    float*    HEND     = (float*)(base + 100663296);      // alias over XSP (dead after conv2)
    uint_t*   xpk      = (uint_t*)(base + 117465088);     // 16,777,216
    ushort_t* convkT_h = (ushort_t*)(base + 134242304);   // 16,777,216
    uint_t*   Gpk      = (uint_t*)(base + 117465088);     // alias over xpk+convkT (dead)
    ushort_t* WinT_h   = (ushort_t*)(base + 151019520);   //  8,388,608
    ushort_t* WoutT_h  = (ushort_t*)(base + 159408128);   //  4,194,304
    ushort_t* WxT_h    = (ushort_t*)(base + 163602432);   //    524,288
    float*    DBCP     = (float*)(base + 164126720);      //  6,291,456
    float*    DBC      = (float*)(base + 170418176);      //  1,572,864
    float*    SD       = (float*)(base + 171991040);      //  1,048,576
    float*    HINIT    = (float*)(base + 173039616);      // 16,777,216

    // 0) all prep in one launch
    prep_all<<<19504, 256, 0, stream>>>(x, W_in, conv_k, W_out, W_x,
                                        xpk, WinT_h, convkT_h, WoutT_h,
                                        WxT_h, XSP_h);
    // 1) xz: xs -> XSP bf16 hi (+pad), res -> RES fp32   (swizzled 1-D grid)
    gemm2<0><<<1024, 256, 0, stream>>>(xpk, WinT_h, 1024, RES, XSP_h);
    // 2) u = silu(conv + b) -> Upk   (A hi-only, sweep-swizzled 1-D grid)
    conv2<<<512, 256, 0, stream>>>(XSP_h, convkT_h, conv_b, Upk);
    // 3) dbc = U @ W_x, split-K x4 + reduce
    gemm2<2><<<dim3(4, 32), 256, 0, stream>>>(Upk, WxT_h, 2048, DBCP, nullptr);
    dbc_reduce<<<1536, 256, 0, stream>>>(DBCP, DBC);
    // 4) delta
    delta_kernel<<<dim3(8, 256), 256, 0, stream>>>(DBC, W_dt, b_dt, DELTA);
    // 5) chunked scan
    scan_p1<<<dim3(8, 64, 2), 256, 0, stream>>>(DELTA, Upk, DBC, A_log, HEND, SD);
    scan_p2<<<256, 256, 0, stream>>>(HEND, SD, A_log, HINIT);
    scan_p3<<<dim3(8, 64, 2), 256, 0, stream>>>(DELTA, Upk, DBC, RES, A_log, Dv,
                                                HINIT, Gpk);
    // 6) out = G @ W_out   (swizzled 1-D grid)
    gemm2<1><<<256, 256, 0, stream>>>(Gpk, WoutT_h, 2048, out, nullptr);
}

// Round 8
// 491.484 us; speedup vs baseline: 6.8223x; 1.0058x over previous
//
#include <hip/hip_runtime.h>
#include <math.h>

// B=2, L=2048, D_MODEL=1024, D_INNER=2048, D_STATE=16, DT_RANK=64, D_CONV=4
// P = B*L = 4096

typedef unsigned short ushort_t;
typedef unsigned int uint_t;
typedef __bf16 bf16x8 __attribute__((ext_vector_type(8)));
typedef float floatx4 __attribute__((ext_vector_type(4)));

#define LDS_STRIDE 40   // 32 + 8 pad shorts

__device__ __forceinline__ float silu_f(float x) { return x / (1.0f + __expf(-x)); }

__device__ __forceinline__ unsigned short f2bf(float f) {
    unsigned u = __float_as_uint(f);
    unsigned r = u + 0x7fffu + ((u >> 16) & 1u);   // RNE (finite values only)
    return (unsigned short)(r >> 16);
}
__device__ __forceinline__ float bf2f(unsigned short h) {
    return __uint_as_float(((unsigned)h) << 16);
}
__device__ __forceinline__ uint_t packhl(float v) {
    const unsigned short h = f2bf(v);
    const unsigned short l = f2bf(v - bf2f(h));
    return (uint_t)h | ((uint_t)l << 16);
}
__device__ __forceinline__ float unpack_sum(uint_t pk) {
    return __uint_as_float(pk << 16) + __uint_as_float(pk & 0xffff0000u);
}
__device__ __forceinline__ void unpack8(uint4 w0, uint4 w1, uint4& H, uint4& L) {
    H.x = (w0.x & 0xffffu) | (w0.y << 16);  L.x = (w0.x >> 16) | (w0.y & 0xffff0000u);
    H.y = (w0.z & 0xffffu) | (w0.w << 16);  L.y = (w0.z >> 16) | (w0.w & 0xffff0000u);
    H.z = (w1.x & 0xffffu) | (w1.y << 16);  L.z = (w1.x >> 16) | (w1.y & 0xffff0000u);
    H.w = (w1.z & 0xffffu) | (w1.w << 16);  L.w = (w1.z >> 16) | (w1.w & 0xffff0000u);
}
// MFMA B-fragment-ordered address for B^T matrix [N][K]:
// lane (m16 + 16*q) of tile (n16, kc) holds B^T[n16*16+m16][kc*32+q*8 .. +8]
__device__ __forceinline__ size_t faddr(int n, int k, int KC) {
    return ((size_t)((n >> 4) * KC + (k >> 5)) * 64 + (n & 15) + (((k >> 3) & 3) << 4)) * 8
           + (k & 7);
}

// ---------------------------------------------------------------------------
// Mega prep kernel (block-range switch). All B-operands written in
// MFMA-fragment order (bf16 hi only).
// ---------------------------------------------------------------------------
__global__ __launch_bounds__(256) void prep_all(
    const float* __restrict__ x, const float* __restrict__ W_in,
    const float* __restrict__ conv_k, const float* __restrict__ W_out,
    const float* __restrict__ W_x,
    uint_t* __restrict__ xpk,
    ushort_t* __restrict__ WinF, ushort_t* __restrict__ convkF,
    ushort_t* __restrict__ WoutF, ushort_t* __restrict__ WxF,
    ushort_t* __restrict__ XSP_h)
{
    __shared__ float ts[32][33];
    const int bid = blockIdx.x;
    const int t = threadIdx.x;
    if (bid < 4096) {
        const size_t i4 = ((size_t)bid * 256 + t) * 4;
        float4 v = *(const float4*)&x[i4];
        uint4 pk;
        pk.x = packhl(v.x); pk.y = packhl(v.y); pk.z = packhl(v.z); pk.w = packhl(v.w);
        *(uint4*)&xpk[i4] = pk;
        return;
    }
    if (bid >= 18432 && bid < 19456) {
        const int idx = (bid - 18432) * 256 + t;
        const int r = idx >> 11, k = idx & 2047;
        float v = (r < 96) ? W_x[(size_t)k * 96 + r] : 0.f;
        WxF[faddr(r, k, 64)] = f2bf(v);
        return;
    }
    if (bid >= 19456) {
        const int idx = (bid - 19456) * 256 + t;   // < 12288
        const int b = idx / 6144, rem = idx % 6144;
        const int lp = rem >> 11, c = rem & 2047;
        XSP_h[((size_t)b * 2051 + lp) * 2048 + c] = 0;
        return;
    }
    // transpose + fragment-order cases (dst is B^T [N=C][K=R])
    const float* src; int R, C, KC; ushort_t* dst; int bx, by;
    if (bid < 8192)       { src = W_in;   R = 1024; C = 4096; KC = 32;  dst = WinF;
                            int l = bid - 4096;  bx = l & 127; by = l >> 7; }
    else if (bid < 16384) { src = conv_k; R = 4096; C = 2048; KC = 128; dst = convkF;
                            int l = bid - 8192;  bx = l & 63;  by = l >> 6; }
    else                  { src = W_out;  R = 2048; C = 1024; KC = 64;  dst = WoutF;
                            int l = bid - 16384; bx = l & 31;  by = l >> 5; }
    const int tx = t & 31, ty = t >> 5;
    const int r0 = by * 32, c0 = bx * 32;
    #pragma unroll
    for (int j = 0; j < 4; ++j)
        ts[ty + j * 8][tx] = src[(size_t)(r0 + ty + j * 8) * C + c0 + tx];
    __syncthreads();
    #pragma unroll
    for (int j = 0; j < 4; ++j) {
        const int n = c0 + ty + j * 8, k = r0 + tx;
        dst[faddr(n, k, KC)] = f2bf(ts[tx][ty + j * 8]);
    }
}

// ---------------------------------------------------------------------------
// 2-term split-bf16 MFMA GEMM, packed A, fragment-ordered direct-global B.
// A packed hi|lo [M][Kfull]; Bf fragment-ordered. 128x128 tile, BK=32,
// 4 waves x (4x4) 16x16x32 tiles, 2 MFMAs per tile (AhB + AlB).
// Only A goes through LDS; B frags are coalesced global dwordx4, prefetched
// one chunk ahead.
// MODE 0 (xz): cols<2048 -> XSP_h bf16 (+3-row causal pad); else RES fp32.
// MODE 1 (out): fp32 store ldc=1024.   MODE 2 (dbc): split-K, cols<96.
// ---------------------------------------------------------------------------
template<int MODE>
__global__ __launch_bounds__(256) void gemm2(
    const uint_t* __restrict__ Apk, const ushort_t* __restrict__ Bf, int Kfull,
    float* __restrict__ Cf, ushort_t* __restrict__ Oh)
{
    __shared__ __align__(16) ushort_t As_h[128 * LDS_STRIDE];
    __shared__ __align__(16) ushort_t As_l[128 * LDS_STRIDE];
    const int t = threadIdx.x;
    int bx, by;
    if (MODE == 2) { bx = blockIdx.x; by = blockIdx.y; }
    else {
        const int lin = blockIdx.x, xcd = lin & 7, s = lin >> 3;
        bx = s >> 2;
        by = xcd * 4 + (s & 3);
    }
    const int m0 = by * 128;
    const int n0 = (MODE == 2) ? 0 : bx * 128;
    const int kbeg = (MODE == 2) ? bx * 512 : 0;
    const int kend = (MODE == 2) ? kbeg + 512 : Kfull;
    const int KC = Kfull >> 5;
    const int lane = t & 63, wave = t >> 6;
    const int wm = (wave >> 1) * 64, wn = (wave & 1) * 64;
    const int m16 = lane & 15, q = lane >> 4;
    const int n16b = (n0 + wn) >> 4;
    const int r_0 = t >> 2, cc_0 = (t & 3) * 8;
    const int r_1 = (t + 256) >> 2, cc_1 = ((t + 256) & 3) * 8;

    uint4 a00 = *(const uint4*)&Apk[(size_t)(m0 + r_0) * Kfull + kbeg + cc_0];
    uint4 a01 = *(const uint4*)&Apk[(size_t)(m0 + r_0) * Kfull + kbeg + cc_0 + 4];
    uint4 a10 = *(const uint4*)&Apk[(size_t)(m0 + r_1) * Kfull + kbeg + cc_1];
    uint4 a11 = *(const uint4*)&Apk[(size_t)(m0 + r_1) * Kfull + kbeg + cc_1 + 4];
    bf16x8 bc[4];
    {
        const int kc = kbeg >> 5;
        #pragma unroll
        for (int j = 0; j < 4; ++j)
            bc[j] = *(const bf16x8*)&Bf[(((size_t)(n16b + j) * KC + kc) * 64 + lane) * 8];
    }

    floatx4 acc[4][4];
    const floatx4 zz = {0.f, 0.f, 0.f, 0.f};
    #pragma unroll
    for (int i = 0; i < 4; ++i)
        #pragma unroll
        for (int j = 0; j < 4; ++j) acc[i][j] = zz;

    for (int k0 = kbeg; k0 < kend; k0 += 32) {
        uint4 H, L;
        unpack8(a00, a01, H, L);
        *(uint4*)&As_h[r_0 * LDS_STRIDE + cc_0] = H;
        *(uint4*)&As_l[r_0 * LDS_STRIDE + cc_0] = L;
        unpack8(a10, a11, H, L);
        *(uint4*)&As_h[r_1 * LDS_STRIDE + cc_1] = H;
        *(uint4*)&As_l[r_1 * LDS_STRIDE + cc_1] = L;
        __syncthreads();
        bf16x8 bn[4];
        if (k0 + 32 < kend) {
            const int kn = k0 + 32, kc = kn >> 5;
            a00 = *(const uint4*)&Apk[(size_t)(m0 + r_0) * Kfull + kn + cc_0];
            a01 = *(const uint4*)&Apk[(size_t)(m0 + r_0) * Kfull + kn + cc_0 + 4];
            a10 = *(const uint4*)&Apk[(size_t)(m0 + r_1) * Kfull + kn + cc_1];
            a11 = *(const uint4*)&Apk[(size_t)(m0 + r_1) * Kfull + kn + cc_1 + 4];
            #pragma unroll
            for (int j = 0; j < 4; ++j)
                bn[j] = *(const bf16x8*)&Bf[(((size_t)(n16b + j) * KC + kc) * 64 + lane) * 8];
        }
        bf16x8 ah[4], al[4];
        #pragma unroll
        for (int i = 0; i < 4; ++i) {
            const int off = (wm + i * 16 + m16) * LDS_STRIDE + q * 8;
            ah[i] = *(const bf16x8*)&As_h[off];
            al[i] = *(const bf16x8*)&As_l[off];
        }
        #pragma unroll
        for (int i = 0; i < 4; ++i)
            #pragma unroll
            for (int j = 0; j < 4; ++j) {
                acc[i][j] = __builtin_amdgcn_mfma_f32_16x16x32_bf16(ah[i], bc[j], acc[i][j], 0, 0, 0);
                acc[i][j] = __builtin_amdgcn_mfma_f32_16x16x32_bf16(al[i], bc[j], acc[i][j], 0, 0, 0);
            }
        #pragma unroll
        for (int j = 0; j < 4; ++j) bc[j] = bn[j];
        __syncthreads();
    }

    float* Cp = (MODE == 2) ? (Cf + (size_t)bx * 393216) : Cf;
    #pragma unroll
    for (int i = 0; i < 4; ++i) {
        const int row_b = m0 + wm + i * 16 + q * 4;
        #pragma unroll
        for (int j = 0; j < 4; ++j) {
            const int col = n0 + wn + j * 16 + m16;
            #pragma unroll
            for (int rr = 0; rr < 4; ++rr) {
                const int row = row_b + rr;
                const float v = acc[i][j][rr];
                if (MODE == 0) {
                    if (n0 < 2048) {
                        const int b = row >> 11, l = row & 2047;
                        Oh[((size_t)b * 2051 + l + 3) * 2048 + col] = f2bf(v);
                    } else {
                        Cp[(size_t)row * 2048 + (col - 2048)] = v;
                    }
                } else if (MODE == 1) {
                    Cp[(size_t)row * 1024 + col] = v;
                } else {
                    if (col < 96) Cp[(size_t)row * 96 + col] = v;
                }
            }
        }
    }
}

// ---------------------------------------------------------------------------
// Conv as plain-bf16 MFMA GEMM (A hi-only through LDS, B fragment-direct).
// A[p][k=w*1024+i] = XSP_h[b][l+w][g*1024+i] (3-row zero pad).
// Bf = convkF fragment-ordered [N=2048][K=4096], KC=128.
// Epilogue: u = silu(acc+bias) -> Upk (packed hi|lo).
// ---------------------------------------------------------------------------
__global__ __launch_bounds__(256) void conv2(
    const ushort_t* __restrict__ Xh, const ushort_t* __restrict__ Bf,
    const float* __restrict__ bias, uint_t* __restrict__ Upk)
{
    __shared__ __align__(16) ushort_t As_h[128 * LDS_STRIDE];
    const int t = threadIdx.x;
    const int lin = blockIdx.x, xcd = lin & 7, s = lin >> 3;   // s in [0,64)
    const int sweep = s >> 5, r = s & 31;
    const int bxp = r >> 1;
    const int by = xcd * 4 + ((sweep << 1) | (r & 1));
    const int m0 = by * 128, n0 = bxp * 128;
    const int g1024 = (n0 >= 1024) ? 1024 : 0;
    const int lane = t & 63, wave = t >> 6;
    const int wm = (wave >> 1) * 64, wn = (wave & 1) * 64;
    const int m16 = lane & 15, q = lane >> 4;
    const int n16b = (n0 + wn) >> 4;
    const int r_0 = t >> 2, cc_0 = (t & 3) * 8;
    const int r_1 = (t + 256) >> 2, cc_1 = ((t + 256) & 3) * 8;
    const int p_0 = m0 + r_0, b_0 = p_0 >> 11, l_0 = p_0 & 2047;
    const int p_1 = m0 + r_1, b_1 = p_1 >> 11, l_1 = p_1 & 2047;

    auto aA = [&](int bb, int ll, int k0, int cc) -> size_t {
        const int w = k0 >> 10;
        const int i = (k0 & 1023) + cc;
        return ((size_t)bb * 2051 + ll + w) * 2048 + g1024 + i;
    };

    uint4 pa0 = *(const uint4*)&Xh[aA(b_0, l_0, 0, cc_0)];
    uint4 pa1 = *(const uint4*)&Xh[aA(b_1, l_1, 0, cc_1)];
    bf16x8 bc[4];
    #pragma unroll
    for (int j = 0; j < 4; ++j)
        bc[j] = *(const bf16x8*)&Bf[(((size_t)(n16b + j) * 128 + 0) * 64 + lane) * 8];

    floatx4 acc[4][4];
    const floatx4 zz = {0.f, 0.f, 0.f, 0.f};
    #pragma unroll
    for (int i = 0; i < 4; ++i)
        #pragma unroll
        for (int j = 0; j < 4; ++j) acc[i][j] = zz;

    for (int k0 = 0; k0 < 4096; k0 += 32) {
        *(uint4*)&As_h[r_0 * LDS_STRIDE + cc_0] = pa0;
        *(uint4*)&As_h[r_1 * LDS_STRIDE + cc_1] = pa1;
        __syncthreads();
        bf16x8 bn[4];
        if (k0 + 32 < 4096) {
            const int kn = k0 + 32, kc = kn >> 5;
            pa0 = *(const uint4*)&Xh[aA(b_0, l_0, kn, cc_0)];
            pa1 = *(const uint4*)&Xh[aA(b_1, l_1, kn, cc_1)];
            #pragma unroll
            for (int j = 0; j < 4; ++j)
                bn[j] = *(const bf16x8*)&Bf[(((size_t)(n16b + j) * 128 + kc) * 64 + lane) * 8];
        }
        bf16x8 ah[4];
        #pragma unroll
        for (int i = 0; i < 4; ++i)
            ah[i] = *(const bf16x8*)&As_h[(wm + i * 16 + m16) * LDS_STRIDE + q * 8];
        #pragma unroll
        for (int i = 0; i < 4; ++i)
            #pragma unroll
            for (int j = 0; j < 4; ++j)
                acc[i][j] = __builtin_amdgcn_mfma_f32_16x16x32_bf16(ah[i], bc[j], acc[i][j], 0, 0, 0);
        #pragma unroll
        for (int j = 0; j < 4; ++j) bc[j] = bn[j];
        __syncthreads();
    }

    #pragma unroll
    for (int i = 0; i < 4; ++i) {
        const int row_b = m0 + wm + i * 16 + q * 4;
        #pragma unroll
        for (int j = 0; j < 4; ++j) {
            const int col = n0 + wn + j * 16 + m16;
            const float bz = bias[col];
            #pragma unroll
            for (int rr = 0; rr < 4; ++rr) {
                const int row = row_b + rr;
                const float v = silu_f(acc[i][j][rr] + bz);
                Upk[(size_t)row * 2048 + col] = packhl(v);
            }
        }
    }
}

// Sum the 4 split-K partials of dbc.
__global__ __launch_bounds__(256) void dbc_reduce(
    const float* __restrict__ DBCP, float* __restrict__ DBC)
{
    const int i = blockIdx.x * 256 + threadIdx.x;   // < 393216
    DBC[i] = (DBCP[i] + DBCP[393216 + i]) + (DBCP[786432 + i] + DBCP[1179648 + i]);
}

// ---------------------------------------------------------------------------
// delta[p,d] = clip(softplus(dbc[p,0:64] @ W_dt[:,d] + b_dt[d]), 1e-3, 1e-1)
// ---------------------------------------------------------------------------
__global__ __launch_bounds__(256) void delta_kernel(
    const float* __restrict__ DBC, const float* __restrict__ W_dt,
    const float* __restrict__ b_dt, float* __restrict__ DELTA)
{
    const int n  = blockIdx.x * 256 + threadIdx.x;
    const int p0 = blockIdx.y * 16;
    const int t  = threadIdx.x;
    __shared__ float dt_s[16][64];
    #pragma unroll
    for (int j = 0; j < 4; ++j) {
        const int lin = j * 256 + t;
        const int r = lin >> 6, k = lin & 63;
        dt_s[r][k] = DBC[(size_t)(p0 + r) * 96 + k];
    }
    __syncthreads();
    float acc[16];
    const float bz = b_dt[n];
    #pragma unroll
    for (int r = 0; r < 16; ++r) acc[r] = bz;
    for (int k = 0; k < 64; ++k) {
        const float wv = W_dt[(size_t)k * 2048 + n];
        #pragma unroll
        for (int r = 0; r < 16; ++r) acc[r] += dt_s[r][k] * wv;
    }
    #pragma unroll
    for (int r = 0; r < 16; ++r) {
        float a = acc[r];
        float sp = (a > 20.f) ? a : log1pf(expf(a));
        sp = fminf(fmaxf(sp, 0.001f), 0.1f);
        DELTA[(size_t)(p0 + r) * 2048 + n] = sp;
    }
}

// ---------------------------------------------------------------------------
// Chunked scan (64 chunks of 32). HEND/HINIT [c][b][d][16n]; SD[c][b][d].
// ---------------------------------------------------------------------------
__global__ __launch_bounds__(256) void scan_p1(
    const float* __restrict__ DELTA, const uint_t* __restrict__ Upk,
    const float* __restrict__ DBC, const float* __restrict__ A_log,
    float* __restrict__ HEND, float* __restrict__ SD)
{
    const int t = threadIdx.x;
    const int d = blockIdx.x * 256 + t;
    const int c = blockIdx.y;
    const int b = blockIdx.z;
    const int p0 = b * 2048 + c * 32;
    __shared__ float Bs[32][16];
    for (int lin = t; lin < 512; lin += 256) {
        const int s = lin >> 4, n = lin & 15;
        Bs[s][n] = DBC[(size_t)(p0 + s) * 96 + 64 + n];
    }
    __syncthreads();
    float Af[16];
    *(float4*)&Af[0]  = *(const float4*)&A_log[(size_t)d * 16 + 0];
    *(float4*)&Af[4]  = *(const float4*)&A_log[(size_t)d * 16 + 4];
    *(float4*)&Af[8]  = *(const float4*)&A_log[(size_t)d * 16 + 8];
    *(float4*)&Af[12] = *(const float4*)&A_log[(size_t)d * 16 + 12];
    #pragma unroll
    for (int n = 0; n < 16; ++n) Af[n] = -__expf(Af[n]);

    float h[16] = {};
    float sd = 0.f;
    for (int s = 0; s < 32; ++s) {
        const size_t ix = (size_t)(p0 + s) * 2048 + d;
        const float dv = DELTA[ix];
        const float uv = unpack_sum(Upk[ix]);
        const float du = dv * uv;
        sd += dv;
        #pragma unroll
        for (int n = 0; n < 16; ++n)
            h[n] = __expf(dv * Af[n]) * h[n] + du * Bs[s][n];
    }
    const size_t hb = (((size_t)c * 2 + b) * 2048 + d) * 16;
    *(float4*)&HEND[hb + 0]  = *(float4*)&h[0];
    *(float4*)&HEND[hb + 4]  = *(float4*)&h[4];
    *(float4*)&HEND[hb + 8]  = *(float4*)&h[8];
    *(float4*)&HEND[hb + 12] = *(float4*)&h[12];
    SD[((size_t)c * 2 + b) * 2048 + d] = sd;
}

__global__ __launch_bounds__(256) void scan_p2(
    const float* __restrict__ HEND, const float* __restrict__ SD,
    const float* __restrict__ A_log, float* __restrict__ HINIT)
{
    const int g = blockIdx.x * 256 + threadIdx.x;   // < 65536
    const int n = g & 15, d = (g >> 4) & 2047, b = (g >> 15) & 1;
    const float Af = -__expf(A_log[(size_t)d * 16 + n]);
    float h = 0.f;
    #pragma unroll 8
    for (int c = 0; c < 64; ++c) {
        const size_t cb = (size_t)c * 2 + b;
        const size_t idx = (cb * 2048 + d) * 16 + n;
        HINIT[idx] = h;
        h = __expf(Af * SD[cb * 2048 + d]) * h + HEND[idx];
    }
}

// Pass 3: re-scan from h_init, y, gate; emit G packed hi|lo.
__global__ __launch_bounds__(256) void scan_p3(
    const float* __restrict__ DELTA, const uint_t* __restrict__ Upk,
    const float* __restrict__ DBC, const float* __restrict__ RES,
    const float* __restrict__ A_log, const float* __restrict__ Dp,
    const float* __restrict__ HINIT, uint_t* __restrict__ Gpk)
{
    const int t = threadIdx.x;
    const int d = blockIdx.x * 256 + t;
    const int c = blockIdx.y;
    const int b = blockIdx.z;
    const int p0 = b * 2048 + c * 32;
    __shared__ float Bs[32][16];
    __shared__ float Cs[32][16];
    for (int lin = t; lin < 512; lin += 256) {
        const int s = lin >> 4, n = lin & 15;
        Bs[s][n] = DBC[(size_t)(p0 + s) * 96 + 64 + n];
        Cs[s][n] = DBC[(size_t)(p0 + s) * 96 + 80 + n];
    }
    __syncthreads();
    float Af[16];
    *(float4*)&Af[0]  = *(const float4*)&A_log[(size_t)d * 16 + 0];
    *(float4*)&Af[4]  = *(const float4*)&A_log[(size_t)d * 16 + 4];
    *(float4*)&Af[8]  = *(const float4*)&A_log[(size_t)d * 16 + 8];
    *(float4*)&Af[12] = *(const float4*)&A_log[(size_t)d * 16 + 12];
    #pragma unroll
    for (int n = 0; n < 16; ++n) Af[n] = -__expf(Af[n]);

    const size_t hb = (((size_t)c * 2 + b) * 2048 + d) * 16;
    float h[16];
    *(float4*)&h[0]  = *(const float4*)&HINIT[hb + 0];
    *(float4*)&h[4]  = *(const float4*)&HINIT[hb + 4];
    *(float4*)&h[8]  = *(const float4*)&HINIT[hb + 8];
    *(float4*)&h[12] = *(const float4*)&HINIT[hb + 12];
    const float Dd = Dp[d];

    for (int s = 0; s < 32; ++s) {
        const int p = p0 + s;
        const size_t ix = (size_t)p * 2048 + d;
        const float dv = DELTA[ix];
        const float uv = unpack_sum(Upk[ix]);
        const float du = dv * uv;
        float y = 0.f;
        #pragma unroll
        for (int n = 0; n < 16; ++n) {
            h[n] = __expf(dv * Af[n]) * h[n] + du * Bs[s][n];
            y += h[n] * Cs[s][n];
        }
        const float resv = RES[ix];
        const float gv = (y + uv * Dd) * silu_f(resv);
        Gpk[ix] = packhl(gv);
    }
}

// ---------------------------------------------------------------------------
extern "C" void kernel_launch(void* const* d_in, const int* in_sizes, int n_in,
                              void* d_out, int out_size, void* d_ws, size_t ws_size,
                              hipStream_t stream) {
    const float* x      = (const float*)d_in[0];
    const float* W_in   = (const float*)d_in[1];
    const float* conv_k = (const float*)d_in[2];
    const float* conv_b = (const float*)d_in[3];
    const float* W_x    = (const float*)d_in[4];
    const float* W_dt   = (const float*)d_in[5];
    const float* b_dt   = (const float*)d_in[6];
    const float* A_log  = (const float*)d_in[7];
    const float* Dv     = (const float*)d_in[8];
    const float* W_out  = (const float*)d_in[9];
    float* out = (float*)d_out;

    char* base = (char*)d_ws;
    float*    RES      = (float*)(base);                  // 33,554,432
    uint_t*   Upk      = (uint_t*)(base + 33554432);      // 33,554,432
    float*    DELTA    = (float*)(base + 67108864);       // 33,554,432
    ushort_t* XSP_h    = (ushort_t*)(base + 100663296);   // 16,801,792 (2 x 2051 x 2048)
    float*    HEND     = (float*)(base + 100663296);      // alias over XSP (dead after conv2)
    uint_t*   xpk      = (uint_t*)(base + 117465088);     // 16,777,216
    ushort_t* convkF   = (ushort_t*)(base + 134242304);   // 16,777,216
    uint_t*   Gpk      = (uint_t*)(base + 117465088);     // alias over xpk+convkF (dead)
    ushort_t* WinF     = (ushort_t*)(base + 151019520);   //  8,388,608
    ushort_t* WoutF    = (ushort_t*)(base + 159408128);   //  4,194,304
    ushort_t* WxF      = (ushort_t*)(base + 163602432);   //    524,288
    float*    DBCP     = (float*)(base + 164126720);      //  6,291,456
    float*    DBC      = (float*)(base + 170418176);      //  1,572,864
    float*    SD       = (float*)(base + 171991040);      //  1,048,576
    float*    HINIT    = (float*)(base + 173039616);      // 16,777,216

    // 0) all prep in one launch
    prep_all<<<19504, 256, 0, stream>>>(x, W_in, conv_k, W_out, W_x,
                                        xpk, WinF, convkF, WoutF, WxF, XSP_h);
    // 1) xz: xs -> XSP bf16 hi (+pad), res -> RES fp32
    gemm2<0><<<1024, 256, 0, stream>>>(xpk, WinF, 1024, RES, XSP_h);
    // 2) u = silu(conv + b) -> Upk
    conv2<<<512, 256, 0, stream>>>(XSP_h, convkF, conv_b, Upk);
    // 3) dbc = U @ W_x, split-K x4 + reduce
    gemm2<2><<<dim3(4, 32), 256, 0, stream>>>(Upk, WxF, 2048, DBCP, nullptr);
    dbc_reduce<<<1536, 256, 0, stream>>>(DBCP, DBC);
    // 4) delta
    delta_kernel<<<dim3(8, 256), 256, 0, stream>>>(DBC, W_dt, b_dt, DELTA);
    // 5) chunked scan
    scan_p1<<<dim3(8, 64, 2), 256, 0, stream>>>(DELTA, Upk, DBC, A_log, HEND, SD);
    scan_p2<<<256, 256, 0, stream>>>(HEND, SD, A_log, HINIT);
    scan_p3<<<dim3(8, 64, 2), 256, 0, stream>>>(DELTA, Upk, DBC, RES, A_log, Dv,
                                                HINIT, Gpk);
    // 6) out = G @ W_out
    gemm2<1><<<256, 256, 0, stream>>>(Gpk, WoutF, 2048, out, nullptr);
}